// Round 2
// baseline (1267.539 us; speedup 1.0000x reference)
//
#include <hip/hip_runtime.h>

// Problem constants
#define B_ROWS 4096
#define DIN 64
#define NH 128
#define DOUT 512
#define NB 256            // blocks in solve grid
#define ROWS_PER_BLK 16
#define MAXSTEP_CAP 1000

// ---------------------------------------------------------------------------
// Kernel A: fixed-point solve, per-block local convergence (no grid sync).
// 1 wave per row (4 rows/wave, 16 rows/block). K (64x128) staged twice in LDS
// (row-major padded to 132 for float4 row dots; transposed padded to 68 for
// float4 column dots).
//
// Correctness argument vs the reference's GLOBAL stopping rule: the map is a
// contraction (rho ~ 0.45); stopping this block when its local
// max(relDeltaAF)+max(relDeltaLF) < 1e-4 (tighter than the global 1e-3) puts
// its state within ~2e-3 relative of the reference state at the reference's
// stop step N (geometric series bound, over- or under-shoot), i.e. ~0.08 abs
// on a 38-magnitude output vs 0.76 threshold; the shared final refinement
// contracts this further.
// ---------------------------------------------------------------------------
__global__ __launch_bounds__(256, 1)
void solve_kernel(const float* __restrict__ LT, const float* __restrict__ Kg,
                  const float* __restrict__ AT, const int* __restrict__ msp,
                  float* __restrict__ AFout, float* __restrict__ LFout)
{
    __shared__ float Ks[DIN][132];   // row access, bank = (4i+h)%32
    __shared__ float KT[NH][68];     // col access, bank = (4h+i)%32
    __shared__ float sAF[16][NH];
    __shared__ float sAdi[16][NH];
    __shared__ float sLdi[16][DIN];
    __shared__ float sLF[16][DIN];
    __shared__ float wredA[4], wredL[4];

    const int tid = threadIdx.x, bid = blockIdx.x;
    const int lane = tid & 63, w = tid >> 6;

    for (int idx = tid; idx < DIN * NH; idx += 256) {
        int i = idx >> 7, h = idx & 127;
        float v = fmaxf(Kg[idx], 0.0f);   // _st_relu forward == relu
        Ks[i][h] = v;
        KT[h][i] = v;
    }
    const float at0 = fmaxf(AT[lane], 0.0f);
    const float at1 = fmaxf(AT[64 + lane], 0.0f);
    int max_step = *msp;
    if (max_step > MAXSTEP_CAP) max_step = MAXSTEP_CAP;

    float af0[4], af1[4], lf[4], lt[4];
    #pragma unroll
    for (int r = 0; r < 4; ++r) {
        int row = bid * ROWS_PER_BLK + (w << 2) + r;
        lt[r] = LT[row * DIN + lane];
        af0[r] = af1[r] = lf[r] = 0.0f;
    }
    __syncthreads();

    // One body == one reference while-loop iteration (and also the final
    // refinement, which is numerically the identical update).
    auto body = [&](float* pmaxA, float* pmaxL) {
        #pragma unroll
        for (int r = 0; r < 4; ++r) {
            int s = (w << 2) + r;
            sAF[s][lane] = af0[r];
            sAF[s][64 + lane] = af1[r];
            sLF[s][lane] = lf[r];
        }
        __syncthreads();
        // P1: Ldi = LT/(K@AF+1) ; Adi = AT/(K^T@LF+1)
        {
            float s1r[4] = {0.f, 0.f, 0.f, 0.f};
            const float4* Kr4 = reinterpret_cast<const float4*>(&Ks[lane][0]);
            #pragma unroll 8
            for (int c = 0; c < 32; ++c) {
                float4 k4 = Kr4[c];
                #pragma unroll
                for (int r = 0; r < 4; ++r) {
                    float4 a4 = *reinterpret_cast<const float4*>(&sAF[(w << 2) + r][c << 2]);
                    s1r[r] += k4.x*a4.x + k4.y*a4.y + k4.z*a4.z + k4.w*a4.w;
                }
            }
            float s3a[4] = {0.f,0.f,0.f,0.f}, s3b[4] = {0.f,0.f,0.f,0.f};
            const float4* Ka4 = reinterpret_cast<const float4*>(&KT[lane][0]);
            const float4* Kb4 = reinterpret_cast<const float4*>(&KT[64 + lane][0]);
            #pragma unroll 8
            for (int c = 0; c < 16; ++c) {
                float4 ka = Ka4[c], kb = Kb4[c];
                #pragma unroll
                for (int r = 0; r < 4; ++r) {
                    float4 v = *reinterpret_cast<const float4*>(&sLF[(w << 2) + r][c << 2]);
                    s3a[r] += ka.x*v.x + ka.y*v.y + ka.z*v.z + ka.w*v.w;
                    s3b[r] += kb.x*v.x + kb.y*v.y + kb.z*v.z + kb.w*v.w;
                }
            }
            #pragma unroll
            for (int r = 0; r < 4; ++r) {
                int s = (w << 2) + r;
                sLdi[s][lane]      = lt[r] / (s1r[r] + 1.0f);
                sAdi[s][lane]      = at0 / (s3a[r] + 1.0f);
                sAdi[s][64 + lane] = at1 / (s3b[r] + 1.0f);
            }
        }
        __syncthreads();
        // P2: AF_new = AT/(K^T@Ldi+1) ; LF_new = LT/(K@Adi+1)
        {
            float s2a[4] = {0.f,0.f,0.f,0.f}, s2b[4] = {0.f,0.f,0.f,0.f};
            const float4* Ka4 = reinterpret_cast<const float4*>(&KT[lane][0]);
            const float4* Kb4 = reinterpret_cast<const float4*>(&KT[64 + lane][0]);
            #pragma unroll 8
            for (int c = 0; c < 16; ++c) {
                float4 ka = Ka4[c], kb = Kb4[c];
                #pragma unroll
                for (int r = 0; r < 4; ++r) {
                    float4 v = *reinterpret_cast<const float4*>(&sLdi[(w << 2) + r][c << 2]);
                    s2a[r] += ka.x*v.x + ka.y*v.y + ka.z*v.z + ka.w*v.w;
                    s2b[r] += kb.x*v.x + kb.y*v.y + kb.z*v.z + kb.w*v.w;
                }
            }
            float s4r[4] = {0.f,0.f,0.f,0.f};
            const float4* Kr4 = reinterpret_cast<const float4*>(&Ks[lane][0]);
            #pragma unroll 8
            for (int c = 0; c < 32; ++c) {
                float4 k4 = Kr4[c];
                #pragma unroll
                for (int r = 0; r < 4; ++r) {
                    float4 a4 = *reinterpret_cast<const float4*>(&sAdi[(w << 2) + r][c << 2]);
                    s4r[r] += k4.x*a4.x + k4.y*a4.y + k4.z*a4.z + k4.w*a4.w;
                }
            }
            #pragma unroll
            for (int r = 0; r < 4; ++r) {
                float afn0 = at0 / (s2a[r] + 1.0f);
                float afn1 = at1 / (s2b[r] + 1.0f);
                float lfn  = lt[r] / (s4r[r] + 1.0f);
                if (pmaxA) {   // diff uses OLD state in the denominator
                    *pmaxA = fmaxf(*pmaxA, fabsf(afn0 - af0[r]) / (af0[r] + 1e-5f));
                    *pmaxA = fmaxf(*pmaxA, fabsf(afn1 - af1[r]) / (af1[r] + 1e-5f));
                    *pmaxL = fmaxf(*pmaxL, fabsf(lfn - lf[r]) / (lf[r] + 1e-5f));
                }
                af0[r] = afn0; af1[r] = afn1; lf[r] = lfn;
            }
        }
        __syncthreads();
    };

    int step = 0;
    bool done = false;
    while (step < max_step && !done) {
        float maxA = 0.0f, maxL = 0.0f;
        body(&maxA, &maxL);
        #pragma unroll
        for (int off = 32; off; off >>= 1) {
            maxA = fmaxf(maxA, __shfl_xor(maxA, off));
            maxL = fmaxf(maxL, __shfl_xor(maxL, off));
        }
        if (lane == 0) { wredA[w] = maxA; wredL[w] = maxL; }
        __syncthreads();
        float mA = fmaxf(fmaxf(wredA[0], wredA[1]), fmaxf(wredA[2], wredA[3]));
        float mL = fmaxf(fmaxf(wredL[0], wredL[1]), fmaxf(wredL[2], wredL[3]));
        done = (mA + mL) < 1e-4f;    // tighter than ref's 1e-3 (see header note)
        ++step;
        __syncthreads();             // protect wred reuse next iteration
    }

    // Final refinement (reference's post-loop extra update) — same body.
    body(nullptr, nullptr);

    #pragma unroll
    for (int r = 0; r < 4; ++r) {
        int row = bid * ROWS_PER_BLK + (w << 2) + r;
        AFout[row * NH + lane]      = af0[r];
        AFout[row * NH + 64 + lane] = af1[r];
        LFout[row * DIN + lane]     = lf[r];
    }
}

// ---------------------------------------------------------------------------
// Kernel B: out[b,o] = sum_{i,h} K[i,h]*LF[b,i]*AF[b,h]*u[i*128+h,o]
//                    + sum_h AF[b,h]*e[h,o] + bias[o]
// Tiled f32 GEMM: 128x64 tile per block, K-chunks of 64 along flattened (i,h).
// A-element folds LF*AF at stage time; B-element folds relu(K)*u at stage time.
// Chunks 128,129 handle the AF@e term (unscaled AF vs e rows).
// ---------------------------------------------------------------------------
__global__ __launch_bounds__(256, 1)
void out_gemm(const float* __restrict__ AFw, const float* __restrict__ LFw,
              const float* __restrict__ Kg, const float* __restrict__ ug,
              const float* __restrict__ eg, const float* __restrict__ bg,
              float* __restrict__ out)
{
    __shared__ float As[128][68];
    __shared__ float Bs[64][68];
    const int tid = threadIdx.x;
    const int tx = tid & 15, ty = tid >> 4;          // 16 x 16 thread grid
    const int b0 = blockIdx.x * 128, o0 = blockIdx.y * 64;
    float acc[8][4] = {};

    for (int c = 0; c < 130; ++c) {
        const bool is_main = (c < 128);
        const int i  = is_main ? (c >> 1) : 0;
        const int h0 = is_main ? ((c & 1) << 6) : ((c - 128) << 6);
        // Stage A: As[row][t] = AF[b0+row][h0+t] * (main ? LF[b0+row][i] : 1)
        #pragma unroll
        for (int rr = 0; rr < 8; ++rr) {
            int row = ty + (rr << 4);
            float scale = is_main ? LFw[(b0 + row) * DIN + i] : 1.0f;
            float4 a4 = *reinterpret_cast<const float4*>(&AFw[(b0 + row) * NH + h0 + (tx << 2)]);
            a4.x *= scale; a4.y *= scale; a4.z *= scale; a4.w *= scale;
            *reinterpret_cast<float4*>(&As[row][tx << 2]) = a4;
        }
        // Stage B: Bs[t][oc] = main ? relu(K[i][h0+t]) * u[...] : e[...]
        #pragma unroll
        for (int rr = 0; rr < 4; ++rr) {
            int t = ty + (rr << 4);
            float4 u4;
            if (is_main) {
                int krow = (i << 7) + h0 + t;
                float kv = fmaxf(Kg[krow], 0.0f);
                u4 = *reinterpret_cast<const float4*>(&ug[krow * DOUT + o0 + (tx << 2)]);
                u4.x *= kv; u4.y *= kv; u4.z *= kv; u4.w *= kv;
            } else {
                u4 = *reinterpret_cast<const float4*>(&eg[(h0 + t) * DOUT + o0 + (tx << 2)]);
            }
            *reinterpret_cast<float4*>(&Bs[t][tx << 2]) = u4;
        }
        __syncthreads();
        #pragma unroll
        for (int t = 0; t < 64; t += 4) {
            float4 q0 = *reinterpret_cast<const float4*>(&Bs[t + 0][tx << 2]);
            float4 q1 = *reinterpret_cast<const float4*>(&Bs[t + 1][tx << 2]);
            float4 q2 = *reinterpret_cast<const float4*>(&Bs[t + 2][tx << 2]);
            float4 q3 = *reinterpret_cast<const float4*>(&Bs[t + 3][tx << 2]);
            #pragma unroll
            for (int r = 0; r < 8; ++r) {
                float4 a4 = *reinterpret_cast<const float4*>(&As[ty + (r << 4)][t]);
                acc[r][0] += a4.x*q0.x + a4.y*q1.x + a4.z*q2.x + a4.w*q3.x;
                acc[r][1] += a4.x*q0.y + a4.y*q1.y + a4.z*q2.y + a4.w*q3.y;
                acc[r][2] += a4.x*q0.z + a4.y*q1.z + a4.z*q2.z + a4.w*q3.z;
                acc[r][3] += a4.x*q0.w + a4.y*q1.w + a4.z*q2.w + a4.w*q3.w;
            }
        }
        __syncthreads();
    }
    float4 bi = *reinterpret_cast<const float4*>(&bg[o0 + (tx << 2)]);
    #pragma unroll
    for (int r = 0; r < 8; ++r) {
        int row = b0 + ty + (r << 4);
        float4 v;
        v.x = acc[r][0] + bi.x; v.y = acc[r][1] + bi.y;
        v.z = acc[r][2] + bi.z; v.w = acc[r][3] + bi.w;
        *reinterpret_cast<float4*>(&out[row * DOUT + o0 + (tx << 2)]) = v;
    }
}

// ---------------------------------------------------------------------------
// Workspace layout (bytes):
//   [0, 2097152)              AF : float[4096][128]
//   [2097152, 2097152+1048576) LF : float[4096][64]
// Total ~3.1 MB. Fully written by solve_kernel before out_gemm reads it, so no
// init/memset is required and replays are deterministic.
// ---------------------------------------------------------------------------
extern "C" void kernel_launch(void* const* d_in, const int* in_sizes, int n_in,
                              void* d_out, int out_size, void* d_ws, size_t ws_size,
                              hipStream_t stream)
{
    const float* LT   = (const float*)d_in[0];
    const float* Kg   = (const float*)d_in[1];
    const float* AT   = (const float*)d_in[2];
    const float* ug   = (const float*)d_in[3];
    const float* eg   = (const float*)d_in[4];
    const float* bg   = (const float*)d_in[5];
    const int*   msp  = (const int*)d_in[6];
    float* out = (float*)d_out;

    char* ws = (char*)d_ws;
    float* AFw = (float*)(ws);
    float* LFw = (float*)(ws + (size_t)B_ROWS * NH * 4);

    solve_kernel<<<dim3(NB), dim3(256), 0, stream>>>(LT, Kg, AT, msp, AFw, LFw);

    dim3 g2(B_ROWS / 128, DOUT / 64);
    out_gemm<<<g2, dim3(256), 0, stream>>>(AFw, LFw, Kg, ug, eg, bg, out);
}

// Round 3
// 460.634 us; speedup vs baseline: 2.7517x; 2.7517x over previous
//
#include <hip/hip_runtime.h>

// Problem constants
#define B_ROWS 4096
#define DIN 64
#define NH 128
#define DOUT 512
#define NB 256
#define ROWS_PER_BLK 16
#define MAXSTEP_CAP 1000
#define KTOT 8320          // 8192 main + 128 e-term
#define WT_STRIDE 8320

typedef __attribute__((ext_vector_type(8))) short short8;
typedef __attribute__((ext_vector_type(4))) float f32x4;

// round-to-nearest-even f32 -> bf16, packed pair into a uint
__device__ inline unsigned bf16pair(float lo, float hi) {
    unsigned a = __float_as_uint(lo), b = __float_as_uint(hi);
    a = (a + 0x7fffu + ((a >> 16) & 1u)) >> 16;
    b = (b + 0x7fffu + ((b >> 16) & 1u)) >> 16;
    return a | (b << 16);
}

// ---------------------------------------------------------------------------
// Kernel A: fixed-point solve, per-block local convergence (no grid sync).
// Unchanged from round 2 (passed, absmax 0.25). See round-2 header for the
// contraction-based correctness argument (local tol 1e-4 vs global 1e-3).
// ---------------------------------------------------------------------------
__global__ __launch_bounds__(256, 1)
void solve_kernel(const float* __restrict__ LT, const float* __restrict__ Kg,
                  const float* __restrict__ AT, const int* __restrict__ msp,
                  float* __restrict__ AFout, float* __restrict__ LFout)
{
    __shared__ float Ks[DIN][132];
    __shared__ float KT[NH][68];
    __shared__ float sAF[16][NH];
    __shared__ float sAdi[16][NH];
    __shared__ float sLdi[16][DIN];
    __shared__ float sLF[16][DIN];
    __shared__ float wredA[4], wredL[4];

    const int tid = threadIdx.x, bid = blockIdx.x;
    const int lane = tid & 63, w = tid >> 6;

    for (int idx = tid; idx < DIN * NH; idx += 256) {
        int i = idx >> 7, h = idx & 127;
        float v = fmaxf(Kg[idx], 0.0f);
        Ks[i][h] = v;
        KT[h][i] = v;
    }
    const float at0 = fmaxf(AT[lane], 0.0f);
    const float at1 = fmaxf(AT[64 + lane], 0.0f);
    int max_step = *msp;
    if (max_step > MAXSTEP_CAP) max_step = MAXSTEP_CAP;

    float af0[4], af1[4], lf[4], lt[4];
    #pragma unroll
    for (int r = 0; r < 4; ++r) {
        int row = bid * ROWS_PER_BLK + (w << 2) + r;
        lt[r] = LT[row * DIN + lane];
        af0[r] = af1[r] = lf[r] = 0.0f;
    }
    __syncthreads();

    auto body = [&](float* pmaxA, float* pmaxL) {
        #pragma unroll
        for (int r = 0; r < 4; ++r) {
            int s = (w << 2) + r;
            sAF[s][lane] = af0[r];
            sAF[s][64 + lane] = af1[r];
            sLF[s][lane] = lf[r];
        }
        __syncthreads();
        {
            float s1r[4] = {0.f, 0.f, 0.f, 0.f};
            const float4* Kr4 = reinterpret_cast<const float4*>(&Ks[lane][0]);
            #pragma unroll 8
            for (int c = 0; c < 32; ++c) {
                float4 k4 = Kr4[c];
                #pragma unroll
                for (int r = 0; r < 4; ++r) {
                    float4 a4 = *reinterpret_cast<const float4*>(&sAF[(w << 2) + r][c << 2]);
                    s1r[r] += k4.x*a4.x + k4.y*a4.y + k4.z*a4.z + k4.w*a4.w;
                }
            }
            float s3a[4] = {0.f,0.f,0.f,0.f}, s3b[4] = {0.f,0.f,0.f,0.f};
            const float4* Ka4 = reinterpret_cast<const float4*>(&KT[lane][0]);
            const float4* Kb4 = reinterpret_cast<const float4*>(&KT[64 + lane][0]);
            #pragma unroll 8
            for (int c = 0; c < 16; ++c) {
                float4 ka = Ka4[c], kb = Kb4[c];
                #pragma unroll
                for (int r = 0; r < 4; ++r) {
                    float4 v = *reinterpret_cast<const float4*>(&sLF[(w << 2) + r][c << 2]);
                    s3a[r] += ka.x*v.x + ka.y*v.y + ka.z*v.z + ka.w*v.w;
                    s3b[r] += kb.x*v.x + kb.y*v.y + kb.z*v.z + kb.w*v.w;
                }
            }
            #pragma unroll
            for (int r = 0; r < 4; ++r) {
                int s = (w << 2) + r;
                sLdi[s][lane]      = lt[r] / (s1r[r] + 1.0f);
                sAdi[s][lane]      = at0 / (s3a[r] + 1.0f);
                sAdi[s][64 + lane] = at1 / (s3b[r] + 1.0f);
            }
        }
        __syncthreads();
        {
            float s2a[4] = {0.f,0.f,0.f,0.f}, s2b[4] = {0.f,0.f,0.f,0.f};
            const float4* Ka4 = reinterpret_cast<const float4*>(&KT[lane][0]);
            const float4* Kb4 = reinterpret_cast<const float4*>(&KT[64 + lane][0]);
            #pragma unroll 8
            for (int c = 0; c < 16; ++c) {
                float4 ka = Ka4[c], kb = Kb4[c];
                #pragma unroll
                for (int r = 0; r < 4; ++r) {
                    float4 v = *reinterpret_cast<const float4*>(&sLdi[(w << 2) + r][c << 2]);
                    s2a[r] += ka.x*v.x + ka.y*v.y + ka.z*v.z + ka.w*v.w;
                    s2b[r] += kb.x*v.x + kb.y*v.y + kb.z*v.z + kb.w*v.w;
                }
            }
            float s4r[4] = {0.f,0.f,0.f,0.f};
            const float4* Kr4 = reinterpret_cast<const float4*>(&Ks[lane][0]);
            #pragma unroll 8
            for (int c = 0; c < 32; ++c) {
                float4 k4 = Kr4[c];
                #pragma unroll
                for (int r = 0; r < 4; ++r) {
                    float4 a4 = *reinterpret_cast<const float4*>(&sAdi[(w << 2) + r][c << 2]);
                    s4r[r] += k4.x*a4.x + k4.y*a4.y + k4.z*a4.z + k4.w*a4.w;
                }
            }
            #pragma unroll
            for (int r = 0; r < 4; ++r) {
                float afn0 = at0 / (s2a[r] + 1.0f);
                float afn1 = at1 / (s2b[r] + 1.0f);
                float lfn  = lt[r] / (s4r[r] + 1.0f);
                if (pmaxA) {
                    *pmaxA = fmaxf(*pmaxA, fabsf(afn0 - af0[r]) / (af0[r] + 1e-5f));
                    *pmaxA = fmaxf(*pmaxA, fabsf(afn1 - af1[r]) / (af1[r] + 1e-5f));
                    *pmaxL = fmaxf(*pmaxL, fabsf(lfn - lf[r]) / (lf[r] + 1e-5f));
                }
                af0[r] = afn0; af1[r] = afn1; lf[r] = lfn;
            }
        }
        __syncthreads();
    };

    int step = 0;
    bool done = false;
    while (step < max_step && !done) {
        float maxA = 0.0f, maxL = 0.0f;
        body(&maxA, &maxL);
        #pragma unroll
        for (int off = 32; off; off >>= 1) {
            maxA = fmaxf(maxA, __shfl_xor(maxA, off));
            maxL = fmaxf(maxL, __shfl_xor(maxL, off));
        }
        if (lane == 0) { wredA[w] = maxA; wredL[w] = maxL; }
        __syncthreads();
        float mA = fmaxf(fmaxf(wredA[0], wredA[1]), fmaxf(wredA[2], wredA[3]));
        float mL = fmaxf(fmaxf(wredL[0], wredL[1]), fmaxf(wredL[2], wredL[3]));
        done = (mA + mL) < 1e-4f;
        ++step;
        __syncthreads();
    }

    body(nullptr, nullptr);

    #pragma unroll
    for (int r = 0; r < 4; ++r) {
        int row = bid * ROWS_PER_BLK + (w << 2) + r;
        AFout[row * NH + lane]      = af0[r];
        AFout[row * NH + 64 + lane] = af1[r];
        LFout[row * DIN + lane]     = lf[r];
    }
}

// ---------------------------------------------------------------------------
// Kernel P: W_T[o][k] = bf16( relu(K[k]) * u[k][o] ) for k < 8192
//           W_T[o][8192+h] = bf16( e[h][o] )
// 64x64 tiles, LDS transpose. Grid (130, 8).
// ---------------------------------------------------------------------------
__global__ __launch_bounds__(256, 1)
void prep_wt(const float* __restrict__ Kg, const float* __restrict__ ug,
             const float* __restrict__ eg, ushort* __restrict__ WT)
{
    __shared__ float tile[64][68];
    const int t = threadIdx.x;
    const int k0 = blockIdx.x * 64;
    const int o0 = blockIdx.y * 64;
    const bool is_main = (k0 < 8192);
    const int r0 = t >> 4, c4 = (t & 15) << 2;
    #pragma unroll
    for (int p = 0; p < 4; ++p) {
        int r = r0 + (p << 4);
        float4 v;
        if (is_main) {
            float kv = fmaxf(Kg[k0 + r], 0.0f);
            v = *reinterpret_cast<const float4*>(&ug[(size_t)(k0 + r) * DOUT + o0 + c4]);
            v.x *= kv; v.y *= kv; v.z *= kv; v.w *= kv;
        } else {
            v = *reinterpret_cast<const float4*>(&eg[(size_t)(k0 - 8192 + r) * DOUT + o0 + c4]);
        }
        *reinterpret_cast<float4*>(&tile[r][c4]) = v;
    }
    __syncthreads();
    const int o = t >> 2, q = t & 3;
    #pragma unroll
    for (int j = 0; j < 2; ++j) {
        int kb = (q << 4) + (j << 3);
        uint4 u4;
        u4.x = bf16pair(tile[kb + 0][o], tile[kb + 1][o]);
        u4.y = bf16pair(tile[kb + 2][o], tile[kb + 3][o]);
        u4.z = bf16pair(tile[kb + 4][o], tile[kb + 5][o]);
        u4.w = bf16pair(tile[kb + 6][o], tile[kb + 7][o]);
        *reinterpret_cast<uint4*>(&WT[(size_t)(o0 + o) * WT_STRIDE + k0 + kb]) = u4;
    }
}

// ---------------------------------------------------------------------------
// Kernel B: bf16 MFMA GEMM.  out[b,o] = sum_k A[b,k]*W[k,o] + bias[o]
//   A[b,k] = LF[b,i]*AF[b,h] (k=i*128+h, folded to bf16 at stage time)
//   A[b,8192+h] = AF[b,h]
//   W given transposed+prescaled in WT (bf16).
// BM=128, BN=64, BK=64, 4 waves (2x2), wave-tile 64x32, mfma 16x16x32 bf16.
// LDS padded to 72 shorts (144B stride -> 2-way bank aliasing = free).
// T14 prefetch: global->reg issued before compute, ds_write + 1 barrier/chunk.
// ---------------------------------------------------------------------------
__global__ __launch_bounds__(256, 1)
void out_gemm_mfma(const float* __restrict__ AFw, const float* __restrict__ LFw,
                   const ushort* __restrict__ WT, const float* __restrict__ bg,
                   float* __restrict__ out)
{
    __shared__ __align__(16) ushort As[2][128][72];
    __shared__ __align__(16) ushort Bs[2][64][72];

    const int t = threadIdx.x;
    const int b0 = blockIdx.x * 128, o0 = blockIdx.y * 64;
    const int w = t >> 6, l = t & 63;
    const int wm = w >> 1, wn = w & 1;
    const int lr = l & 15, lg = l >> 4;

    // staging maps
    const int arow = t >> 1, asub = t & 1;       // A: 2 thr/row, 32 k each
    const int brow = t >> 2, bq = t & 3;         // B: 4 thr/row, 16 k each

    f32x4 acc[4][2];
    #pragma unroll
    for (int mi = 0; mi < 4; ++mi)
        #pragma unroll
        for (int ni = 0; ni < 2; ++ni)
            acc[mi][ni] = (f32x4){0.f, 0.f, 0.f, 0.f};

    float4 ra[8]; float rs; uint4 rb[2];

    auto stage_load = [&](int c) {
        const bool mn = (c < 128);
        const int h0 = mn ? ((c & 1) << 6) : ((c - 128) << 6);
        const float4* AF4 = reinterpret_cast<const float4*>(
            &AFw[(size_t)(b0 + arow) * NH + h0 + asub * 32]);
        #pragma unroll
        for (int g = 0; g < 8; ++g) ra[g] = AF4[g];
        rs = mn ? LFw[(size_t)(b0 + arow) * DIN + (c >> 1)] : 1.0f;
        const uint4* W4 = reinterpret_cast<const uint4*>(
            &WT[(size_t)(o0 + brow) * WT_STRIDE + c * 64 + bq * 16]);
        rb[0] = W4[0];
        rb[1] = W4[1];
    };
    auto stage_write = [&](int buf) {
        #pragma unroll
        for (int g = 0; g < 4; ++g) {
            float4 f0 = ra[2 * g], f1 = ra[2 * g + 1];
            uint4 wv;
            wv.x = bf16pair(f0.x * rs, f0.y * rs);
            wv.y = bf16pair(f0.z * rs, f0.w * rs);
            wv.z = bf16pair(f1.x * rs, f1.y * rs);
            wv.w = bf16pair(f1.z * rs, f1.w * rs);
            *reinterpret_cast<uint4*>(&As[buf][arow][asub * 32 + g * 8]) = wv;
        }
        *reinterpret_cast<uint4*>(&Bs[buf][brow][bq * 16])     = rb[0];
        *reinterpret_cast<uint4*>(&Bs[buf][brow][bq * 16 + 8]) = rb[1];
    };
    auto compute = [&](int buf) {
        #pragma unroll
        for (int ks = 0; ks < 2; ++ks) {
            const int koff = ks * 32 + lg * 8;
            short8 a0 = *reinterpret_cast<const short8*>(&As[buf][wm * 64 +  0 + lr][koff]);
            short8 a1 = *reinterpret_cast<const short8*>(&As[buf][wm * 64 + 16 + lr][koff]);
            short8 a2 = *reinterpret_cast<const short8*>(&As[buf][wm * 64 + 32 + lr][koff]);
            short8 a3 = *reinterpret_cast<const short8*>(&As[buf][wm * 64 + 48 + lr][koff]);
            short8 b0v = *reinterpret_cast<const short8*>(&Bs[buf][wn * 32 +  0 + lr][koff]);
            short8 b1v = *reinterpret_cast<const short8*>(&Bs[buf][wn * 32 + 16 + lr][koff]);
            acc[0][0] = __builtin_amdgcn_mfma_f32_16x16x32_bf16(a0, b0v, acc[0][0], 0, 0, 0);
            acc[1][0] = __builtin_amdgcn_mfma_f32_16x16x32_bf16(a1, b0v, acc[1][0], 0, 0, 0);
            acc[2][0] = __builtin_amdgcn_mfma_f32_16x16x32_bf16(a2, b0v, acc[2][0], 0, 0, 0);
            acc[3][0] = __builtin_amdgcn_mfma_f32_16x16x32_bf16(a3, b0v, acc[3][0], 0, 0, 0);
            acc[0][1] = __builtin_amdgcn_mfma_f32_16x16x32_bf16(a0, b1v, acc[0][1], 0, 0, 0);
            acc[1][1] = __builtin_amdgcn_mfma_f32_16x16x32_bf16(a1, b1v, acc[1][1], 0, 0, 0);
            acc[2][1] = __builtin_amdgcn_mfma_f32_16x16x32_bf16(a2, b1v, acc[2][1], 0, 0, 0);
            acc[3][1] = __builtin_amdgcn_mfma_f32_16x16x32_bf16(a3, b1v, acc[3][1], 0, 0, 0);
        }
    };

    stage_load(0);
    stage_write(0);
    __syncthreads();
    for (int c = 0; c < 130; ++c) {
        if (c < 129) stage_load(c + 1);     // global loads fly during compute
        compute(c & 1);
        if (c < 129) {
            stage_write((c + 1) & 1);
            __syncthreads();
        }
    }

    // epilogue: bias + store
    #pragma unroll
    for (int ni = 0; ni < 2; ++ni) {
        const int col = o0 + wn * 32 + ni * 16 + lr;
        const float bb = bg[col];
        #pragma unroll
        for (int mi = 0; mi < 4; ++mi) {
            #pragma unroll
            for (int r = 0; r < 4; ++r) {
                int row = b0 + wm * 64 + mi * 16 + lg * 4 + r;
                out[(size_t)row * DOUT + col] = acc[mi][ni][r] + bb;
            }
        }
    }
}

// ---------------------------------------------------------------------------
// Workspace layout (bytes):
//   [0,        2097152)   AF  : float[4096][128]
//   [2097152,  3145728)   LF  : float[4096][64]
//   [3145728, +8519680)   WT  : ushort[512][8320]   (bf16 of relu(K)*u, + e)
// Total ~11.7 MB. Fully rewritten before use each launch -> deterministic.
// ---------------------------------------------------------------------------
extern "C" void kernel_launch(void* const* d_in, const int* in_sizes, int n_in,
                              void* d_out, int out_size, void* d_ws, size_t ws_size,
                              hipStream_t stream)
{
    const float* LT   = (const float*)d_in[0];
    const float* Kg   = (const float*)d_in[1];
    const float* AT   = (const float*)d_in[2];
    const float* ug   = (const float*)d_in[3];
    const float* eg   = (const float*)d_in[4];
    const float* bg   = (const float*)d_in[5];
    const int*   msp  = (const int*)d_in[6];
    float* out = (float*)d_out;

    char* ws = (char*)d_ws;
    float*  AFw = (float*)(ws);
    float*  LFw = (float*)(ws + 2097152);
    ushort* WTw = (ushort*)(ws + 3145728);

    solve_kernel<<<dim3(NB), dim3(256), 0, stream>>>(LT, Kg, AT, msp, AFw, LFw);
    prep_wt<<<dim3(130, 8), dim3(256), 0, stream>>>(Kg, ug, eg, WTw);

    dim3 g2(B_ROWS / 128, DOUT / 64);
    out_gemm_mfma<<<g2, dim3(256), 0, stream>>>(AFw, LFw, WTw, bg, out);
}

// Round 4
// 399.102 us; speedup vs baseline: 3.1760x; 1.1542x over previous
//
#include <hip/hip_runtime.h>

// Problem constants
#define B_ROWS 4096
#define DIN 64
#define NH 128
#define DOUT 512
#define ROWS_PER_BLK 16
#define MAXSTEP_CAP 1000
#define KTOT 8320          // 8192 main + 128 e-term
#define WT_STRIDE 8320

typedef __attribute__((ext_vector_type(8))) short short8;
typedef __attribute__((ext_vector_type(4))) float f32x4;

// round-to-nearest-even f32 -> bf16, packed pair into a uint
__device__ inline unsigned bf16pair(float lo, float hi) {
    unsigned a = __float_as_uint(lo), b = __float_as_uint(hi);
    a = (a + 0x7fffu + ((a >> 16) & 1u)) >> 16;
    b = (b + 0x7fffu + ((b >> 16) & 1u)) >> 16;
    return a | (b << 16);
}

__device__ inline float frcp(float x) { return __builtin_amdgcn_rcpf(x); }

// ---------------------------------------------------------------------------
// Kernel A: fixed-point solve, SPLIT INTO TWO INDEPENDENT CHAINS.
// Reference body:
//   Ldi = LT/(K@AF+1); AF' = AT/(K^T@Ldi+1)   <- depends only on AF
//   Adi = AT/(K^T@LF+1); LF' = LT/(K@Adi+1)   <- depends only on LF
// Blocks 0..255: AF-chain (16 rows each). Blocks 256..511: LF-chain.
// Per-block local convergence at 5e-5 per chain (sum <= old 1e-4 combined;
// contraction rho~0.45 bounds deviation from the reference's global-stop
// state well under threshold — validated rounds 2-3 at absmax 0.25).
// LDS ~50KB -> 2 blocks/CU -> 2 waves/SIMD (was 1: VALUBusy 46%).
// K stored once row-major; column access Ks[i][lane] is lane-consecutive
// (conflict-free b32); row access via b128 (2-way alias only).
// ---------------------------------------------------------------------------
__global__ __launch_bounds__(256, 2)
void solve_chain(const float* __restrict__ LT, const float* __restrict__ Kg,
                 const float* __restrict__ AT, const int* __restrict__ msp,
                 float* __restrict__ AFout, float* __restrict__ LFout)
{
    __shared__ float Ks[DIN][132];   // 33.8 KB
    __shared__ float sX[16][NH];     // state broadcast (AF or LF)
    __shared__ float sY[16][NH];     // intermediate (Ldi or Adi)
    __shared__ float wred[4];

    const int tid = threadIdx.x;
    const int lane = tid & 63, w = tid >> 6;
    const int bid = blockIdx.x & 255;
    const bool isL = blockIdx.x >= 256;

    for (int idx = tid; idx < DIN * NH; idx += 256) {
        int i = idx >> 7, h = idx & 127;
        Ks[i][h] = fmaxf(Kg[idx], 0.0f);   // _st_relu forward == relu
    }
    const float at0 = fmaxf(AT[lane], 0.0f);
    const float at1 = fmaxf(AT[64 + lane], 0.0f);
    int max_step = *msp;
    if (max_step > MAXSTEP_CAP) max_step = MAXSTEP_CAP;

    float lt[4];
    #pragma unroll
    for (int r = 0; r < 4; ++r) {
        int row = bid * ROWS_PER_BLK + (w << 2) + r;
        lt[r] = LT[row * DIN + lane];
    }
    __syncthreads();

    if (!isL) {
        // ============== AF-chain: state af0/af1 (h=lane, h=64+lane) ==========
        float af0[4] = {0.f,0.f,0.f,0.f}, af1[4] = {0.f,0.f,0.f,0.f};

        auto body = [&](float* pmax) {
            #pragma unroll
            for (int r = 0; r < 4; ++r) {
                int s = (w << 2) + r;
                sX[s][lane] = af0[r];
                sX[s][64 + lane] = af1[r];
            }
            __syncthreads();
            // P1 row-dot (lane = i): Ldi[r,i] = lt/(sum_h K[i,h]*AF[r,h] + 1)
            float s1[4] = {0.f,0.f,0.f,0.f};
            const f32x4* Kr4 = reinterpret_cast<const f32x4*>(&Ks[lane][0]);
            #pragma unroll 8
            for (int c = 0; c < 32; ++c) {
                f32x4 k4 = Kr4[c];
                #pragma unroll
                for (int r = 0; r < 4; ++r) {
                    f32x4 a4 = *reinterpret_cast<const f32x4*>(&sX[(w << 2) + r][c << 2]);
                    s1[r] += k4[0]*a4[0] + k4[1]*a4[1] + k4[2]*a4[2] + k4[3]*a4[3];
                }
            }
            #pragma unroll
            for (int r = 0; r < 4; ++r)
                sY[(w << 2) + r][lane] = lt[r] * frcp(s1[r] + 1.0f);
            __syncthreads();
            // P2 col-dot (h = lane, 64+lane): AF'[r,h] = at/(sum_i K[i,h]*Ldi[r,i]+1)
            float s2a[4] = {0.f,0.f,0.f,0.f}, s2b[4] = {0.f,0.f,0.f,0.f};
            #pragma unroll 4
            for (int i4 = 0; i4 < 16; ++i4) {
                f32x4 yb[4];
                #pragma unroll
                for (int r = 0; r < 4; ++r)
                    yb[r] = *reinterpret_cast<const f32x4*>(&sY[(w << 2) + r][i4 << 2]);
                #pragma unroll
                for (int j = 0; j < 4; ++j) {
                    int i = (i4 << 2) + j;
                    float k0 = Ks[i][lane], k1 = Ks[i][64 + lane];
                    #pragma unroll
                    for (int r = 0; r < 4; ++r) {
                        s2a[r] += k0 * yb[r][j];
                        s2b[r] += k1 * yb[r][j];
                    }
                }
            }
            #pragma unroll
            for (int r = 0; r < 4; ++r) {
                float a0 = at0 * frcp(s2a[r] + 1.0f);
                float a1 = at1 * frcp(s2b[r] + 1.0f);
                if (pmax) {
                    *pmax = fmaxf(*pmax, fabsf(a0 - af0[r]) * frcp(af0[r] + 1e-5f));
                    *pmax = fmaxf(*pmax, fabsf(a1 - af1[r]) * frcp(af1[r] + 1e-5f));
                }
                af0[r] = a0; af1[r] = a1;
            }
        };

        int step = 0;
        bool done = false;
        while (step < max_step && !done) {
            float maxd = 0.0f;
            body(&maxd);
            #pragma unroll
            for (int off = 32; off; off >>= 1)
                maxd = fmaxf(maxd, __shfl_xor(maxd, off));
            if (lane == 0) wred[w] = maxd;
            __syncthreads();
            done = fmaxf(fmaxf(wred[0], wred[1]), fmaxf(wred[2], wred[3])) < 5e-5f;
            ++step;
        }
        body(nullptr);   // final refinement (reference post-loop update)

        #pragma unroll
        for (int r = 0; r < 4; ++r) {
            int row = bid * ROWS_PER_BLK + (w << 2) + r;
            AFout[row * NH + lane]      = af0[r];
            AFout[row * NH + 64 + lane] = af1[r];
        }
    } else {
        // ============== LF-chain: state lf (i=lane) ==========================
        float lf[4] = {0.f,0.f,0.f,0.f};

        auto body = [&](float* pmax) {
            #pragma unroll
            for (int r = 0; r < 4; ++r)
                sX[(w << 2) + r][lane] = lf[r];
            __syncthreads();
            // P1 col-dot (h = lane, 64+lane): Adi[r,h] = at/(sum_i K[i,h]*LF[r,i]+1)
            float s3a[4] = {0.f,0.f,0.f,0.f}, s3b[4] = {0.f,0.f,0.f,0.f};
            #pragma unroll 4
            for (int i4 = 0; i4 < 16; ++i4) {
                f32x4 xb[4];
                #pragma unroll
                for (int r = 0; r < 4; ++r)
                    xb[r] = *reinterpret_cast<const f32x4*>(&sX[(w << 2) + r][i4 << 2]);
                #pragma unroll
                for (int j = 0; j < 4; ++j) {
                    int i = (i4 << 2) + j;
                    float k0 = Ks[i][lane], k1 = Ks[i][64 + lane];
                    #pragma unroll
                    for (int r = 0; r < 4; ++r) {
                        s3a[r] += k0 * xb[r][j];
                        s3b[r] += k1 * xb[r][j];
                    }
                }
            }
            #pragma unroll
            for (int r = 0; r < 4; ++r) {
                int s = (w << 2) + r;
                sY[s][lane]      = at0 * frcp(s3a[r] + 1.0f);
                sY[s][64 + lane] = at1 * frcp(s3b[r] + 1.0f);
            }
            __syncthreads();
            // P2 row-dot (lane = i): LF'[r,i] = lt/(sum_h K[i,h]*Adi[r,h]+1)
            float s4[4] = {0.f,0.f,0.f,0.f};
            const f32x4* Kr4 = reinterpret_cast<const f32x4*>(&Ks[lane][0]);
            #pragma unroll 8
            for (int c = 0; c < 32; ++c) {
                f32x4 k4 = Kr4[c];
                #pragma unroll
                for (int r = 0; r < 4; ++r) {
                    f32x4 a4 = *reinterpret_cast<const f32x4*>(&sY[(w << 2) + r][c << 2]);
                    s4[r] += k4[0]*a4[0] + k4[1]*a4[1] + k4[2]*a4[2] + k4[3]*a4[3];
                }
            }
            #pragma unroll
            for (int r = 0; r < 4; ++r) {
                float ln = lt[r] * frcp(s4[r] + 1.0f);
                if (pmax)
                    *pmax = fmaxf(*pmax, fabsf(ln - lf[r]) * frcp(lf[r] + 1e-5f));
                lf[r] = ln;
            }
        };

        int step = 0;
        bool done = false;
        while (step < max_step && !done) {
            float maxd = 0.0f;
            body(&maxd);
            #pragma unroll
            for (int off = 32; off; off >>= 1)
                maxd = fmaxf(maxd, __shfl_xor(maxd, off));
            if (lane == 0) wred[w] = maxd;
            __syncthreads();
            done = fmaxf(fmaxf(wred[0], wred[1]), fmaxf(wred[2], wred[3])) < 5e-5f;
            ++step;
        }
        body(nullptr);   // final refinement

        #pragma unroll
        for (int r = 0; r < 4; ++r) {
            int row = bid * ROWS_PER_BLK + (w << 2) + r;
            LFout[row * DIN + lane] = lf[r];
        }
    }
}

// ---------------------------------------------------------------------------
// Kernel P: W_T[o][k] = bf16( relu(K[k]) * u[k][o] ) for k < 8192
//           W_T[o][8192+h] = bf16( e[h][o] )
// 64x64 tiles, LDS transpose. Grid (130, 8). Unchanged from round 3.
// ---------------------------------------------------------------------------
__global__ __launch_bounds__(256, 1)
void prep_wt(const float* __restrict__ Kg, const float* __restrict__ ug,
             const float* __restrict__ eg, ushort* __restrict__ WT)
{
    __shared__ float tile[64][68];
    const int t = threadIdx.x;
    const int k0 = blockIdx.x * 64;
    const int o0 = blockIdx.y * 64;
    const bool is_main = (k0 < 8192);
    const int r0 = t >> 4, c4 = (t & 15) << 2;
    #pragma unroll
    for (int p = 0; p < 4; ++p) {
        int r = r0 + (p << 4);
        float4 v;
        if (is_main) {
            float kv = fmaxf(Kg[k0 + r], 0.0f);
            v = *reinterpret_cast<const float4*>(&ug[(size_t)(k0 + r) * DOUT + o0 + c4]);
            v.x *= kv; v.y *= kv; v.z *= kv; v.w *= kv;
        } else {
            v = *reinterpret_cast<const float4*>(&eg[(size_t)(k0 - 8192 + r) * DOUT + o0 + c4]);
        }
        *reinterpret_cast<float4*>(&tile[r][c4]) = v;
    }
    __syncthreads();
    const int o = t >> 2, q = t & 3;
    #pragma unroll
    for (int j = 0; j < 2; ++j) {
        int kb = (q << 4) + (j << 3);
        uint4 u4;
        u4.x = bf16pair(tile[kb + 0][o], tile[kb + 1][o]);
        u4.y = bf16pair(tile[kb + 2][o], tile[kb + 3][o]);
        u4.z = bf16pair(tile[kb + 4][o], tile[kb + 5][o]);
        u4.w = bf16pair(tile[kb + 6][o], tile[kb + 7][o]);
        *reinterpret_cast<uint4*>(&WT[(size_t)(o0 + o) * WT_STRIDE + k0 + kb]) = u4;
    }
}

// ---------------------------------------------------------------------------
// Kernel B: bf16 MFMA GEMM. Unchanged from round 3 (passed, ~? us — counters
// next round). out[b,o] = sum_k A[b,k]*W[k,o] + bias[o].
// ---------------------------------------------------------------------------
__global__ __launch_bounds__(256, 1)
void out_gemm_mfma(const float* __restrict__ AFw, const float* __restrict__ LFw,
                   const ushort* __restrict__ WT, const float* __restrict__ bg,
                   float* __restrict__ out)
{
    __shared__ __align__(16) ushort As[2][128][72];
    __shared__ __align__(16) ushort Bs[2][64][72];

    const int t = threadIdx.x;
    const int b0 = blockIdx.x * 128, o0 = blockIdx.y * 64;
    const int w = t >> 6, l = t & 63;
    const int wm = w >> 1, wn = w & 1;
    const int lr = l & 15, lg = l >> 4;

    const int arow = t >> 1, asub = t & 1;
    const int brow = t >> 2, bq = t & 3;

    f32x4 acc[4][2];
    #pragma unroll
    for (int mi = 0; mi < 4; ++mi)
        #pragma unroll
        for (int ni = 0; ni < 2; ++ni)
            acc[mi][ni] = (f32x4){0.f, 0.f, 0.f, 0.f};

    float4 ra[8]; float rs; uint4 rb[2];

    auto stage_load = [&](int c) {
        const bool mn = (c < 128);
        const int h0 = mn ? ((c & 1) << 6) : ((c - 128) << 6);
        const float4* AF4 = reinterpret_cast<const float4*>(
            &AFw[(size_t)(b0 + arow) * NH + h0 + asub * 32]);
        #pragma unroll
        for (int g = 0; g < 8; ++g) ra[g] = AF4[g];
        rs = mn ? LFw[(size_t)(b0 + arow) * DIN + (c >> 1)] : 1.0f;
        const uint4* W4 = reinterpret_cast<const uint4*>(
            &WT[(size_t)(o0 + brow) * WT_STRIDE + c * 64 + bq * 16]);
        rb[0] = W4[0];
        rb[1] = W4[1];
    };
    auto stage_write = [&](int buf) {
        #pragma unroll
        for (int g = 0; g < 4; ++g) {
            float4 f0 = ra[2 * g], f1 = ra[2 * g + 1];
            uint4 wv;
            wv.x = bf16pair(f0.x * rs, f0.y * rs);
            wv.y = bf16pair(f0.z * rs, f0.w * rs);
            wv.z = bf16pair(f1.x * rs, f1.y * rs);
            wv.w = bf16pair(f1.z * rs, f1.w * rs);
            *reinterpret_cast<uint4*>(&As[buf][arow][asub * 32 + g * 8]) = wv;
        }
        *reinterpret_cast<uint4*>(&Bs[buf][brow][bq * 16])     = rb[0];
        *reinterpret_cast<uint4*>(&Bs[buf][brow][bq * 16 + 8]) = rb[1];
    };
    auto compute = [&](int buf) {
        #pragma unroll
        for (int ks = 0; ks < 2; ++ks) {
            const int koff = ks * 32 + lg * 8;
            short8 a0 = *reinterpret_cast<const short8*>(&As[buf][wm * 64 +  0 + lr][koff]);
            short8 a1 = *reinterpret_cast<const short8*>(&As[buf][wm * 64 + 16 + lr][koff]);
            short8 a2 = *reinterpret_cast<const short8*>(&As[buf][wm * 64 + 32 + lr][koff]);
            short8 a3 = *reinterpret_cast<const short8*>(&As[buf][wm * 64 + 48 + lr][koff]);
            short8 b0v = *reinterpret_cast<const short8*>(&Bs[buf][wn * 32 +  0 + lr][koff]);
            short8 b1v = *reinterpret_cast<const short8*>(&Bs[buf][wn * 32 + 16 + lr][koff]);
            acc[0][0] = __builtin_amdgcn_mfma_f32_16x16x32_bf16(a0, b0v, acc[0][0], 0, 0, 0);
            acc[1][0] = __builtin_amdgcn_mfma_f32_16x16x32_bf16(a1, b0v, acc[1][0], 0, 0, 0);
            acc[2][0] = __builtin_amdgcn_mfma_f32_16x16x32_bf16(a2, b0v, acc[2][0], 0, 0, 0);
            acc[3][0] = __builtin_amdgcn_mfma_f32_16x16x32_bf16(a3, b0v, acc[3][0], 0, 0, 0);
            acc[0][1] = __builtin_amdgcn_mfma_f32_16x16x32_bf16(a0, b1v, acc[0][1], 0, 0, 0);
            acc[1][1] = __builtin_amdgcn_mfma_f32_16x16x32_bf16(a1, b1v, acc[1][1], 0, 0, 0);
            acc[2][1] = __builtin_amdgcn_mfma_f32_16x16x32_bf16(a2, b1v, acc[2][1], 0, 0, 0);
            acc[3][1] = __builtin_amdgcn_mfma_f32_16x16x32_bf16(a3, b1v, acc[3][1], 0, 0, 0);
        }
    };

    stage_load(0);
    stage_write(0);
    __syncthreads();
    for (int c = 0; c < 130; ++c) {
        if (c < 129) stage_load(c + 1);
        compute(c & 1);
        if (c < 129) {
            stage_write((c + 1) & 1);
            __syncthreads();
        }
    }

    #pragma unroll
    for (int ni = 0; ni < 2; ++ni) {
        const int col = o0 + wn * 32 + ni * 16 + lr;
        const float bb = bg[col];
        #pragma unroll
        for (int mi = 0; mi < 4; ++mi) {
            #pragma unroll
            for (int r = 0; r < 4; ++r) {
                int row = b0 + wm * 64 + mi * 16 + lg * 4 + r;
                out[(size_t)row * DOUT + col] = acc[mi][ni][r] + bb;
            }
        }
    }
}

// ---------------------------------------------------------------------------
// Workspace layout (bytes):
//   [0,        2097152)   AF  : float[4096][128]
//   [2097152,  3145728)   LF  : float[4096][64]
//   [3145728, +8519680)   WT  : ushort[512][8320]   (bf16 of relu(K)*u, + e)
// Fully rewritten before use each launch -> deterministic.
// ---------------------------------------------------------------------------
extern "C" void kernel_launch(void* const* d_in, const int* in_sizes, int n_in,
                              void* d_out, int out_size, void* d_ws, size_t ws_size,
                              hipStream_t stream)
{
    const float* LT   = (const float*)d_in[0];
    const float* Kg   = (const float*)d_in[1];
    const float* AT   = (const float*)d_in[2];
    const float* ug   = (const float*)d_in[3];
    const float* eg   = (const float*)d_in[4];
    const float* bg   = (const float*)d_in[5];
    const int*   msp  = (const int*)d_in[6];
    float* out = (float*)d_out;

    char* ws = (char*)d_ws;
    float*  AFw = (float*)(ws);
    float*  LFw = (float*)(ws + 2097152);
    ushort* WTw = (ushort*)(ws + 3145728);

    solve_chain<<<dim3(512), dim3(256), 0, stream>>>(LT, Kg, AT, msp, AFw, LFw);
    prep_wt<<<dim3(130, 8), dim3(256), 0, stream>>>(Kg, ug, eg, WTw);

    dim3 g2(B_ROWS / 128, DOUT / 64);
    out_gemm_mfma<<<g2, dim3(256), 0, stream>>>(AFw, LFw, WTw, bg, out);
}

// Round 5
// 311.080 us; speedup vs baseline: 4.0746x; 1.2830x over previous
//
#include <hip/hip_runtime.h>

// Problem constants
#define B_ROWS 4096
#define DIN 64
#define NH 128
#define DOUT 512
#define ROWS_PER_BLK 16
#define MAXSTEP_CAP 1000
#define KTOT 8320          // 8192 main + 128 e-term
#define WT_STRIDE 8320

typedef __attribute__((ext_vector_type(8))) short short8;
typedef __attribute__((ext_vector_type(4))) float f32x4;

// round-to-nearest-even f32 -> bf16, packed pair into a uint
__device__ inline unsigned bf16pair(float lo, float hi) {
    unsigned a = __float_as_uint(lo), b = __float_as_uint(hi);
    a = (a + 0x7fffu + ((a >> 16) & 1u)) >> 16;
    b = (b + 0x7fffu + ((b >> 16) & 1u)) >> 16;
    return a | (b << 16);
}

__device__ inline float frcp(float x) { return __builtin_amdgcn_rcpf(x); }

// ---------------------------------------------------------------------------
// Kernel A: fixed-point solve, two independent chains (unchanged, round 4:
// ~135 us). Blocks 0..255: AF-chain; 256..511: LF-chain. Local tol 5e-5.
// ---------------------------------------------------------------------------
__global__ __launch_bounds__(256, 2)
void solve_chain(const float* __restrict__ LT, const float* __restrict__ Kg,
                 const float* __restrict__ AT, const int* __restrict__ msp,
                 float* __restrict__ AFout, float* __restrict__ LFout)
{
    __shared__ float Ks[DIN][132];
    __shared__ float sX[16][NH];
    __shared__ float sY[16][NH];
    __shared__ float wred[4];

    const int tid = threadIdx.x;
    const int lane = tid & 63, w = tid >> 6;
    const int bid = blockIdx.x & 255;
    const bool isL = blockIdx.x >= 256;

    for (int idx = tid; idx < DIN * NH; idx += 256) {
        int i = idx >> 7, h = idx & 127;
        Ks[i][h] = fmaxf(Kg[idx], 0.0f);
    }
    const float at0 = fmaxf(AT[lane], 0.0f);
    const float at1 = fmaxf(AT[64 + lane], 0.0f);
    int max_step = *msp;
    if (max_step > MAXSTEP_CAP) max_step = MAXSTEP_CAP;

    float lt[4];
    #pragma unroll
    for (int r = 0; r < 4; ++r) {
        int row = bid * ROWS_PER_BLK + (w << 2) + r;
        lt[r] = LT[row * DIN + lane];
    }
    __syncthreads();

    if (!isL) {
        float af0[4] = {0.f,0.f,0.f,0.f}, af1[4] = {0.f,0.f,0.f,0.f};

        auto body = [&](float* pmax) {
            #pragma unroll
            for (int r = 0; r < 4; ++r) {
                int s = (w << 2) + r;
                sX[s][lane] = af0[r];
                sX[s][64 + lane] = af1[r];
            }
            __syncthreads();
            float s1[4] = {0.f,0.f,0.f,0.f};
            const f32x4* Kr4 = reinterpret_cast<const f32x4*>(&Ks[lane][0]);
            #pragma unroll 8
            for (int c = 0; c < 32; ++c) {
                f32x4 k4 = Kr4[c];
                #pragma unroll
                for (int r = 0; r < 4; ++r) {
                    f32x4 a4 = *reinterpret_cast<const f32x4*>(&sX[(w << 2) + r][c << 2]);
                    s1[r] += k4[0]*a4[0] + k4[1]*a4[1] + k4[2]*a4[2] + k4[3]*a4[3];
                }
            }
            #pragma unroll
            for (int r = 0; r < 4; ++r)
                sY[(w << 2) + r][lane] = lt[r] * frcp(s1[r] + 1.0f);
            __syncthreads();
            float s2a[4] = {0.f,0.f,0.f,0.f}, s2b[4] = {0.f,0.f,0.f,0.f};
            #pragma unroll 4
            for (int i4 = 0; i4 < 16; ++i4) {
                f32x4 yb[4];
                #pragma unroll
                for (int r = 0; r < 4; ++r)
                    yb[r] = *reinterpret_cast<const f32x4*>(&sY[(w << 2) + r][i4 << 2]);
                #pragma unroll
                for (int j = 0; j < 4; ++j) {
                    int i = (i4 << 2) + j;
                    float k0 = Ks[i][lane], k1 = Ks[i][64 + lane];
                    #pragma unroll
                    for (int r = 0; r < 4; ++r) {
                        s2a[r] += k0 * yb[r][j];
                        s2b[r] += k1 * yb[r][j];
                    }
                }
            }
            #pragma unroll
            for (int r = 0; r < 4; ++r) {
                float a0 = at0 * frcp(s2a[r] + 1.0f);
                float a1 = at1 * frcp(s2b[r] + 1.0f);
                if (pmax) {
                    *pmax = fmaxf(*pmax, fabsf(a0 - af0[r]) * frcp(af0[r] + 1e-5f));
                    *pmax = fmaxf(*pmax, fabsf(a1 - af1[r]) * frcp(af1[r] + 1e-5f));
                }
                af0[r] = a0; af1[r] = a1;
            }
        };

        int step = 0;
        bool done = false;
        while (step < max_step && !done) {
            float maxd = 0.0f;
            body(&maxd);
            #pragma unroll
            for (int off = 32; off; off >>= 1)
                maxd = fmaxf(maxd, __shfl_xor(maxd, off));
            if (lane == 0) wred[w] = maxd;
            __syncthreads();
            done = fmaxf(fmaxf(wred[0], wred[1]), fmaxf(wred[2], wred[3])) < 5e-5f;
            ++step;
        }
        body(nullptr);

        #pragma unroll
        for (int r = 0; r < 4; ++r) {
            int row = bid * ROWS_PER_BLK + (w << 2) + r;
            AFout[row * NH + lane]      = af0[r];
            AFout[row * NH + 64 + lane] = af1[r];
        }
    } else {
        float lf[4] = {0.f,0.f,0.f,0.f};

        auto body = [&](float* pmax) {
            #pragma unroll
            for (int r = 0; r < 4; ++r)
                sX[(w << 2) + r][lane] = lf[r];
            __syncthreads();
            float s3a[4] = {0.f,0.f,0.f,0.f}, s3b[4] = {0.f,0.f,0.f,0.f};
            #pragma unroll 4
            for (int i4 = 0; i4 < 16; ++i4) {
                f32x4 xb[4];
                #pragma unroll
                for (int r = 0; r < 4; ++r)
                    xb[r] = *reinterpret_cast<const f32x4*>(&sX[(w << 2) + r][i4 << 2]);
                #pragma unroll
                for (int j = 0; j < 4; ++j) {
                    int i = (i4 << 2) + j;
                    float k0 = Ks[i][lane], k1 = Ks[i][64 + lane];
                    #pragma unroll
                    for (int r = 0; r < 4; ++r) {
                        s3a[r] += k0 * xb[r][j];
                        s3b[r] += k1 * xb[r][j];
                    }
                }
            }
            #pragma unroll
            for (int r = 0; r < 4; ++r) {
                int s = (w << 2) + r;
                sY[s][lane]      = at0 * frcp(s3a[r] + 1.0f);
                sY[s][64 + lane] = at1 * frcp(s3b[r] + 1.0f);
            }
            __syncthreads();
            float s4[4] = {0.f,0.f,0.f,0.f};
            const f32x4* Kr4 = reinterpret_cast<const f32x4*>(&Ks[lane][0]);
            #pragma unroll 8
            for (int c = 0; c < 32; ++c) {
                f32x4 k4 = Kr4[c];
                #pragma unroll
                for (int r = 0; r < 4; ++r) {
                    f32x4 a4 = *reinterpret_cast<const f32x4*>(&sY[(w << 2) + r][c << 2]);
                    s4[r] += k4[0]*a4[0] + k4[1]*a4[1] + k4[2]*a4[2] + k4[3]*a4[3];
                }
            }
            #pragma unroll
            for (int r = 0; r < 4; ++r) {
                float ln = lt[r] * frcp(s4[r] + 1.0f);
                if (pmax)
                    *pmax = fmaxf(*pmax, fabsf(ln - lf[r]) * frcp(lf[r] + 1e-5f));
                lf[r] = ln;
            }
        };

        int step = 0;
        bool done = false;
        while (step < max_step && !done) {
            float maxd = 0.0f;
            body(&maxd);
            #pragma unroll
            for (int off = 32; off; off >>= 1)
                maxd = fmaxf(maxd, __shfl_xor(maxd, off));
            if (lane == 0) wred[w] = maxd;
            __syncthreads();
            done = fmaxf(fmaxf(wred[0], wred[1]), fmaxf(wred[2], wred[3])) < 5e-5f;
            ++step;
        }
        body(nullptr);

        #pragma unroll
        for (int r = 0; r < 4; ++r) {
            int row = bid * ROWS_PER_BLK + (w << 2) + r;
            LFout[row * DIN + lane] = lf[r];
        }
    }
}

// ---------------------------------------------------------------------------
// Kernel P: W_T[o][k] = bf16( relu(K[k]) * u[k][o] ), e appended at k>=8192.
// Unchanged from round 3.
// ---------------------------------------------------------------------------
__global__ __launch_bounds__(256, 1)
void prep_wt(const float* __restrict__ Kg, const float* __restrict__ ug,
             const float* __restrict__ eg, ushort* __restrict__ WT)
{
    __shared__ float tile[64][68];
    const int t = threadIdx.x;
    const int k0 = blockIdx.x * 64;
    const int o0 = blockIdx.y * 64;
    const bool is_main = (k0 < 8192);
    const int r0 = t >> 4, c4 = (t & 15) << 2;
    #pragma unroll
    for (int p = 0; p < 4; ++p) {
        int r = r0 + (p << 4);
        float4 v;
        if (is_main) {
            float kv = fmaxf(Kg[k0 + r], 0.0f);
            v = *reinterpret_cast<const float4*>(&ug[(size_t)(k0 + r) * DOUT + o0 + c4]);
            v.x *= kv; v.y *= kv; v.z *= kv; v.w *= kv;
        } else {
            v = *reinterpret_cast<const float4*>(&eg[(size_t)(k0 - 8192 + r) * DOUT + o0 + c4]);
        }
        *reinterpret_cast<float4*>(&tile[r][c4]) = v;
    }
    __syncthreads();
    const int o = t >> 2, q = t & 3;
    #pragma unroll
    for (int j = 0; j < 2; ++j) {
        int kb = (q << 4) + (j << 3);
        uint4 u4;
        u4.x = bf16pair(tile[kb + 0][o], tile[kb + 1][o]);
        u4.y = bf16pair(tile[kb + 2][o], tile[kb + 3][o]);
        u4.z = bf16pair(tile[kb + 4][o], tile[kb + 5][o]);
        u4.w = bf16pair(tile[kb + 6][o], tile[kb + 7][o]);
        *reinterpret_cast<uint4*>(&WT[(size_t)(o0 + o) * WT_STRIDE + k0 + kb]) = u4;
    }
}

// ---------------------------------------------------------------------------
// Kernel B (v3, rank-1 factored):
//   out[b,o] = sum_i LF[b,i] * (sum_h AF[b,h] * W[i*128+h, o]) + e-term + bias
// BM=64, BN=64 -> grid (64,8) = 512 blocks = 2 blocks/CU (TLP!).
// 4 waves, wave-tile 32x32 (2m x 2n frags), mfma 16x16x32 bf16.
// AF staged ONCE to LDS as bf16, A-fragments then held in REGISTERS for the
// entire i-loop (no A re-staging — round-4's 130x redundant fold is gone).
// LF^T staged once (f32). Per i: double-buffered reg-staged B-tile (W_i),
// K=128 in 4 MFMA steps into a temp acc, then acc += LF[row,i] * temp.
// Iteration i==64 is the e-term (scale 1, WT rows 8192..8319).
// LDS: AFb 17.4K + LFt 17.4K + Bs 2x17.4K = 69.6 KB -> 2 blocks/CU.
// Pad 136 shorts (272B): 16 lanes reading rows at fixed k hit banks 4r%32
// -> 2-way alias only (free, m136).
// ---------------------------------------------------------------------------
__global__ __launch_bounds__(256, 2)
void out_gemm_rank1(const float* __restrict__ AFw, const float* __restrict__ LFw,
                    const ushort* __restrict__ WT, const float* __restrict__ bg,
                    float* __restrict__ out)
{
    __shared__ __align__(16) ushort AFb[64][136];
    __shared__ __align__(16) float  LFt[64][68];
    __shared__ __align__(16) ushort Bs[2][64][136];

    const int t = threadIdx.x;
    const int b0 = blockIdx.x * 64, o0 = blockIdx.y * 64;
    const int w = t >> 6, l = t & 63;
    const int wm = w >> 1, wn = w & 1;       // 2x2 wave grid
    const int lr = l & 15, lg = l >> 4;

    // ---- prologue staging: AF (bf16) + LF^T (f32), once ----
    {
        const int row = t >> 2, q = t & 3;
        const float4* srcA = reinterpret_cast<const float4*>(
            &AFw[(size_t)(b0 + row) * NH + q * 32]);
        #pragma unroll
        for (int g = 0; g < 4; ++g) {
            float4 fa = srcA[2 * g], fb = srcA[2 * g + 1];
            uint4 wv;
            wv.x = bf16pair(fa.x, fa.y); wv.y = bf16pair(fa.z, fa.w);
            wv.z = bf16pair(fb.x, fb.y); wv.w = bf16pair(fb.z, fb.w);
            *reinterpret_cast<uint4*>(&AFb[row][q * 32 + g * 8]) = wv;
        }
        const f32x4* srcL = reinterpret_cast<const f32x4*>(
            &LFw[(size_t)(b0 + row) * DIN + q * 16]);
        #pragma unroll
        for (int g = 0; g < 4; ++g) {
            f32x4 fv = srcL[g];
            #pragma unroll
            for (int j = 0; j < 4; ++j)
                LFt[q * 16 + g * 4 + j][row] = fv[j];
        }
    }

    uint4 rb[4];
    auto loadB = [&](int i) {
        const uint4* p = reinterpret_cast<const uint4*>(
            &WT[(size_t)(o0 + (t >> 2)) * WT_STRIDE + i * 128 + (t & 3) * 32]);
        #pragma unroll
        for (int g = 0; g < 4; ++g) rb[g] = p[g];
    };
    auto writeB = [&](int buf) {
        #pragma unroll
        for (int g = 0; g < 4; ++g)
            *reinterpret_cast<uint4*>(&Bs[buf][t >> 2][(t & 3) * 32 + g * 8]) = rb[g];
    };

    loadB(0);
    writeB(0);
    __syncthreads();

    // ---- hold A-fragments in registers for the whole i-loop ----
    short8 afr0[4], afr1[4];
    #pragma unroll
    for (int ks = 0; ks < 4; ++ks) {
        afr0[ks] = *reinterpret_cast<const short8*>(&AFb[wm * 32 +      lr][ks * 32 + lg * 8]);
        afr1[ks] = *reinterpret_cast<const short8*>(&AFb[wm * 32 + 16 + lr][ks * 32 + lg * 8]);
    }

    f32x4 acc00 = {0.f,0.f,0.f,0.f}, acc01 = acc00, acc10 = acc00, acc11 = acc00;

    for (int i = 0; i <= 64; ++i) {
        const int buf = i & 1;
        if (i < 64) loadB(i + 1);            // prefetch next B-tile into regs
        f32x4 t00 = {0.f,0.f,0.f,0.f}, t01 = t00, t10 = t00, t11 = t00;
        #pragma unroll
        for (int ks = 0; ks < 4; ++ks) {
            short8 bv0 = *reinterpret_cast<const short8*>(&Bs[buf][wn * 32 +      lr][ks * 32 + lg * 8]);
            short8 bv1 = *reinterpret_cast<const short8*>(&Bs[buf][wn * 32 + 16 + lr][ks * 32 + lg * 8]);
            t00 = __builtin_amdgcn_mfma_f32_16x16x32_bf16(afr0[ks], bv0, t00, 0, 0, 0);
            t10 = __builtin_amdgcn_mfma_f32_16x16x32_bf16(afr1[ks], bv0, t10, 0, 0, 0);
            t01 = __builtin_amdgcn_mfma_f32_16x16x32_bf16(afr0[ks], bv1, t01, 0, 0, 0);
            t11 = __builtin_amdgcn_mfma_f32_16x16x32_bf16(afr1[ks], bv1, t11, 0, 0, 0);
        }
        if (i < 64) {
            f32x4 lf0 = *reinterpret_cast<const f32x4*>(&LFt[i][wm * 32 +      lg * 4]);
            f32x4 lf1 = *reinterpret_cast<const f32x4*>(&LFt[i][wm * 32 + 16 + lg * 4]);
            #pragma unroll
            for (int r = 0; r < 4; ++r) {
                acc00[r] += lf0[r] * t00[r];
                acc01[r] += lf0[r] * t01[r];
                acc10[r] += lf1[r] * t10[r];
                acc11[r] += lf1[r] * t11[r];
            }
            writeB(buf ^ 1);                 // safe: others read Bs[buf]
            __syncthreads();
        } else {                             // e-term: scale 1
            #pragma unroll
            for (int r = 0; r < 4; ++r) {
                acc00[r] += t00[r];
                acc01[r] += t01[r];
                acc10[r] += t10[r];
                acc11[r] += t11[r];
            }
        }
    }

    // ---- epilogue: bias + store ----
    const int col = o0 + wn * 32 + lr;
    const float bb0 = bg[col], bb1 = bg[col + 16];
    #pragma unroll
    for (int r = 0; r < 4; ++r) {
        const int row0 = b0 + wm * 32 + lg * 4 + r;
        out[(size_t)row0 * DOUT + col]            = acc00[r] + bb0;
        out[(size_t)row0 * DOUT + col + 16]       = acc01[r] + bb1;
        out[(size_t)(row0 + 16) * DOUT + col]      = acc10[r] + bb0;
        out[(size_t)(row0 + 16) * DOUT + col + 16] = acc11[r] + bb1;
    }
}

// ---------------------------------------------------------------------------
// Workspace layout (bytes):
//   [0,        2097152)   AF  : float[4096][128]
//   [2097152,  3145728)   LF  : float[4096][64]
//   [3145728, +8519680)   WT  : ushort[512][8320]   (bf16 of relu(K)*u, + e)
// Fully rewritten before use each launch -> deterministic.
// ---------------------------------------------------------------------------
extern "C" void kernel_launch(void* const* d_in, const int* in_sizes, int n_in,
                              void* d_out, int out_size, void* d_ws, size_t ws_size,
                              hipStream_t stream)
{
    const float* LT   = (const float*)d_in[0];
    const float* Kg   = (const float*)d_in[1];
    const float* AT   = (const float*)d_in[2];
    const float* ug   = (const float*)d_in[3];
    const float* eg   = (const float*)d_in[4];
    const float* bg   = (const float*)d_in[5];
    const int*   msp  = (const int*)d_in[6];
    float* out = (float*)d_out;

    char* ws = (char*)d_ws;
    float*  AFw = (float*)(ws);
    float*  LFw = (float*)(ws + 2097152);
    ushort* WTw = (ushort*)(ws + 3145728);

    solve_chain<<<dim3(512), dim3(256), 0, stream>>>(LT, Kg, AT, msp, AFw, LFw);
    prep_wt<<<dim3(130, 8), dim3(256), 0, stream>>>(Kg, ug, eg, WTw);

    dim3 g2(B_ROWS / 64, DOUT / 64);
    out_gemm_rank1<<<g2, dim3(256), 0, stream>>>(AFw, LFw, WTw, bg, out);
}

// Round 6
// 220.909 us; speedup vs baseline: 5.7378x; 1.4082x over previous
//
#include <hip/hip_runtime.h>

// Problem constants
#define B_ROWS 4096
#define DIN 64
#define NH 128
#define DOUT 512
#define ROWS_PER_BLK 16
#define MAXSTEP_CAP 1000
#define KTOT 8320          // 8192 main + 128 e-term
#define WT_STRIDE 8320

typedef __attribute__((ext_vector_type(8))) short short8;
typedef __attribute__((ext_vector_type(4))) float f32x4;

// round-to-nearest-even f32 -> bf16, packed pair into a uint
__device__ inline unsigned bf16pair(float lo, float hi) {
    unsigned a = __float_as_uint(lo), b = __float_as_uint(hi);
    a = (a + 0x7fffu + ((a >> 16) & 1u)) >> 16;
    b = (b + 0x7fffu + ((b >> 16) & 1u)) >> 16;
    return a | (b << 16);
}

__device__ inline float frcp(float x) { return __builtin_amdgcn_rcpf(x); }

// split x (8 f32) into hi = bf16(x), lo = bf16(x - hi); quantization error
// <= 2^-18 relative — far below the 5e-5 convergence tolerance.
__device__ inline void split8v(f32x4 a, f32x4 b, short8& hi, short8& lo) {
    float x[8] = {a[0], a[1], a[2], a[3], b[0], b[1], b[2], b[3]};
    unsigned hb[8]; float rs[8];
    #pragma unroll
    for (int j = 0; j < 8; ++j) {
        unsigned u = __float_as_uint(x[j]);
        unsigned h = (u + 0x7fffu + ((u >> 16) & 1u)) & 0xffff0000u;
        hb[j] = h >> 16;
        rs[j] = x[j] - __uint_as_float(h);
    }
    uint4 hv, lv;
    hv.x = hb[0] | (hb[1] << 16); hv.y = hb[2] | (hb[3] << 16);
    hv.z = hb[4] | (hb[5] << 16); hv.w = hb[6] | (hb[7] << 16);
    lv.x = bf16pair(rs[0], rs[1]); lv.y = bf16pair(rs[2], rs[3]);
    lv.z = bf16pair(rs[4], rs[5]); lv.w = bf16pair(rs[6], rs[7]);
    hi = *reinterpret_cast<short8*>(&hv);
    lo = *reinterpret_cast<short8*>(&lv);
}

// ---------------------------------------------------------------------------
// Kernel A (v3): fixed-point solve via split-bf16 MFMA iterations.
// Blocks 0..255: AF-chain (16 rows each); 256..511: LF-chain.
// Per iteration (AF chain):  S1 = X@K~^T (16x64), Ldi = lt*rcp(S1+1);
//                            S2 = Ldi@K~ (16x128), AF' = at*rcp(S2+1).
// K~ = bf16(relu(K)) held in REGISTERS as MFMA B-fragments (Bk: contig-h,
// Bt: contig-i — by symmetry the LF chain uses the identical fragments).
// State A-fragments are built per-iter from f32 LDS with hi/lo bf16 split
// (2 MFMA per fragment) so state quantization (~2^-18) is below tol 5e-5.
// After convergence on the K~ map: 3 full-f32 VALU refinement iterations
// (exact relu(K) from LDS) contract the bf16-K fixed-point offset (~2e-3
// rel) to ~1e-3*rho^2 — the last one doubles as the reference's post-loop
// tracked update. Validated structure: rounds 2-5, absmax 0.25.
// ---------------------------------------------------------------------------
__global__ __launch_bounds__(256, 2)
void solve_chain(const float* __restrict__ LT, const float* __restrict__ Kg,
                 const float* __restrict__ AT, const int* __restrict__ msp,
                 float* __restrict__ AFout, float* __restrict__ LFout)
{
    __shared__ float Ksf[DIN][132];   // f32 relu(K) for refinement
    __shared__ float sX[16][132];     // state (AF: 128 cols, LF: 64 cols)
    __shared__ float sY[16][132];     // intermediate (Ldi: 64, Adi: 128)
    __shared__ float wred[4];

    const int tid = threadIdx.x;
    const int lane = tid & 63, w = tid >> 6;
    const int lr = lane & 15, lg = lane >> 4;
    const int bid = blockIdx.x & 255;
    const bool isL = blockIdx.x >= 256;
    const int b0row = bid * ROWS_PER_BLK;

    // stage f32 relu(K); zero state
    for (int idx = tid; idx < DIN * NH; idx += 256) {
        int i = idx >> 7, h = idx & 127;
        Ksf[i][h] = fmaxf(Kg[idx], 0.0f);
    }
    for (int idx = tid; idx < 16 * 132; idx += 256)
        (&sX[0][0])[idx] = 0.0f;

    int max_step = *msp;
    if (max_step > MAXSTEP_CAP) max_step = MAXSTEP_CAP;

    // ---- K~ B-fragments in registers (shared by both chains) ----
    short8 Bk[4];      // B[k=h][col=i]: K[16w+lr][ks*32+lg*8 + j]
    #pragma unroll
    for (int ks = 0; ks < 4; ++ks) {
        const float* p = &Kg[(16 * w + lr) * NH + ks * 32 + lg * 8];
        float4 f0 = *reinterpret_cast<const float4*>(p);
        float4 f1 = *reinterpret_cast<const float4*>(p + 4);
        uint4 v;
        v.x = bf16pair(fmaxf(f0.x, 0.f), fmaxf(f0.y, 0.f));
        v.y = bf16pair(fmaxf(f0.z, 0.f), fmaxf(f0.w, 0.f));
        v.z = bf16pair(fmaxf(f1.x, 0.f), fmaxf(f1.y, 0.f));
        v.w = bf16pair(fmaxf(f1.z, 0.f), fmaxf(f1.w, 0.f));
        Bk[ks] = *reinterpret_cast<short8*>(&v);
    }
    short8 Bt[2][2];   // B[k=i][col=h]: K[ks*32+lg*8+j][32w+16t+lr]
    #pragma unroll
    for (int t = 0; t < 2; ++t)
        #pragma unroll
        for (int ks = 0; ks < 2; ++ks) {
            float xx[8];
            #pragma unroll
            for (int j = 0; j < 8; ++j)
                xx[j] = fmaxf(Kg[(ks * 32 + lg * 8 + j) * NH + 32 * w + 16 * t + lr], 0.f);
            uint4 v;
            v.x = bf16pair(xx[0], xx[1]); v.y = bf16pair(xx[2], xx[3]);
            v.z = bf16pair(xx[4], xx[5]); v.w = bf16pair(xx[6], xx[7]);
            Bt[t][ks] = *reinterpret_cast<short8*>(&v);
        }

    // per-lane constants for the MFMA phase (C/D layout: col=lane&15,
    // row=(lane>>4)*4+r). Identical formulas for both chains.
    float ltv[4];
    #pragma unroll
    for (int r = 0; r < 4; ++r)
        ltv[r] = LT[(size_t)(b0row + lg * 4 + r) * DIN + 16 * w + lr];
    float atv[2];
    #pragma unroll
    for (int t = 0; t < 2; ++t)
        atv[t] = fmaxf(AT[32 * w + 16 * t + lr], 0.f);

    __syncthreads();

    int step = 0;
    bool done = false;

    if (!isL) {
        // ================= AF chain (MFMA loop) =================
        float prevA[2][4] = {};
        while (step < max_step && !done) {
            // S1 = X @ K~^T  -> Ldi (16x64), wave owns cols i in [16w,16w+16)
            f32x4 acc1 = {0.f, 0.f, 0.f, 0.f};
            #pragma unroll
            for (int ks = 0; ks < 4; ++ks) {
                f32x4 a = *reinterpret_cast<const f32x4*>(&sX[lr][ks * 32 + lg * 8]);
                f32x4 b = *reinterpret_cast<const f32x4*>(&sX[lr][ks * 32 + lg * 8 + 4]);
                short8 hi, lo; split8v(a, b, hi, lo);
                acc1 = __builtin_amdgcn_mfma_f32_16x16x32_bf16(hi, Bk[ks], acc1, 0, 0, 0);
                acc1 = __builtin_amdgcn_mfma_f32_16x16x32_bf16(lo, Bk[ks], acc1, 0, 0, 0);
            }
            #pragma unroll
            for (int r = 0; r < 4; ++r)
                sY[lg * 4 + r][16 * w + lr] = ltv[r] * frcp(acc1[r] + 1.0f);
            __syncthreads();
            // S2 = Ldi @ K~  -> AF' (16x128), wave owns cols h in [32w,32w+32)
            short8 ahi[2], alo[2];
            #pragma unroll
            for (int ks = 0; ks < 2; ++ks) {
                f32x4 a = *reinterpret_cast<const f32x4*>(&sY[lr][ks * 32 + lg * 8]);
                f32x4 b = *reinterpret_cast<const f32x4*>(&sY[lr][ks * 32 + lg * 8 + 4]);
                split8v(a, b, ahi[ks], alo[ks]);
            }
            float diff = 0.0f;
            #pragma unroll
            for (int t = 0; t < 2; ++t) {
                f32x4 acc2 = {0.f, 0.f, 0.f, 0.f};
                #pragma unroll
                for (int ks = 0; ks < 2; ++ks) {
                    acc2 = __builtin_amdgcn_mfma_f32_16x16x32_bf16(ahi[ks], Bt[t][ks], acc2, 0, 0, 0);
                    acc2 = __builtin_amdgcn_mfma_f32_16x16x32_bf16(alo[ks], Bt[t][ks], acc2, 0, 0, 0);
                }
                #pragma unroll
                for (int r = 0; r < 4; ++r) {
                    float v = atv[t] * frcp(acc2[r] + 1.0f);
                    diff = fmaxf(diff, fabsf(v - prevA[t][r]) * frcp(prevA[t][r] + 1e-5f));
                    prevA[t][r] = v;
                    sX[lg * 4 + r][32 * w + 16 * t + lr] = v;
                }
            }
            #pragma unroll
            for (int off = 32; off; off >>= 1)
                diff = fmaxf(diff, __shfl_xor(diff, off));
            if (lane == 0) wred[w] = diff;
            __syncthreads();
            done = fmaxf(fmaxf(wred[0], wred[1]), fmaxf(wred[2], wred[3])) < 5e-5f;
            ++step;
        }
        // ---- bridge to f32 refinement layout ----
        float af0[4], af1[4], ltr[4];
        #pragma unroll
        for (int r = 0; r < 4; ++r) {
            af0[r] = sX[(w << 2) + r][lane];
            af1[r] = sX[(w << 2) + r][64 + lane];
            ltr[r] = LT[(size_t)(b0row + (w << 2) + r) * DIN + lane];
        }
        const float at0 = fmaxf(AT[lane], 0.f), at1 = fmaxf(AT[64 + lane], 0.f);
        __syncthreads();
        // ---- 3 exact-f32 refinements (last = reference post-loop update) ----
        for (int it = 0; it < 3; ++it) {
            #pragma unroll
            for (int r = 0; r < 4; ++r) {
                int s = (w << 2) + r;
                sX[s][lane] = af0[r];
                sX[s][64 + lane] = af1[r];
            }
            __syncthreads();
            float s1[4] = {0.f, 0.f, 0.f, 0.f};
            const f32x4* Kr4 = reinterpret_cast<const f32x4*>(&Ksf[lane][0]);
            #pragma unroll 8
            for (int c = 0; c < 32; ++c) {
                f32x4 k4 = Kr4[c];
                #pragma unroll
                for (int r = 0; r < 4; ++r) {
                    f32x4 a4 = *reinterpret_cast<const f32x4*>(&sX[(w << 2) + r][c << 2]);
                    s1[r] += k4[0]*a4[0] + k4[1]*a4[1] + k4[2]*a4[2] + k4[3]*a4[3];
                }
            }
            #pragma unroll
            for (int r = 0; r < 4; ++r)
                sY[(w << 2) + r][lane] = ltr[r] * frcp(s1[r] + 1.0f);
            __syncthreads();
            float s2a[4] = {0.f,0.f,0.f,0.f}, s2b[4] = {0.f,0.f,0.f,0.f};
            #pragma unroll 4
            for (int i4 = 0; i4 < 16; ++i4) {
                f32x4 yb[4];
                #pragma unroll
                for (int r = 0; r < 4; ++r)
                    yb[r] = *reinterpret_cast<const f32x4*>(&sY[(w << 2) + r][i4 << 2]);
                #pragma unroll
                for (int j = 0; j < 4; ++j) {
                    int i = (i4 << 2) + j;
                    float k0 = Ksf[i][lane], k1 = Ksf[i][64 + lane];
                    #pragma unroll
                    for (int r = 0; r < 4; ++r) {
                        s2a[r] += k0 * yb[r][j];
                        s2b[r] += k1 * yb[r][j];
                    }
                }
            }
            #pragma unroll
            for (int r = 0; r < 4; ++r) {
                af0[r] = at0 * frcp(s2a[r] + 1.0f);
                af1[r] = at1 * frcp(s2b[r] + 1.0f);
            }
            __syncthreads();
        }
        #pragma unroll
        for (int r = 0; r < 4; ++r) {
            int row = b0row + (w << 2) + r;
            AFout[row * NH + lane]      = af0[r];
            AFout[row * NH + 64 + lane] = af1[r];
        }
    } else {
        // ================= LF chain (MFMA loop) =================
        float prevL[4] = {};
        while (step < max_step && !done) {
            // S3 = LF @ K~ -> Adi (16x128), wave owns cols h in [32w,32w+32)
            short8 ahi[2], alo[2];
            #pragma unroll
            for (int ks = 0; ks < 2; ++ks) {
                f32x4 a = *reinterpret_cast<const f32x4*>(&sX[lr][ks * 32 + lg * 8]);
                f32x4 b = *reinterpret_cast<const f32x4*>(&sX[lr][ks * 32 + lg * 8 + 4]);
                split8v(a, b, ahi[ks], alo[ks]);
            }
            #pragma unroll
            for (int t = 0; t < 2; ++t) {
                f32x4 acc3 = {0.f, 0.f, 0.f, 0.f};
                #pragma unroll
                for (int ks = 0; ks < 2; ++ks) {
                    acc3 = __builtin_amdgcn_mfma_f32_16x16x32_bf16(ahi[ks], Bt[t][ks], acc3, 0, 0, 0);
                    acc3 = __builtin_amdgcn_mfma_f32_16x16x32_bf16(alo[ks], Bt[t][ks], acc3, 0, 0, 0);
                }
                #pragma unroll
                for (int r = 0; r < 4; ++r)
                    sY[lg * 4 + r][32 * w + 16 * t + lr] = atv[t] * frcp(acc3[r] + 1.0f);
            }
            __syncthreads();
            // S4 = Adi @ K~^T -> LF' (16x64), wave owns cols i in [16w,16w+16)
            f32x4 acc4 = {0.f, 0.f, 0.f, 0.f};
            #pragma unroll
            for (int ks = 0; ks < 4; ++ks) {
                f32x4 a = *reinterpret_cast<const f32x4*>(&sY[lr][ks * 32 + lg * 8]);
                f32x4 b = *reinterpret_cast<const f32x4*>(&sY[lr][ks * 32 + lg * 8 + 4]);
                short8 hi, lo; split8v(a, b, hi, lo);
                acc4 = __builtin_amdgcn_mfma_f32_16x16x32_bf16(hi, Bk[ks], acc4, 0, 0, 0);
                acc4 = __builtin_amdgcn_mfma_f32_16x16x32_bf16(lo, Bk[ks], acc4, 0, 0, 0);
            }
            float diff = 0.0f;
            #pragma unroll
            for (int r = 0; r < 4; ++r) {
                float v = ltv[r] * frcp(acc4[r] + 1.0f);
                diff = fmaxf(diff, fabsf(v - prevL[r]) * frcp(prevL[r] + 1e-5f));
                prevL[r] = v;
                sX[lg * 4 + r][16 * w + lr] = v;
            }
            #pragma unroll
            for (int off = 32; off; off >>= 1)
                diff = fmaxf(diff, __shfl_xor(diff, off));
            if (lane == 0) wred[w] = diff;
            __syncthreads();
            done = fmaxf(fmaxf(wred[0], wred[1]), fmaxf(wred[2], wred[3])) < 5e-5f;
            ++step;
        }
        // ---- bridge + 3 exact-f32 refinements ----
        float lf[4], ltr[4];
        #pragma unroll
        for (int r = 0; r < 4; ++r) {
            lf[r]  = sX[(w << 2) + r][lane];
            ltr[r] = LT[(size_t)(b0row + (w << 2) + r) * DIN + lane];
        }
        const float at0 = fmaxf(AT[lane], 0.f), at1 = fmaxf(AT[64 + lane], 0.f);
        __syncthreads();
        for (int it = 0; it < 3; ++it) {
            #pragma unroll
            for (int r = 0; r < 4; ++r)
                sX[(w << 2) + r][lane] = lf[r];
            __syncthreads();
            float s3a[4] = {0.f,0.f,0.f,0.f}, s3b[4] = {0.f,0.f,0.f,0.f};
            #pragma unroll 4
            for (int i4 = 0; i4 < 16; ++i4) {
                f32x4 xb[4];
                #pragma unroll
                for (int r = 0; r < 4; ++r)
                    xb[r] = *reinterpret_cast<const f32x4*>(&sX[(w << 2) + r][i4 << 2]);
                #pragma unroll
                for (int j = 0; j < 4; ++j) {
                    int i = (i4 << 2) + j;
                    float k0 = Ksf[i][lane], k1 = Ksf[i][64 + lane];
                    #pragma unroll
                    for (int r = 0; r < 4; ++r) {
                        s3a[r] += k0 * xb[r][j];
                        s3b[r] += k1 * xb[r][j];
                    }
                }
            }
            #pragma unroll
            for (int r = 0; r < 4; ++r) {
                int s = (w << 2) + r;
                sY[s][lane]      = at0 * frcp(s3a[r] + 1.0f);
                sY[s][64 + lane] = at1 * frcp(s3b[r] + 1.0f);
            }
            __syncthreads();
            float s4[4] = {0.f, 0.f, 0.f, 0.f};
            const f32x4* Kr4 = reinterpret_cast<const f32x4*>(&Ksf[lane][0]);
            #pragma unroll 8
            for (int c = 0; c < 32; ++c) {
                f32x4 k4 = Kr4[c];
                #pragma unroll
                for (int r = 0; r < 4; ++r) {
                    f32x4 a4 = *reinterpret_cast<const f32x4*>(&sY[(w << 2) + r][c << 2]);
                    s4[r] += k4[0]*a4[0] + k4[1]*a4[1] + k4[2]*a4[2] + k4[3]*a4[3];
                }
            }
            #pragma unroll
            for (int r = 0; r < 4; ++r)
                lf[r] = ltr[r] * frcp(s4[r] + 1.0f);
            __syncthreads();
        }
        #pragma unroll
        for (int r = 0; r < 4; ++r) {
            int row = b0row + (w << 2) + r;
            LFout[row * DIN + lane] = lf[r];
        }
    }
}

// ---------------------------------------------------------------------------
// Kernel P: W_T[o][k] = bf16( relu(K[k]) * u[k][o] ), e appended at k>=8192.
// Unchanged from round 3.
// ---------------------------------------------------------------------------
__global__ __launch_bounds__(256, 1)
void prep_wt(const float* __restrict__ Kg, const float* __restrict__ ug,
             const float* __restrict__ eg, ushort* __restrict__ WT)
{
    __shared__ float tile[64][68];
    const int t = threadIdx.x;
    const int k0 = blockIdx.x * 64;
    const int o0 = blockIdx.y * 64;
    const bool is_main = (k0 < 8192);
    const int r0 = t >> 4, c4 = (t & 15) << 2;
    #pragma unroll
    for (int p = 0; p < 4; ++p) {
        int r = r0 + (p << 4);
        float4 v;
        if (is_main) {
            float kv = fmaxf(Kg[k0 + r], 0.0f);
            v = *reinterpret_cast<const float4*>(&ug[(size_t)(k0 + r) * DOUT + o0 + c4]);
            v.x *= kv; v.y *= kv; v.z *= kv; v.w *= kv;
        } else {
            v = *reinterpret_cast<const float4*>(&eg[(size_t)(k0 - 8192 + r) * DOUT + o0 + c4]);
        }
        *reinterpret_cast<float4*>(&tile[r][c4]) = v;
    }
    __syncthreads();
    const int o = t >> 2, q = t & 3;
    #pragma unroll
    for (int j = 0; j < 2; ++j) {
        int kb = (q << 4) + (j << 3);
        uint4 u4;
        u4.x = bf16pair(tile[kb + 0][o], tile[kb + 1][o]);
        u4.y = bf16pair(tile[kb + 2][o], tile[kb + 3][o]);
        u4.z = bf16pair(tile[kb + 4][o], tile[kb + 5][o]);
        u4.w = bf16pair(tile[kb + 6][o], tile[kb + 7][o]);
        *reinterpret_cast<uint4*>(&WT[(size_t)(o0 + o) * WT_STRIDE + k0 + kb]) = u4;
    }
}

// ---------------------------------------------------------------------------
// Kernel B (rank-1 factored, round 5 + XCD-affinity swizzle):
// 1D grid 512; o-tile = blockIdx&7 so each XCD's L2 caches ONE 1MB WT slice.
// ---------------------------------------------------------------------------
__global__ __launch_bounds__(256, 2)
void out_gemm_rank1(const float* __restrict__ AFw, const float* __restrict__ LFw,
                    const ushort* __restrict__ WT, const float* __restrict__ bg,
                    float* __restrict__ out)
{
    __shared__ __align__(16) ushort AFb[64][136];
    __shared__ __align__(16) float  LFt[64][68];
    __shared__ __align__(16) ushort Bs[2][64][136];

    const int t = threadIdx.x;
    const int b0 = (blockIdx.x >> 3) * 64, o0 = (blockIdx.x & 7) * 64;
    const int w = t >> 6, l = t & 63;
    const int wm = w >> 1, wn = w & 1;
    const int lr = l & 15, lg = l >> 4;

    {
        const int row = t >> 2, q = t & 3;
        const float4* srcA = reinterpret_cast<const float4*>(
            &AFw[(size_t)(b0 + row) * NH + q * 32]);
        #pragma unroll
        for (int g = 0; g < 4; ++g) {
            float4 fa = srcA[2 * g], fb = srcA[2 * g + 1];
            uint4 wv;
            wv.x = bf16pair(fa.x, fa.y); wv.y = bf16pair(fa.z, fa.w);
            wv.z = bf16pair(fb.x, fb.y); wv.w = bf16pair(fb.z, fb.w);
            *reinterpret_cast<uint4*>(&AFb[row][q * 32 + g * 8]) = wv;
        }
        const f32x4* srcL = reinterpret_cast<const f32x4*>(
            &LFw[(size_t)(b0 + row) * DIN + q * 16]);
        #pragma unroll
        for (int g = 0; g < 4; ++g) {
            f32x4 fv = srcL[g];
            #pragma unroll
            for (int j = 0; j < 4; ++j)
                LFt[q * 16 + g * 4 + j][row] = fv[j];
        }
    }

    uint4 rb[4];
    auto loadB = [&](int i) {
        const uint4* p = reinterpret_cast<const uint4*>(
            &WT[(size_t)(o0 + (t >> 2)) * WT_STRIDE + i * 128 + (t & 3) * 32]);
        #pragma unroll
        for (int g = 0; g < 4; ++g) rb[g] = p[g];
    };
    auto writeB = [&](int buf) {
        #pragma unroll
        for (int g = 0; g < 4; ++g)
            *reinterpret_cast<uint4*>(&Bs[buf][t >> 2][(t & 3) * 32 + g * 8]) = rb[g];
    };

    loadB(0);
    writeB(0);
    __syncthreads();

    short8 afr0[4], afr1[4];
    #pragma unroll
    for (int ks = 0; ks < 4; ++ks) {
        afr0[ks] = *reinterpret_cast<const short8*>(&AFb[wm * 32 +      lr][ks * 32 + lg * 8]);
        afr1[ks] = *reinterpret_cast<const short8*>(&AFb[wm * 32 + 16 + lr][ks * 32 + lg * 8]);
    }

    f32x4 acc00 = {0.f,0.f,0.f,0.f}, acc01 = acc00, acc10 = acc00, acc11 = acc00;

    for (int i = 0; i <= 64; ++i) {
        const int buf = i & 1;
        if (i < 64) loadB(i + 1);
        f32x4 t00 = {0.f,0.f,0.f,0.f}, t01 = t00, t10 = t00, t11 = t00;
        #pragma unroll
        for (int ks = 0; ks < 4; ++ks) {
            short8 bv0 = *reinterpret_cast<const short8*>(&Bs[buf][wn * 32 +      lr][ks * 32 + lg * 8]);
            short8 bv1 = *reinterpret_cast<const short8*>(&Bs[buf][wn * 32 + 16 + lr][ks * 32 + lg * 8]);
            t00 = __builtin_amdgcn_mfma_f32_16x16x32_bf16(afr0[ks], bv0, t00, 0, 0, 0);
            t10 = __builtin_amdgcn_mfma_f32_16x16x32_bf16(afr1[ks], bv0, t10, 0, 0, 0);
            t01 = __builtin_amdgcn_mfma_f32_16x16x32_bf16(afr0[ks], bv1, t01, 0, 0, 0);
            t11 = __builtin_amdgcn_mfma_f32_16x16x32_bf16(afr1[ks], bv1, t11, 0, 0, 0);
        }
        if (i < 64) {
            f32x4 lf0 = *reinterpret_cast<const f32x4*>(&LFt[i][wm * 32 +      lg * 4]);
            f32x4 lf1 = *reinterpret_cast<const f32x4*>(&LFt[i][wm * 32 + 16 + lg * 4]);
            #pragma unroll
            for (int r = 0; r < 4; ++r) {
                acc00[r] += lf0[r] * t00[r];
                acc01[r] += lf0[r] * t01[r];
                acc10[r] += lf1[r] * t10[r];
                acc11[r] += lf1[r] * t11[r];
            }
            writeB(buf ^ 1);
            __syncthreads();
        } else {
            #pragma unroll
            for (int r = 0; r < 4; ++r) {
                acc00[r] += t00[r];
                acc01[r] += t01[r];
                acc10[r] += t10[r];
                acc11[r] += t11[r];
            }
        }
    }

    const int col = o0 + wn * 32 + lr;
    const float bb0 = bg[col], bb1 = bg[col + 16];
    #pragma unroll
    for (int r = 0; r < 4; ++r) {
        const int row0 = b0 + wm * 32 + lg * 4 + r;
        out[(size_t)row0 * DOUT + col]            = acc00[r] + bb0;
        out[(size_t)row0 * DOUT + col + 16]       = acc01[r] + bb1;
        out[(size_t)(row0 + 16) * DOUT + col]      = acc10[r] + bb0;
        out[(size_t)(row0 + 16) * DOUT + col + 16] = acc11[r] + bb1;
    }
}

// ---------------------------------------------------------------------------
// Workspace layout (bytes):
//   [0,        2097152)   AF  : float[4096][128]
//   [2097152,  3145728)   LF  : float[4096][64]
//   [3145728, +8519680)   WT  : ushort[512][8320]
// Fully rewritten before use each launch -> deterministic.
// ---------------------------------------------------------------------------
extern "C" void kernel_launch(void* const* d_in, const int* in_sizes, int n_in,
                              void* d_out, int out_size, void* d_ws, size_t ws_size,
                              hipStream_t stream)
{
    const float* LT   = (const float*)d_in[0];
    const float* Kg   = (const float*)d_in[1];
    const float* AT   = (const float*)d_in[2];
    const float* ug   = (const float*)d_in[3];
    const float* eg   = (const float*)d_in[4];
    const float* bg   = (const float*)d_in[5];
    const int*   msp  = (const int*)d_in[6];
    float* out = (float*)d_out;

    char* ws = (char*)d_ws;
    float*  AFw = (float*)(ws);
    float*  LFw = (float*)(ws + 2097152);
    ushort* WTw = (ushort*)(ws + 3145728);

    solve_chain<<<dim3(512), dim3(256), 0, stream>>>(LT, Kg, AT, msp, AFw, LFw);
    prep_wt<<<dim3(130, 8), dim3(256), 0, stream>>>(Kg, ug, eg, WTw);

    out_gemm_rank1<<<dim3(512), dim3(256), 0, stream>>>(AFw, LFw, WTw, bg, out);
}

// Round 7
// 197.644 us; speedup vs baseline: 6.4132x; 1.1177x over previous
//
#include <hip/hip_runtime.h>

// Problem constants
#define B_ROWS 4096
#define DIN 64
#define NH 128
#define DOUT 512
#define ROWS_PER_BLK 16
#define MAXSTEP_CAP 1000
#define KTOT 8320          // 8192 main + 128 e-term
#define WT_STRIDE 8320

typedef __attribute__((ext_vector_type(8))) short short8;
typedef __attribute__((ext_vector_type(4))) float f32x4;

// round-to-nearest-even f32 -> bf16, packed pair into a uint
__device__ inline unsigned bf16pair(float lo, float hi) {
    unsigned a = __float_as_uint(lo), b = __float_as_uint(hi);
    a = (a + 0x7fffu + ((a >> 16) & 1u)) >> 16;
    b = (b + 0x7fffu + ((b >> 16) & 1u)) >> 16;
    return a | (b << 16);
}

__device__ inline float frcp(float x) { return __builtin_amdgcn_rcpf(x); }

// split x (8 f32) into hi = bf16(x), lo = bf16(x - hi); quantization error
// <= 2^-18 relative — far below the 5e-5 convergence tolerance.
__device__ inline void split8v(f32x4 a, f32x4 b, short8& hi, short8& lo) {
    float x[8] = {a[0], a[1], a[2], a[3], b[0], b[1], b[2], b[3]};
    unsigned hb[8]; float rs[8];
    #pragma unroll
    for (int j = 0; j < 8; ++j) {
        unsigned u = __float_as_uint(x[j]);
        unsigned h = (u + 0x7fffu + ((u >> 16) & 1u)) & 0xffff0000u;
        hb[j] = h >> 16;
        rs[j] = x[j] - __uint_as_float(h);
    }
    uint4 hv, lv;
    hv.x = hb[0] | (hb[1] << 16); hv.y = hb[2] | (hb[3] << 16);
    hv.z = hb[4] | (hb[5] << 16); hv.w = hb[6] | (hb[7] << 16);
    lv.x = bf16pair(rs[0], rs[1]); lv.y = bf16pair(rs[2], rs[3]);
    lv.z = bf16pair(rs[4], rs[5]); lv.w = bf16pair(rs[6], rs[7]);
    hi = *reinterpret_cast<short8*>(&hv);
    lo = *reinterpret_cast<short8*>(&lv);
}

// ---------------------------------------------------------------------------
// Kernel A: fixed-point solve via split-bf16 MFMA iterations (round 6, ~45us).
// Blocks 0..255: AF-chain; 256..511: LF-chain. Local tol 5e-5 on the bf16-K
// map, then 3 exact-f32 refinement iterations. Validated: absmax 0.25.
// ---------------------------------------------------------------------------
__global__ __launch_bounds__(256, 2)
void solve_chain(const float* __restrict__ LT, const float* __restrict__ Kg,
                 const float* __restrict__ AT, const int* __restrict__ msp,
                 float* __restrict__ AFout, float* __restrict__ LFout)
{
    __shared__ float Ksf[DIN][132];   // f32 relu(K) for refinement
    __shared__ float sX[16][132];     // state (AF: 128 cols, LF: 64 cols)
    __shared__ float sY[16][132];     // intermediate (Ldi: 64, Adi: 128)
    __shared__ float wred[4];

    const int tid = threadIdx.x;
    const int lane = tid & 63, w = tid >> 6;
    const int lr = lane & 15, lg = lane >> 4;
    const int bid = blockIdx.x & 255;
    const bool isL = blockIdx.x >= 256;
    const int b0row = bid * ROWS_PER_BLK;

    for (int idx = tid; idx < DIN * NH; idx += 256) {
        int i = idx >> 7, h = idx & 127;
        Ksf[i][h] = fmaxf(Kg[idx], 0.0f);
    }
    for (int idx = tid; idx < 16 * 132; idx += 256)
        (&sX[0][0])[idx] = 0.0f;

    int max_step = *msp;
    if (max_step > MAXSTEP_CAP) max_step = MAXSTEP_CAP;

    short8 Bk[4];      // B[k=h][col=i]: K[16w+lr][ks*32+lg*8 + j]
    #pragma unroll
    for (int ks = 0; ks < 4; ++ks) {
        const float* p = &Kg[(16 * w + lr) * NH + ks * 32 + lg * 8];
        float4 f0 = *reinterpret_cast<const float4*>(p);
        float4 f1 = *reinterpret_cast<const float4*>(p + 4);
        uint4 v;
        v.x = bf16pair(fmaxf(f0.x, 0.f), fmaxf(f0.y, 0.f));
        v.y = bf16pair(fmaxf(f0.z, 0.f), fmaxf(f0.w, 0.f));
        v.z = bf16pair(fmaxf(f1.x, 0.f), fmaxf(f1.y, 0.f));
        v.w = bf16pair(fmaxf(f1.z, 0.f), fmaxf(f1.w, 0.f));
        Bk[ks] = *reinterpret_cast<short8*>(&v);
    }
    short8 Bt[2][2];   // B[k=i][col=h]: K[ks*32+lg*8+j][32w+16t+lr]
    #pragma unroll
    for (int t = 0; t < 2; ++t)
        #pragma unroll
        for (int ks = 0; ks < 2; ++ks) {
            float xx[8];
            #pragma unroll
            for (int j = 0; j < 8; ++j)
                xx[j] = fmaxf(Kg[(ks * 32 + lg * 8 + j) * NH + 32 * w + 16 * t + lr], 0.f);
            uint4 v;
            v.x = bf16pair(xx[0], xx[1]); v.y = bf16pair(xx[2], xx[3]);
            v.z = bf16pair(xx[4], xx[5]); v.w = bf16pair(xx[6], xx[7]);
            Bt[t][ks] = *reinterpret_cast<short8*>(&v);
        }

    float ltv[4];
    #pragma unroll
    for (int r = 0; r < 4; ++r)
        ltv[r] = LT[(size_t)(b0row + lg * 4 + r) * DIN + 16 * w + lr];
    float atv[2];
    #pragma unroll
    for (int t = 0; t < 2; ++t)
        atv[t] = fmaxf(AT[32 * w + 16 * t + lr], 0.f);

    __syncthreads();

    int step = 0;
    bool done = false;

    if (!isL) {
        // ================= AF chain (MFMA loop) =================
        float prevA[2][4] = {};
        while (step < max_step && !done) {
            f32x4 acc1 = {0.f, 0.f, 0.f, 0.f};
            #pragma unroll
            for (int ks = 0; ks < 4; ++ks) {
                f32x4 a = *reinterpret_cast<const f32x4*>(&sX[lr][ks * 32 + lg * 8]);
                f32x4 b = *reinterpret_cast<const f32x4*>(&sX[lr][ks * 32 + lg * 8 + 4]);
                short8 hi, lo; split8v(a, b, hi, lo);
                acc1 = __builtin_amdgcn_mfma_f32_16x16x32_bf16(hi, Bk[ks], acc1, 0, 0, 0);
                acc1 = __builtin_amdgcn_mfma_f32_16x16x32_bf16(lo, Bk[ks], acc1, 0, 0, 0);
            }
            #pragma unroll
            for (int r = 0; r < 4; ++r)
                sY[lg * 4 + r][16 * w + lr] = ltv[r] * frcp(acc1[r] + 1.0f);
            __syncthreads();
            short8 ahi[2], alo[2];
            #pragma unroll
            for (int ks = 0; ks < 2; ++ks) {
                f32x4 a = *reinterpret_cast<const f32x4*>(&sY[lr][ks * 32 + lg * 8]);
                f32x4 b = *reinterpret_cast<const f32x4*>(&sY[lr][ks * 32 + lg * 8 + 4]);
                split8v(a, b, ahi[ks], alo[ks]);
            }
            float diff = 0.0f;
            #pragma unroll
            for (int t = 0; t < 2; ++t) {
                f32x4 acc2 = {0.f, 0.f, 0.f, 0.f};
                #pragma unroll
                for (int ks = 0; ks < 2; ++ks) {
                    acc2 = __builtin_amdgcn_mfma_f32_16x16x32_bf16(ahi[ks], Bt[t][ks], acc2, 0, 0, 0);
                    acc2 = __builtin_amdgcn_mfma_f32_16x16x32_bf16(alo[ks], Bt[t][ks], acc2, 0, 0, 0);
                }
                #pragma unroll
                for (int r = 0; r < 4; ++r) {
                    float v = atv[t] * frcp(acc2[r] + 1.0f);
                    diff = fmaxf(diff, fabsf(v - prevA[t][r]) * frcp(prevA[t][r] + 1e-5f));
                    prevA[t][r] = v;
                    sX[lg * 4 + r][32 * w + 16 * t + lr] = v;
                }
            }
            #pragma unroll
            for (int off = 32; off; off >>= 1)
                diff = fmaxf(diff, __shfl_xor(diff, off));
            if (lane == 0) wred[w] = diff;
            __syncthreads();
            done = fmaxf(fmaxf(wred[0], wred[1]), fmaxf(wred[2], wred[3])) < 5e-5f;
            ++step;
        }
        float af0[4], af1[4], ltr[4];
        #pragma unroll
        for (int r = 0; r < 4; ++r) {
            af0[r] = sX[(w << 2) + r][lane];
            af1[r] = sX[(w << 2) + r][64 + lane];
            ltr[r] = LT[(size_t)(b0row + (w << 2) + r) * DIN + lane];
        }
        const float at0 = fmaxf(AT[lane], 0.f), at1 = fmaxf(AT[64 + lane], 0.f);
        __syncthreads();
        for (int it = 0; it < 3; ++it) {
            #pragma unroll
            for (int r = 0; r < 4; ++r) {
                int s = (w << 2) + r;
                sX[s][lane] = af0[r];
                sX[s][64 + lane] = af1[r];
            }
            __syncthreads();
            float s1[4] = {0.f, 0.f, 0.f, 0.f};
            const f32x4* Kr4 = reinterpret_cast<const f32x4*>(&Ksf[lane][0]);
            #pragma unroll 8
            for (int c = 0; c < 32; ++c) {
                f32x4 k4 = Kr4[c];
                #pragma unroll
                for (int r = 0; r < 4; ++r) {
                    f32x4 a4 = *reinterpret_cast<const f32x4*>(&sX[(w << 2) + r][c << 2]);
                    s1[r] += k4[0]*a4[0] + k4[1]*a4[1] + k4[2]*a4[2] + k4[3]*a4[3];
                }
            }
            #pragma unroll
            for (int r = 0; r < 4; ++r)
                sY[(w << 2) + r][lane] = ltr[r] * frcp(s1[r] + 1.0f);
            __syncthreads();
            float s2a[4] = {0.f,0.f,0.f,0.f}, s2b[4] = {0.f,0.f,0.f,0.f};
            #pragma unroll 4
            for (int i4 = 0; i4 < 16; ++i4) {
                f32x4 yb[4];
                #pragma unroll
                for (int r = 0; r < 4; ++r)
                    yb[r] = *reinterpret_cast<const f32x4*>(&sY[(w << 2) + r][i4 << 2]);
                #pragma unroll
                for (int j = 0; j < 4; ++j) {
                    int i = (i4 << 2) + j;
                    float k0 = Ksf[i][lane], k1 = Ksf[i][64 + lane];
                    #pragma unroll
                    for (int r = 0; r < 4; ++r) {
                        s2a[r] += k0 * yb[r][j];
                        s2b[r] += k1 * yb[r][j];
                    }
                }
            }
            #pragma unroll
            for (int r = 0; r < 4; ++r) {
                af0[r] = at0 * frcp(s2a[r] + 1.0f);
                af1[r] = at1 * frcp(s2b[r] + 1.0f);
            }
            __syncthreads();
        }
        #pragma unroll
        for (int r = 0; r < 4; ++r) {
            int row = b0row + (w << 2) + r;
            AFout[row * NH + lane]      = af0[r];
            AFout[row * NH + 64 + lane] = af1[r];
        }
    } else {
        // ================= LF chain (MFMA loop) =================
        float prevL[4] = {};
        while (step < max_step && !done) {
            short8 ahi[2], alo[2];
            #pragma unroll
            for (int ks = 0; ks < 2; ++ks) {
                f32x4 a = *reinterpret_cast<const f32x4*>(&sX[lr][ks * 32 + lg * 8]);
                f32x4 b = *reinterpret_cast<const f32x4*>(&sX[lr][ks * 32 + lg * 8 + 4]);
                split8v(a, b, ahi[ks], alo[ks]);
            }
            #pragma unroll
            for (int t = 0; t < 2; ++t) {
                f32x4 acc3 = {0.f, 0.f, 0.f, 0.f};
                #pragma unroll
                for (int ks = 0; ks < 2; ++ks) {
                    acc3 = __builtin_amdgcn_mfma_f32_16x16x32_bf16(ahi[ks], Bt[t][ks], acc3, 0, 0, 0);
                    acc3 = __builtin_amdgcn_mfma_f32_16x16x32_bf16(alo[ks], Bt[t][ks], acc3, 0, 0, 0);
                }
                #pragma unroll
                for (int r = 0; r < 4; ++r)
                    sY[lg * 4 + r][32 * w + 16 * t + lr] = atv[t] * frcp(acc3[r] + 1.0f);
            }
            __syncthreads();
            f32x4 acc4 = {0.f, 0.f, 0.f, 0.f};
            #pragma unroll
            for (int ks = 0; ks < 4; ++ks) {
                f32x4 a = *reinterpret_cast<const f32x4*>(&sY[lr][ks * 32 + lg * 8]);
                f32x4 b = *reinterpret_cast<const f32x4*>(&sY[lr][ks * 32 + lg * 8 + 4]);
                short8 hi, lo; split8v(a, b, hi, lo);
                acc4 = __builtin_amdgcn_mfma_f32_16x16x32_bf16(hi, Bk[ks], acc4, 0, 0, 0);
                acc4 = __builtin_amdgcn_mfma_f32_16x16x32_bf16(lo, Bk[ks], acc4, 0, 0, 0);
            }
            float diff = 0.0f;
            #pragma unroll
            for (int r = 0; r < 4; ++r) {
                float v = ltv[r] * frcp(acc4[r] + 1.0f);
                diff = fmaxf(diff, fabsf(v - prevL[r]) * frcp(prevL[r] + 1e-5f));
                prevL[r] = v;
                sX[lg * 4 + r][16 * w + lr] = v;
            }
            #pragma unroll
            for (int off = 32; off; off >>= 1)
                diff = fmaxf(diff, __shfl_xor(diff, off));
            if (lane == 0) wred[w] = diff;
            __syncthreads();
            done = fmaxf(fmaxf(wred[0], wred[1]), fmaxf(wred[2], wred[3])) < 5e-5f;
            ++step;
        }
        float lf[4], ltr[4];
        #pragma unroll
        for (int r = 0; r < 4; ++r) {
            lf[r]  = sX[(w << 2) + r][lane];
            ltr[r] = LT[(size_t)(b0row + (w << 2) + r) * DIN + lane];
        }
        const float at0 = fmaxf(AT[lane], 0.f), at1 = fmaxf(AT[64 + lane], 0.f);
        __syncthreads();
        for (int it = 0; it < 3; ++it) {
            #pragma unroll
            for (int r = 0; r < 4; ++r)
                sX[(w << 2) + r][lane] = lf[r];
            __syncthreads();
            float s3a[4] = {0.f,0.f,0.f,0.f}, s3b[4] = {0.f,0.f,0.f,0.f};
            #pragma unroll 4
            for (int i4 = 0; i4 < 16; ++i4) {
                f32x4 xb[4];
                #pragma unroll
                for (int r = 0; r < 4; ++r)
                    xb[r] = *reinterpret_cast<const f32x4*>(&sX[(w << 2) + r][i4 << 2]);
                #pragma unroll
                for (int j = 0; j < 4; ++j) {
                    int i = (i4 << 2) + j;
                    float k0 = Ksf[i][lane], k1 = Ksf[i][64 + lane];
                    #pragma unroll
                    for (int r = 0; r < 4; ++r) {
                        s3a[r] += k0 * xb[r][j];
                        s3b[r] += k1 * xb[r][j];
                    }
                }
            }
            #pragma unroll
            for (int r = 0; r < 4; ++r) {
                int s = (w << 2) + r;
                sY[s][lane]      = at0 * frcp(s3a[r] + 1.0f);
                sY[s][64 + lane] = at1 * frcp(s3b[r] + 1.0f);
            }
            __syncthreads();
            float s4[4] = {0.f, 0.f, 0.f, 0.f};
            const f32x4* Kr4 = reinterpret_cast<const f32x4*>(&Ksf[lane][0]);
            #pragma unroll 8
            for (int c = 0; c < 32; ++c) {
                f32x4 k4 = Kr4[c];
                #pragma unroll
                for (int r = 0; r < 4; ++r) {
                    f32x4 a4 = *reinterpret_cast<const f32x4*>(&sY[(w << 2) + r][c << 2]);
                    s4[r] += k4[0]*a4[0] + k4[1]*a4[1] + k4[2]*a4[2] + k4[3]*a4[3];
                }
            }
            #pragma unroll
            for (int r = 0; r < 4; ++r)
                lf[r] = ltr[r] * frcp(s4[r] + 1.0f);
            __syncthreads();
        }
        #pragma unroll
        for (int r = 0; r < 4; ++r) {
            int row = b0row + (w << 2) + r;
            LFout[row * DIN + lane] = lf[r];
        }
    }
}

// ---------------------------------------------------------------------------
// Kernel P: W_T[o][k] = bf16( relu(K[k]) * u[k][o] ), e appended at k>=8192.
// ---------------------------------------------------------------------------
__global__ __launch_bounds__(256, 1)
void prep_wt(const float* __restrict__ Kg, const float* __restrict__ ug,
             const float* __restrict__ eg, ushort* __restrict__ WT)
{
    __shared__ float tile[64][68];
    const int t = threadIdx.x;
    const int k0 = blockIdx.x * 64;
    const int o0 = blockIdx.y * 64;
    const bool is_main = (k0 < 8192);
    const int r0 = t >> 4, c4 = (t & 15) << 2;
    #pragma unroll
    for (int p = 0; p < 4; ++p) {
        int r = r0 + (p << 4);
        float4 v;
        if (is_main) {
            float kv = fmaxf(Kg[k0 + r], 0.0f);
            v = *reinterpret_cast<const float4*>(&ug[(size_t)(k0 + r) * DOUT + o0 + c4]);
            v.x *= kv; v.y *= kv; v.z *= kv; v.w *= kv;
        } else {
            v = *reinterpret_cast<const float4*>(&eg[(size_t)(k0 - 8192 + r) * DOUT + o0 + c4]);
        }
        *reinterpret_cast<float4*>(&tile[r][c4]) = v;
    }
    __syncthreads();
    const int o = t >> 2, q = t & 3;
    #pragma unroll
    for (int j = 0; j < 2; ++j) {
        int kb = (q << 4) + (j << 3);
        uint4 u4;
        u4.x = bf16pair(tile[kb + 0][o], tile[kb + 1][o]);
        u4.y = bf16pair(tile[kb + 2][o], tile[kb + 3][o]);
        u4.z = bf16pair(tile[kb + 4][o], tile[kb + 5][o]);
        u4.w = bf16pair(tile[kb + 6][o], tile[kb + 7][o]);
        *reinterpret_cast<uint4*>(&WT[(size_t)(o0 + o) * WT_STRIDE + k0 + kb]) = u4;
    }
}

// ---------------------------------------------------------------------------
// Kernel B (v4, rank-1 + BARRIER-FREE main loop):
//   out[b,o] = sum_i LF[b,i] * (AF[b,:] @ W_i[:,o]) + e-term + bias
// Round-6 pathology: 65 tiny LDS B-tiles each gated by ds_write+barrier with
// phase-aligned blocks -> 86% idle. Fix: B-fragments are per-lane CONTIGUOUS
// 16B in WT -> load them straight from L2 with global_load_dwordx4, 2-deep
// register prefetch (bA/bB), NO __syncthreads after the prologue. 4 waves x
// 2 blocks/CU free-run. L2 traffic 2x (1.09 GB, XCD-affine slices) but at
// 34 TB/s aggregate that's ~32 us — far better than the latency serialization.
// LDS = AFb + LFt only (34.8 KB).
// ---------------------------------------------------------------------------
__global__ __launch_bounds__(256, 2)
void out_gemm_rank1(const float* __restrict__ AFw, const float* __restrict__ LFw,
                    const ushort* __restrict__ WT, const float* __restrict__ bg,
                    float* __restrict__ out)
{
    __shared__ __align__(16) ushort AFb[64][136];
    __shared__ __align__(16) float  LFt[64][68];

    const int t = threadIdx.x;
    const int b0 = (blockIdx.x >> 3) * 64, o0 = (blockIdx.x & 7) * 64;
    const int w = t >> 6, l = t & 63;
    const int wm = w >> 1, wn = w & 1;       // 2x2 wave grid, wave-tile 32x32
    const int lr = l & 15, lg = l >> 4;

    // ---- prologue: AF (bf16) + LF^T (f32) to LDS, ONE barrier ----
    {
        const int row = t >> 2, q = t & 3;
        const float4* srcA = reinterpret_cast<const float4*>(
            &AFw[(size_t)(b0 + row) * NH + q * 32]);
        #pragma unroll
        for (int g = 0; g < 4; ++g) {
            float4 fa = srcA[2 * g], fb = srcA[2 * g + 1];
            uint4 wv;
            wv.x = bf16pair(fa.x, fa.y); wv.y = bf16pair(fa.z, fa.w);
            wv.z = bf16pair(fb.x, fb.y); wv.w = bf16pair(fb.z, fb.w);
            *reinterpret_cast<uint4*>(&AFb[row][q * 32 + g * 8]) = wv;
        }
        const f32x4* srcL = reinterpret_cast<const f32x4*>(
            &LFw[(size_t)(b0 + row) * DIN + q * 16]);
        #pragma unroll
        for (int g = 0; g < 4; ++g) {
            f32x4 fv = srcL[g];
            #pragma unroll
            for (int j = 0; j < 4; ++j)
                LFt[q * 16 + g * 4 + j][row] = fv[j];
        }
    }
    __syncthreads();   // the ONLY barrier

    // per-lane W base: row = o0 + wn*32 + lr, col byte = lg*16
    const char* wbase = reinterpret_cast<const char*>(WT)
        + ((size_t)(o0 + wn * 32 + lr) * WT_STRIDE + lg * 8) * 2;

    short8 bA[8], bB[8];
    // dst[n*4+ks] = W[(row + n*16)][i*128 + ks*32 + lg*8 .. +7]
    auto loadB = [&](short8* dst, int i) {
        const char* p = wbase + (size_t)i * 256;
        #pragma unroll
        for (int n = 0; n < 2; ++n)
            #pragma unroll
            for (int ks = 0; ks < 4; ++ks)
                dst[n * 4 + ks] = *reinterpret_cast<const short8*>(
                    p + n * (16 * WT_STRIDE * 2) + ks * 64);
    };

    loadB(bA, 0);      // first tile in flight while we read A-frags from LDS

    // ---- A-fragments in registers for the whole loop ----
    short8 afr0[4], afr1[4];
    #pragma unroll
    for (int ks = 0; ks < 4; ++ks) {
        afr0[ks] = *reinterpret_cast<const short8*>(&AFb[wm * 32 +      lr][ks * 32 + lg * 8]);
        afr1[ks] = *reinterpret_cast<const short8*>(&AFb[wm * 32 + 16 + lr][ks * 32 + lg * 8]);
    }

    f32x4 acc00 = {0.f,0.f,0.f,0.f}, acc01 = acc00, acc10 = acc00, acc11 = acc00;
    f32x4 t00, t01, t10, t11;

    auto computeI = [&](const short8* bf) {
        t00 = (f32x4){0.f,0.f,0.f,0.f}; t01 = t00; t10 = t00; t11 = t00;
        #pragma unroll
        for (int ks = 0; ks < 4; ++ks) {
            t00 = __builtin_amdgcn_mfma_f32_16x16x32_bf16(afr0[ks], bf[ks],     t00, 0, 0, 0);
            t10 = __builtin_amdgcn_mfma_f32_16x16x32_bf16(afr1[ks], bf[ks],     t10, 0, 0, 0);
            t01 = __builtin_amdgcn_mfma_f32_16x16x32_bf16(afr0[ks], bf[4 + ks], t01, 0, 0, 0);
            t11 = __builtin_amdgcn_mfma_f32_16x16x32_bf16(afr1[ks], bf[4 + ks], t11, 0, 0, 0);
        }
    };
    auto scaleAdd = [&](int i) {
        f32x4 lf0 = *reinterpret_cast<const f32x4*>(&LFt[i][wm * 32 +      lg * 4]);
        f32x4 lf1 = *reinterpret_cast<const f32x4*>(&LFt[i][wm * 32 + 16 + lg * 4]);
        #pragma unroll
        for (int r = 0; r < 4; ++r) {
            acc00[r] += lf0[r] * t00[r];
            acc01[r] += lf0[r] * t01[r];
            acc10[r] += lf1[r] * t10[r];
            acc11[r] += lf1[r] * t11[r];
        }
    };

    // i = 0..63 (LF-scaled), i = 64 (e-term, scale 1). 2-deep prefetch.
    #pragma unroll 1
    for (int ii = 0; ii < 32; ++ii) {
        const int i0 = 2 * ii;
        loadB(bB, i0 + 1);
        computeI(bA);
        scaleAdd(i0);
        loadB(bA, i0 + 2);
        computeI(bB);
        scaleAdd(i0 + 1);
    }
    computeI(bA);      // i = 64: e-term, scale 1
    #pragma unroll
    for (int r = 0; r < 4; ++r) {
        acc00[r] += t00[r];
        acc01[r] += t01[r];
        acc10[r] += t10[r];
        acc11[r] += t11[r];
    }

    // ---- epilogue: bias + store ----
    const int col = o0 + wn * 32 + lr;
    const float bb0 = bg[col], bb1 = bg[col + 16];
    #pragma unroll
    for (int r = 0; r < 4; ++r) {
        const int row0 = b0 + wm * 32 + lg * 4 + r;
        out[(size_t)row0 * DOUT + col]             = acc00[r] + bb0;
        out[(size_t)row0 * DOUT + col + 16]        = acc01[r] + bb1;
        out[(size_t)(row0 + 16) * DOUT + col]      = acc10[r] + bb0;
        out[(size_t)(row0 + 16) * DOUT + col + 16] = acc11[r] + bb1;
    }
}

// ---------------------------------------------------------------------------
// Workspace layout (bytes):
//   [0,        2097152)   AF  : float[4096][128]
//   [2097152,  3145728)   LF  : float[4096][64]
//   [3145728, +8519680)   WT  : ushort[512][8320]
// Fully rewritten before use each launch -> deterministic.
// ---------------------------------------------------------------------------
extern "C" void kernel_launch(void* const* d_in, const int* in_sizes, int n_in,
                              void* d_out, int out_size, void* d_ws, size_t ws_size,
                              hipStream_t stream)
{
    const float* LT   = (const float*)d_in[0];
    const float* Kg   = (const float*)d_in[1];
    const float* AT   = (const float*)d_in[2];
    const float* ug   = (const float*)d_in[3];
    const float* eg   = (const float*)d_in[4];
    const float* bg   = (const float*)d_in[5];
    const int*   msp  = (const int*)d_in[6];
    float* out = (float*)d_out;

    char* ws = (char*)d_ws;
    float*  AFw = (float*)(ws);
    float*  LFw = (float*)(ws + 2097152);
    ushort* WTw = (ushort*)(ws + 3145728);

    solve_chain<<<dim3(512), dim3(256), 0, stream>>>(LT, Kg, AT, msp, AFw, LFw);
    prep_wt<<<dim3(130, 8), dim3(256), 0, stream>>>(Kg, ug, eg, WTw);

    out_gemm_rank1<<<dim3(512), dim3(256), 0, stream>>>(AFw, LFw, WTw, bg, out);
}

// Round 8
// 116.417 us; speedup vs baseline: 10.8879x; 1.6977x over previous
//
#include <hip/hip_runtime.h>

// Problem constants
#define B_ROWS 4096
#define DIN 64
#define NH 128
#define DOUT 512
#define ROWS_PER_BLK 16
#define MAXSTEP_CAP 1000

typedef __attribute__((ext_vector_type(8))) short short8;
typedef __attribute__((ext_vector_type(4))) float f32x4;
typedef __attribute__((ext_vector_type(4))) unsigned u32x4;

// round-to-nearest-even f32 -> bf16, packed pair into a uint
__device__ inline unsigned bf16pair(float lo, float hi) {
    unsigned a = __float_as_uint(lo), b = __float_as_uint(hi);
    a = (a + 0x7fffu + ((a >> 16) & 1u)) >> 16;
    b = (b + 0x7fffu + ((b >> 16) & 1u)) >> 16;
    return a | (b << 16);
}

__device__ inline float frcp(float x) { return __builtin_amdgcn_rcpf(x); }
__device__ inline short8 as_s8(u32x4 v) { return __builtin_bit_cast(short8, v); }

// split x (8 f32) into hi = bf16(x), lo = bf16(x - hi)
__device__ inline void split8v(f32x4 a, f32x4 b, short8& hi, short8& lo) {
    float x[8] = {a[0], a[1], a[2], a[3], b[0], b[1], b[2], b[3]};
    unsigned hb[8]; float rs[8];
    #pragma unroll
    for (int j = 0; j < 8; ++j) {
        unsigned u = __float_as_uint(x[j]);
        unsigned h = (u + 0x7fffu + ((u >> 16) & 1u)) & 0xffff0000u;
        hb[j] = h >> 16;
        rs[j] = x[j] - __uint_as_float(h);
    }
    uint4 hv, lv;
    hv.x = hb[0] | (hb[1] << 16); hv.y = hb[2] | (hb[3] << 16);
    hv.z = hb[4] | (hb[5] << 16); hv.w = hb[6] | (hb[7] << 16);
    lv.x = bf16pair(rs[0], rs[1]); lv.y = bf16pair(rs[2], rs[3]);
    lv.z = bf16pair(rs[4], rs[5]); lv.w = bf16pair(rs[6], rs[7]);
    hi = *reinterpret_cast<short8*>(&hv);
    lo = *reinterpret_cast<short8*>(&lv);
}

// issue 8 global_load_dwordx4 for one B-tile (frag-contiguous layout):
// buf[f] <- 16B at ptr + f*1024 (+ lane*16 baked into ptr). asm-tied regs
// FORCE the double-buffer to stay resident (round-7: compiler dropped it
// at VGPR=64 and serialized). offset imm is 13-bit signed -> split at 4096.
#define ISSUE_TILE(buf, ptr) do {                                                          \
    const char* _p  = (ptr);                                                               \
    const char* _p2 = _p + 4096;                                                           \
    asm volatile("global_load_dwordx4 %0, %1, off"             : "=v"(buf[0]) : "v"(_p));  \
    asm volatile("global_load_dwordx4 %0, %1, off offset:1024" : "=v"(buf[1]) : "v"(_p));  \
    asm volatile("global_load_dwordx4 %0, %1, off offset:2048" : "=v"(buf[2]) : "v"(_p));  \
    asm volatile("global_load_dwordx4 %0, %1, off offset:3072" : "=v"(buf[3]) : "v"(_p));  \
    asm volatile("global_load_dwordx4 %0, %1, off"             : "=v"(buf[4]) : "v"(_p2)); \
    asm volatile("global_load_dwordx4 %0, %1, off offset:1024" : "=v"(buf[5]) : "v"(_p2)); \
    asm volatile("global_load_dwordx4 %0, %1, off offset:2048" : "=v"(buf[6]) : "v"(_p2)); \
    asm volatile("global_load_dwordx4 %0, %1, off offset:3072" : "=v"(buf[7]) : "v"(_p2)); \
} while (0)

// counted wait + scheduling fence (rule #18: MFMA can hoist past bare waitcnt)
#define WAIT_VM(N) do {                                  \
    asm volatile("s_waitcnt vmcnt(" #N ")");             \
    __builtin_amdgcn_sched_barrier(0);                   \
} while (0)

// ---------------------------------------------------------------------------
// Kernel A: fixed-point solve via split-bf16 MFMA iterations (round 6, ~45us).
// Blocks 0..255: AF-chain; 256..511: LF-chain. Local tol 5e-5 on the bf16-K
// map, then 3 exact-f32 refinement iterations. Validated: absmax 0.25.
// ---------------------------------------------------------------------------
__global__ __launch_bounds__(256, 2)
void solve_chain(const float* __restrict__ LT, const float* __restrict__ Kg,
                 const float* __restrict__ AT, const int* __restrict__ msp,
                 float* __restrict__ AFout, float* __restrict__ LFout)
{
    __shared__ float Ksf[DIN][132];   // f32 relu(K) for refinement
    __shared__ float sX[16][132];     // state (AF: 128 cols, LF: 64 cols)
    __shared__ float sY[16][132];     // intermediate (Ldi: 64, Adi: 128)
    __shared__ float wred[4];

    const int tid = threadIdx.x;
    const int lane = tid & 63, w = tid >> 6;
    const int lr = lane & 15, lg = lane >> 4;
    const int bid = blockIdx.x & 255;
    const bool isL = blockIdx.x >= 256;
    const int b0row = bid * ROWS_PER_BLK;

    for (int idx = tid; idx < DIN * NH; idx += 256) {
        int i = idx >> 7, h = idx & 127;
        Ksf[i][h] = fmaxf(Kg[idx], 0.0f);
    }
    for (int idx = tid; idx < 16 * 132; idx += 256)
        (&sX[0][0])[idx] = 0.0f;

    int max_step = *msp;
    if (max_step > MAXSTEP_CAP) max_step = MAXSTEP_CAP;

    short8 Bk[4];      // B[k=h][col=i]: K[16w+lr][ks*32+lg*8 + j]
    #pragma unroll
    for (int ks = 0; ks < 4; ++ks) {
        const float* p = &Kg[(16 * w + lr) * NH + ks * 32 + lg * 8];
        float4 f0 = *reinterpret_cast<const float4*>(p);
        float4 f1 = *reinterpret_cast<const float4*>(p + 4);
        uint4 v;
        v.x = bf16pair(fmaxf(f0.x, 0.f), fmaxf(f0.y, 0.f));
        v.y = bf16pair(fmaxf(f0.z, 0.f), fmaxf(f0.w, 0.f));
        v.z = bf16pair(fmaxf(f1.x, 0.f), fmaxf(f1.y, 0.f));
        v.w = bf16pair(fmaxf(f1.z, 0.f), fmaxf(f1.w, 0.f));
        Bk[ks] = *reinterpret_cast<short8*>(&v);
    }
    short8 Bt[2][2];   // B[k=i][col=h]: K[ks*32+lg*8+j][32w+16t+lr]
    #pragma unroll
    for (int t = 0; t < 2; ++t)
        #pragma unroll
        for (int ks = 0; ks < 2; ++ks) {
            float xx[8];
            #pragma unroll
            for (int j = 0; j < 8; ++j)
                xx[j] = fmaxf(Kg[(ks * 32 + lg * 8 + j) * NH + 32 * w + 16 * t + lr], 0.f);
            uint4 v;
            v.x = bf16pair(xx[0], xx[1]); v.y = bf16pair(xx[2], xx[3]);
            v.z = bf16pair(xx[4], xx[5]); v.w = bf16pair(xx[6], xx[7]);
            Bt[t][ks] = *reinterpret_cast<short8*>(&v);
        }

    float ltv[4];
    #pragma unroll
    for (int r = 0; r < 4; ++r)
        ltv[r] = LT[(size_t)(b0row + lg * 4 + r) * DIN + 16 * w + lr];
    float atv[2];
    #pragma unroll
    for (int t = 0; t < 2; ++t)
        atv[t] = fmaxf(AT[32 * w + 16 * t + lr], 0.f);

    __syncthreads();

    int step = 0;
    bool done = false;

    if (!isL) {
        // ================= AF chain (MFMA loop) =================
        float prevA[2][4] = {};
        while (step < max_step && !done) {
            f32x4 acc1 = {0.f, 0.f, 0.f, 0.f};
            #pragma unroll
            for (int ks = 0; ks < 4; ++ks) {
                f32x4 a = *reinterpret_cast<const f32x4*>(&sX[lr][ks * 32 + lg * 8]);
                f32x4 b = *reinterpret_cast<const f32x4*>(&sX[lr][ks * 32 + lg * 8 + 4]);
                short8 hi, lo; split8v(a, b, hi, lo);
                acc1 = __builtin_amdgcn_mfma_f32_16x16x32_bf16(hi, Bk[ks], acc1, 0, 0, 0);
                acc1 = __builtin_amdgcn_mfma_f32_16x16x32_bf16(lo, Bk[ks], acc1, 0, 0, 0);
            }
            #pragma unroll
            for (int r = 0; r < 4; ++r)
                sY[lg * 4 + r][16 * w + lr] = ltv[r] * frcp(acc1[r] + 1.0f);
            __syncthreads();
            short8 ahi[2], alo[2];
            #pragma unroll
            for (int ks = 0; ks < 2; ++ks) {
                f32x4 a = *reinterpret_cast<const f32x4*>(&sY[lr][ks * 32 + lg * 8]);
                f32x4 b = *reinterpret_cast<const f32x4*>(&sY[lr][ks * 32 + lg * 8 + 4]);
                split8v(a, b, ahi[ks], alo[ks]);
            }
            float diff = 0.0f;
            #pragma unroll
            for (int t = 0; t < 2; ++t) {
                f32x4 acc2 = {0.f, 0.f, 0.f, 0.f};
                #pragma unroll
                for (int ks = 0; ks < 2; ++ks) {
                    acc2 = __builtin_amdgcn_mfma_f32_16x16x32_bf16(ahi[ks], Bt[t][ks], acc2, 0, 0, 0);
                    acc2 = __builtin_amdgcn_mfma_f32_16x16x32_bf16(alo[ks], Bt[t][ks], acc2, 0, 0, 0);
                }
                #pragma unroll
                for (int r = 0; r < 4; ++r) {
                    float v = atv[t] * frcp(acc2[r] + 1.0f);
                    diff = fmaxf(diff, fabsf(v - prevA[t][r]) * frcp(prevA[t][r] + 1e-5f));
                    prevA[t][r] = v;
                    sX[lg * 4 + r][32 * w + 16 * t + lr] = v;
                }
            }
            #pragma unroll
            for (int off = 32; off; off >>= 1)
                diff = fmaxf(diff, __shfl_xor(diff, off));
            if (lane == 0) wred[w] = diff;
            __syncthreads();
            done = fmaxf(fmaxf(wred[0], wred[1]), fmaxf(wred[2], wred[3])) < 5e-5f;
            ++step;
        }
        float af0[4], af1[4], ltr[4];
        #pragma unroll
        for (int r = 0; r < 4; ++r) {
            af0[r] = sX[(w << 2) + r][lane];
            af1[r] = sX[(w << 2) + r][64 + lane];
            ltr[r] = LT[(size_t)(b0row + (w << 2) + r) * DIN + lane];
        }
        const float at0 = fmaxf(AT[lane], 0.f), at1 = fmaxf(AT[64 + lane], 0.f);
        __syncthreads();
        for (int it = 0; it < 3; ++it) {
            #pragma unroll
            for (int r = 0; r < 4; ++r) {
                int s = (w << 2) + r;
                sX[s][lane] = af0[r];
                sX[s][64 + lane] = af1[r];
            }
            __syncthreads();
            float s1[4] = {0.f, 0.f, 0.f, 0.f};
            const f32x4* Kr4 = reinterpret_cast<const f32x4*>(&Ksf[lane][0]);
            #pragma unroll 8
            for (int c = 0; c < 32; ++c) {
                f32x4 k4 = Kr4[c];
                #pragma unroll
                for (int r = 0; r < 4; ++r) {
                    f32x4 a4 = *reinterpret_cast<const f32x4*>(&sX[(w << 2) + r][c << 2]);
                    s1[r] += k4[0]*a4[0] + k4[1]*a4[1] + k4[2]*a4[2] + k4[3]*a4[3];
                }
            }
            #pragma unroll
            for (int r = 0; r < 4; ++r)
                sY[(w << 2) + r][lane] = ltr[r] * frcp(s1[r] + 1.0f);
            __syncthreads();
            float s2a[4] = {0.f,0.f,0.f,0.f}, s2b[4] = {0.f,0.f,0.f,0.f};
            #pragma unroll 4
            for (int i4 = 0; i4 < 16; ++i4) {
                f32x4 yb[4];
                #pragma unroll
                for (int r = 0; r < 4; ++r)
                    yb[r] = *reinterpret_cast<const f32x4*>(&sY[(w << 2) + r][i4 << 2]);
                #pragma unroll
                for (int j = 0; j < 4; ++j) {
                    int i = (i4 << 2) + j;
                    float k0 = Ksf[i][lane], k1 = Ksf[i][64 + lane];
                    #pragma unroll
                    for (int r = 0; r < 4; ++r) {
                        s2a[r] += k0 * yb[r][j];
                        s2b[r] += k1 * yb[r][j];
                    }
                }
            }
            #pragma unroll
            for (int r = 0; r < 4; ++r) {
                af0[r] = at0 * frcp(s2a[r] + 1.0f);
                af1[r] = at1 * frcp(s2b[r] + 1.0f);
            }
            __syncthreads();
        }
        #pragma unroll
        for (int r = 0; r < 4; ++r) {
            int row = b0row + (w << 2) + r;
            AFout[row * NH + lane]      = af0[r];
            AFout[row * NH + 64 + lane] = af1[r];
        }
    } else {
        // ================= LF chain (MFMA loop) =================
        float prevL[4] = {};
        while (step < max_step && !done) {
            short8 ahi[2], alo[2];
            #pragma unroll
            for (int ks = 0; ks < 2; ++ks) {
                f32x4 a = *reinterpret_cast<const f32x4*>(&sX[lr][ks * 32 + lg * 8]);
                f32x4 b = *reinterpret_cast<const f32x4*>(&sX[lr][ks * 32 + lg * 8 + 4]);
                split8v(a, b, ahi[ks], alo[ks]);
            }
            #pragma unroll
            for (int t = 0; t < 2; ++t) {
                f32x4 acc3 = {0.f, 0.f, 0.f, 0.f};
                #pragma unroll
                for (int ks = 0; ks < 2; ++ks) {
                    acc3 = __builtin_amdgcn_mfma_f32_16x16x32_bf16(ahi[ks], Bt[t][ks], acc3, 0, 0, 0);
                    acc3 = __builtin_amdgcn_mfma_f32_16x16x32_bf16(alo[ks], Bt[t][ks], acc3, 0, 0, 0);
                }
                #pragma unroll
                for (int r = 0; r < 4; ++r)
                    sY[lg * 4 + r][32 * w + 16 * t + lr] = atv[t] * frcp(acc3[r] + 1.0f);
            }
            __syncthreads();
            f32x4 acc4 = {0.f, 0.f, 0.f, 0.f};
            #pragma unroll
            for (int ks = 0; ks < 4; ++ks) {
                f32x4 a = *reinterpret_cast<const f32x4*>(&sY[lr][ks * 32 + lg * 8]);
                f32x4 b = *reinterpret_cast<const f32x4*>(&sY[lr][ks * 32 + lg * 8 + 4]);
                short8 hi, lo; split8v(a, b, hi, lo);
                acc4 = __builtin_amdgcn_mfma_f32_16x16x32_bf16(hi, Bk[ks], acc4, 0, 0, 0);
                acc4 = __builtin_amdgcn_mfma_f32_16x16x32_bf16(lo, Bk[ks], acc4, 0, 0, 0);
            }
            float diff = 0.0f;
            #pragma unroll
            for (int r = 0; r < 4; ++r) {
                float v = ltv[r] * frcp(acc4[r] + 1.0f);
                diff = fmaxf(diff, fabsf(v - prevL[r]) * frcp(prevL[r] + 1e-5f));
                prevL[r] = v;
                sX[lg * 4 + r][16 * w + lr] = v;
            }
            #pragma unroll
            for (int off = 32; off; off >>= 1)
                diff = fmaxf(diff, __shfl_xor(diff, off));
            if (lane == 0) wred[w] = diff;
            __syncthreads();
            done = fmaxf(fmaxf(wred[0], wred[1]), fmaxf(wred[2], wred[3])) < 5e-5f;
            ++step;
        }
        float lf[4], ltr[4];
        #pragma unroll
        for (int r = 0; r < 4; ++r) {
            lf[r]  = sX[(w << 2) + r][lane];
            ltr[r] = LT[(size_t)(b0row + (w << 2) + r) * DIN + lane];
        }
        const float at0 = fmaxf(AT[lane], 0.f), at1 = fmaxf(AT[64 + lane], 0.f);
        __syncthreads();
        for (int it = 0; it < 3; ++it) {
            #pragma unroll
            for (int r = 0; r < 4; ++r)
                sX[(w << 2) + r][lane] = lf[r];
            __syncthreads();
            float s3a[4] = {0.f,0.f,0.f,0.f}, s3b[4] = {0.f,0.f,0.f,0.f};
            #pragma unroll 4
            for (int i4 = 0; i4 < 16; ++i4) {
                f32x4 xb[4];
                #pragma unroll
                for (int r = 0; r < 4; ++r)
                    xb[r] = *reinterpret_cast<const f32x4*>(&sX[(w << 2) + r][i4 << 2]);
                #pragma unroll
                for (int j = 0; j < 4; ++j) {
                    int i = (i4 << 2) + j;
                    float k0 = Ksf[i][lane], k1 = Ksf[i][64 + lane];
                    #pragma unroll
                    for (int r = 0; r < 4; ++r) {
                        s3a[r] += k0 * xb[r][j];
                        s3b[r] += k1 * xb[r][j];
                    }
                }
            }
            #pragma unroll
            for (int r = 0; r < 4; ++r) {
                int s = (w << 2) + r;
                sY[s][lane]      = at0 * frcp(s3a[r] + 1.0f);
                sY[s][64 + lane] = at1 * frcp(s3b[r] + 1.0f);
            }
            __syncthreads();
            float s4[4] = {0.f, 0.f, 0.f, 0.f};
            const f32x4* Kr4 = reinterpret_cast<const f32x4*>(&Ksf[lane][0]);
            #pragma unroll 8
            for (int c = 0; c < 32; ++c) {
                f32x4 k4 = Kr4[c];
                #pragma unroll
                for (int r = 0; r < 4; ++r) {
                    f32x4 a4 = *reinterpret_cast<const f32x4*>(&sY[(w << 2) + r][c << 2]);
                    s4[r] += k4[0]*a4[0] + k4[1]*a4[1] + k4[2]*a4[2] + k4[3]*a4[3];
                }
            }
            #pragma unroll
            for (int r = 0; r < 4; ++r)
                lf[r] = ltr[r] * frcp(s4[r] + 1.0f);
            __syncthreads();
        }
        #pragma unroll
        for (int r = 0; r < 4; ++r) {
            int row = b0row + (w << 2) + r;
            LFout[row * DIN + lane] = lf[r];
        }
    }
}

// ---------------------------------------------------------------------------
// Kernel P (v2): write W in FRAGMENT-CONTIGUOUS order.
// WT2 byte layout: ((ot*65 + i)*16 + wn*8 + f)*1024 + lane*16, holding
//   value[k][o] with k = i*128 + (f&3)*32 + (lane>>4)*8 + j,
//                 o = ot*64 + wn*32 + (f>>2)*16 + (lane&15),
//   value = relu(K[k])*u[k][o] (i<64)  |  e[h][o], h=k-8192 (i==64).
// One wave load in the GEMM = one contiguous 1KB block (was 16 scattered
// 64B lines). Grid (65, 8), 256 threads, LDS 128x68 f32 tile.
// ---------------------------------------------------------------------------
__global__ __launch_bounds__(256, 2)
void prep_wt2(const float* __restrict__ Kg, const float* __restrict__ ug,
              const float* __restrict__ eg, ushort* __restrict__ WT2)
{
    __shared__ float tile[128][68];
    const int t = threadIdx.x;
    const int i = blockIdx.x;        // 0..64
    const int ot = blockIdx.y;       // 0..7
    const int k0 = i * 128;
    const bool mn = (i < 64);

    {   // stage 128 k-rows x 64 o-cols, scaled
        const int r = t >> 1, c0 = (t & 1) * 32;
        const float* src = mn ? &ug[(size_t)(k0 + r) * DOUT + ot * 64 + c0]
                              : &eg[(size_t)r * DOUT + ot * 64 + c0];
        const float sc = mn ? fmaxf(Kg[k0 + r], 0.0f) : 1.0f;
        #pragma unroll
        for (int g = 0; g < 8; ++g) {
            float4 v = *reinterpret_cast<const float4*>(src + g * 4);
            v.x *= sc; v.y *= sc; v.z *= sc; v.w *= sc;
            *reinterpret_cast<float4*>(&tile[r][c0 + g * 4]) = v;
        }
    }
    __syncthreads();

    {   // emit 16 fragment-blocks of 1KB; thread t -> wnf = t>>4, 4 lanes each
        const int wnf = t >> 4;                 // wn*8 + f
        const int f = wnf & 7;
        const int wn = wnf >> 3;
        const int ks = f & 3, n = (f >> 2) & 1;
        ushort* dst = WT2 + ((size_t)(ot * 65 + i) * 16 + wnf) * 512;  // *1024B
        #pragma unroll
        for (int q = 0; q < 4; ++q) {
            const int l = (t & 15) * 4 + q;
            const int rb = ks * 32 + (l >> 4) * 8;
            const int c  = wn * 32 + n * 16 + (l & 15);
            uint4 v;
            v.x = bf16pair(tile[rb + 0][c], tile[rb + 1][c]);
            v.y = bf16pair(tile[rb + 2][c], tile[rb + 3][c]);
            v.z = bf16pair(tile[rb + 4][c], tile[rb + 5][c]);
            v.w = bf16pair(tile[rb + 6][c], tile[rb + 7][c]);
            *reinterpret_cast<uint4*>(dst + l * 8) = v;
        }
    }
}

// ---------------------------------------------------------------------------
// Kernel B (v5): rank-1 + asm-pipelined B-stream.
//   out[b,o] = sum_i LF[b,i] * (AF[b,:] @ W_i[:,o]) + e-term + bias
// Round-7 failure: VGPR=64 proved the compiler dropped the double-buffer and
// serialized load->use. Fix: asm-tied register buffers (ISSUE_TILE) + counted
// s_waitcnt vmcnt(8) + sched_barrier(0). WT2 fragment layout makes every load
// a contiguous 1KB wave access. No __syncthreads in the main loop.
// ---------------------------------------------------------------------------
__global__ __launch_bounds__(256, 2)
void out_gemm_rank1(const float* __restrict__ AFw, const float* __restrict__ LFw,
                    const ushort* __restrict__ WT2, const float* __restrict__ bg,
                    float* __restrict__ out)
{
    __shared__ __align__(16) ushort AFb[64][136];
    __shared__ __align__(16) float  LFt[64][68];

    const int t = threadIdx.x;
    const int ot = blockIdx.x & 7;
    const int b0 = (blockIdx.x >> 3) * 64, o0 = ot * 64;
    const int w = t >> 6, l = t & 63;
    const int wm = w >> 1, wn = w & 1;       // 2x2 wave grid, wave-tile 32x32
    const int lr = l & 15, lg = l >> 4;

    // ---- prologue: AF (bf16) + LF^T (f32) to LDS, ONE barrier ----
    {
        const int row = t >> 2, q = t & 3;
        const float4* srcA = reinterpret_cast<const float4*>(
            &AFw[(size_t)(b0 + row) * NH + q * 32]);
        #pragma unroll
        for (int g = 0; g < 4; ++g) {
            float4 fa = srcA[2 * g], fb = srcA[2 * g + 1];
            uint4 wv;
            wv.x = bf16pair(fa.x, fa.y); wv.y = bf16pair(fa.z, fa.w);
            wv.z = bf16pair(fb.x, fb.y); wv.w = bf16pair(fb.z, fb.w);
            *reinterpret_cast<uint4*>(&AFb[row][q * 32 + g * 8]) = wv;
        }
        const f32x4* srcL = reinterpret_cast<const f32x4*>(
            &LFw[(size_t)(b0 + row) * DIN + q * 16]);
        #pragma unroll
        for (int g = 0; g < 4; ++g) {
            f32x4 fv = srcL[g];
            #pragma unroll
            for (int j = 0; j < 4; ++j)
                LFt[q * 16 + g * 4 + j][row] = fv[j];
        }
    }
    __syncthreads();   // the ONLY barrier

    // per-(wave,lane) base into WT2: tile i at base + i*16384, frag f at +f*1024
    const char* base = reinterpret_cast<const char*>(WT2)
        + ((size_t)(ot * 65) * 16 + wn * 8) * 1024 + l * 16;

    u32x4 bA[8], bB[8];
    ISSUE_TILE(bA, base);              // tile 0 in flight

    // ---- A-fragments in registers for the whole loop ----
    short8 afr0[4], afr1[4];
    #pragma unroll
    for (int ks = 0; ks < 4; ++ks) {
        afr0[ks] = *reinterpret_cast<const short8*>(&AFb[wm * 32 +      lr][ks * 32 + lg * 8]);
        afr1[ks] = *reinterpret_cast<const short8*>(&AFb[wm * 32 + 16 + lr][ks * 32 + lg * 8]);
    }

    f32x4 acc00 = {0.f,0.f,0.f,0.f}, acc01 = acc00, acc10 = acc00, acc11 = acc00;
    f32x4 t00, t01, t10, t11;

    auto computeI = [&](const u32x4* bf) {
        t00 = (f32x4){0.f,0.f,0.f,0.f}; t01 = t00; t10 = t00; t11 = t00;
        #pragma unroll
        for (int ks = 0; ks < 4; ++ks) {
            short8 b0v = as_s8(bf[ks]);
            short8 b1v = as_s8(bf[4 + ks]);
            t00 = __builtin_amdgcn_mfma_f32_16x16x32_bf16(afr0[ks], b0v, t00, 0, 0, 0);
            t10 = __builtin_amdgcn_mfma_f32_16x16x32_bf16(afr1[ks], b0v, t10, 0, 0, 0);
            t01 = __builtin_amdgcn_mfma_f32_16x16x32_bf16(afr0[ks], b1v, t01, 0, 0, 0);
            t11 = __builtin_amdgcn_mfma_f32_16x16x32_bf16(afr1[ks], b1v, t11, 0, 0, 0);
        }
    };
    auto scaleAdd = [&](int i) {
        f32x4 lf0 = *reinterpret_cast<const f32x4*>(&LFt[i][wm * 32 +      lg * 4]);
        f32x4 lf1 = *reinterpret_cast<const f32x4*>(&LFt[i][wm * 32 + 16 + lg * 4]);
        #pragma unroll
        for (int r = 0; r < 4; ++r) {
            acc00[r] += lf0[r] * t00[r];
            acc01[r] += lf0[r] * t01[r];
            acc10[r] += lf1[r] * t10[r];
            acc11[r] += lf1[r] * t11[r];
        }
    };

    // i = 0..63 (LF-scaled), i = 64 (e-term). 2-deep asm pipeline:
    // steady state keeps 16 loads outstanding; vmcnt(8) = prev tile complete.
    #pragma unroll 1
    for (int i = 0; i < 64; i += 2) {
        ISSUE_TILE(bB, base + (size_t)(i + 1) * 16384);
        WAIT_VM(8);
        computeI(bA);
        scaleAdd(i);
        ISSUE_TILE(bA, base + (size_t)(i + 2) * 16384);   // i=62 -> tile 64
        WAIT_VM(8);
        computeI(bB);
        scaleAdd(i + 1);
    }
    WAIT_VM(0);
    computeI(bA);      // i = 64: e-term, scale 1
    #pragma unroll
    for (int r = 0; r < 4; ++r) {
        acc00[r] += t00[r];
        acc01[r] += t01[r];
        acc10[r] += t10[r];
        acc11[r] += t11[r];
    }

    // ---- epilogue: bias + store ----
    const int col = o0 + wn * 32 + lr;
    const float bb0 = bg[col], bb1 = bg[col + 16];
    #pragma unroll
    for (int r = 0; r < 4; ++r) {
        const int row0 = b0 + wm * 32 + lg * 4 + r;
        out[(size_t)row0 * DOUT + col]             = acc00[r] + bb0;
        out[(size_t)row0 * DOUT + col + 16]        = acc01[r] + bb1;
        out[(size_t)(row0 + 16) * DOUT + col]      = acc10[r] + bb0;
        out[(size_t)(row0 + 16) * DOUT + col + 16] = acc11[r] + bb1;
    }
}

// ---------------------------------------------------------------------------
// Workspace layout (bytes):
//   [0,        2097152)   AF  : float[4096][128]
//   [2097152,  3145728)   LF  : float[4096][64]
//   [3145728, +8519680)   WT2 : fragment-ordered bf16 W (8 o-tiles x 65 x 16KB)
// Fully rewritten before use each launch -> deterministic.
// ---------------------------------------------------------------------------
extern "C" void kernel_launch(void* const* d_in, const int* in_sizes, int n_in,
                              void* d_out, int out_size, void* d_ws, size_t ws_size,
                              hipStream_t stream)
{
    const float* LT   = (const float*)d_in[0];
    const float* Kg   = (const float*)d_in[1];
    const float* AT   = (const float*)d_in[2];
    const float* ug   = (const float*)d_in[3];
    const float* eg   = (const float*)d_in[4];
    const float* bg   = (const float*)d_in[5];
    const int*   msp  = (const int*)d_in[6];
    float* out = (float*)d_out;

    char* ws = (char*)d_ws;
    float*  AFw = (float*)(ws);
    float*  LFw = (float*)(ws + 2097152);
    ushort* WT2 = (ushort*)(ws + 3145728);

    solve_chain<<<dim3(512), dim3(256), 0, stream>>>(LT, Kg, AT, msp, AFw, LFw);
    prep_wt2<<<dim3(65, 8), dim3(256), 0, stream>>>(Kg, ug, eg, WT2);

    out_gemm_rank1<<<dim3(512), dim3(256), 0, stream>>>(AFw, LFw, WT2, bg, out);
}

// Round 9
// 103.718 us; speedup vs baseline: 12.2210x; 1.1224x over previous
//
#include <hip/hip_runtime.h>

// Problem constants
#define B_ROWS 4096
#define DIN 64
#define NH 128
#define DOUT 512
#define ROWS_PER_BLK 16
#define MAXSTEP_CAP 1000

typedef __attribute__((ext_vector_type(8))) short short8;
typedef __attribute__((ext_vector_type(4))) float f32x4;
typedef __attribute__((ext_vector_type(4))) unsigned u32x4;

// round-to-nearest-even f32 -> bf16, packed pair into a uint
__device__ inline unsigned bf16pair(float lo, float hi) {
    unsigned a = __float_as_uint(lo), b = __float_as_uint(hi);
    a = (a + 0x7fffu + ((a >> 16) & 1u)) >> 16;
    b = (b + 0x7fffu + ((b >> 16) & 1u)) >> 16;
    return a | (b << 16);
}

__device__ inline float frcp(float x) { return __builtin_amdgcn_rcpf(x); }
__device__ inline short8 as_s8(u32x4 v) { return __builtin_bit_cast(short8, v); }

// split-at-write: v -> hi=bf16(v), lo=bf16(v-hi). Same rounding as the
// validated split8v (rounds 6-8) -> iteration map numerically identical.
__device__ inline void splitw(float v, ushort* ph, ushort* pl) {
    unsigned u = __float_as_uint(v);
    unsigned uh = (u + 0x7fffu + ((u >> 16) & 1u)) & 0xffff0000u;
    float rs = v - __uint_as_float(uh);
    unsigned ul = __float_as_uint(rs);
    *ph = (ushort)(uh >> 16);
    *pl = (ushort)((ul + 0x7fffu + ((ul >> 16) & 1u)) >> 16);
}
// recombine for the f32 refinement bridge
__device__ inline float cmb(ushort h, ushort l) {
    return __uint_as_float((unsigned)h << 16) + __uint_as_float((unsigned)l << 16);
}

// issue 8 global_load_dwordx4 for one B-tile (frag-contiguous layout)
#define ISSUE_TILE(buf, ptr) do {                                                          \
    const char* _p  = (ptr);                                                               \
    const char* _p2 = _p + 4096;                                                           \
    asm volatile("global_load_dwordx4 %0, %1, off"             : "=v"(buf[0]) : "v"(_p));  \
    asm volatile("global_load_dwordx4 %0, %1, off offset:1024" : "=v"(buf[1]) : "v"(_p));  \
    asm volatile("global_load_dwordx4 %0, %1, off offset:2048" : "=v"(buf[2]) : "v"(_p));  \
    asm volatile("global_load_dwordx4 %0, %1, off offset:3072" : "=v"(buf[3]) : "v"(_p));  \
    asm volatile("global_load_dwordx4 %0, %1, off"             : "=v"(buf[4]) : "v"(_p2)); \
    asm volatile("global_load_dwordx4 %0, %1, off offset:1024" : "=v"(buf[5]) : "v"(_p2)); \
    asm volatile("global_load_dwordx4 %0, %1, off offset:2048" : "=v"(buf[6]) : "v"(_p2)); \
    asm volatile("global_load_dwordx4 %0, %1, off offset:3072" : "=v"(buf[7]) : "v"(_p2)); \
} while (0)

#define WAIT_VM(N) do {                                  \
    asm volatile("s_waitcnt vmcnt(" #N ")");             \
    __builtin_amdgcn_sched_barrier(0);                   \
} while (0)

// ---------------------------------------------------------------------------
// Kernel A (v4): split-bf16 MFMA solve with SPLIT-AT-WRITE state.
// Round-8 diagnosis: VALUBusy 60%, MfmaUtil 4.5% — each wave re-split the
// f32 LDS state per read (6x split8v/wave/iter ~= 2100 VALU/block-iter).
// Now state & intermediate are stored as separate hi/lo bf16 LDS arrays
// (Xh/Xl/Yh/Yl ushort[16][136]): producers split once at write (~10 VALU/val),
// readers are pure ds_read_b128 (zero unpack). Dual accumulators halve the
// MFMA dependency depth; convergence test is rcp-free (|d| < tol*(x+eps)).
// After convergence: 3 exact-f32 refinement iterations (arrays alias the
// ushort pool). Semantics identical to rounds 6-8 (absmax 0.25).
// ---------------------------------------------------------------------------
__global__ __launch_bounds__(256, 2)
void solve_chain(const float* __restrict__ LT, const float* __restrict__ Kg,
                 const float* __restrict__ AT, const int* __restrict__ msp,
                 float* __restrict__ AFout, float* __restrict__ LFout)
{
    __shared__ __align__(16) ushort SB[4][16][136];  // Xh,Xl,Yh,Yl (17.4KB)
    __shared__ float Ksf[DIN][132];                  // f32 relu(K), refinement
    __shared__ float wred[4];

    auto& Xh = SB[0]; auto& Xl = SB[1]; auto& Yh = SB[2]; auto& Yl = SB[3];
    // refinement f32 views alias the pool (used only after the MFMA loop)
    float (*sXf)[132] = reinterpret_cast<float(*)[132]>(&SB[0][0][0]);
    float (*sYf)[132] = reinterpret_cast<float(*)[132]>(&SB[2][0][0]);

    const int tid = threadIdx.x;
    const int lane = tid & 63, w = tid >> 6;
    const int lr = lane & 15, lg = lane >> 4;
    const int bid = blockIdx.x & 255;
    const bool isL = blockIdx.x >= 256;
    const int b0row = bid * ROWS_PER_BLK;
    const float TOL = 5e-5f;

    for (int idx = tid; idx < DIN * NH; idx += 256) {
        int i = idx >> 7, h = idx & 127;
        Ksf[i][h] = fmaxf(Kg[idx], 0.0f);
    }
    // zero X (hi+lo) = first 8704 bytes of SB
    for (int idx = tid; idx < 2176; idx += 256)
        reinterpret_cast<unsigned*>(&SB[0][0][0])[idx] = 0u;

    int max_step = *msp;
    if (max_step > MAXSTEP_CAP) max_step = MAXSTEP_CAP;

    // K~ B-fragments in registers (validated rounds 6-8)
    short8 Bk[4];      // B[k=h][col=i]
    #pragma unroll
    for (int ks = 0; ks < 4; ++ks) {
        const float* p = &Kg[(16 * w + lr) * NH + ks * 32 + lg * 8];
        float4 f0 = *reinterpret_cast<const float4*>(p);
        float4 f1 = *reinterpret_cast<const float4*>(p + 4);
        uint4 v;
        v.x = bf16pair(fmaxf(f0.x, 0.f), fmaxf(f0.y, 0.f));
        v.y = bf16pair(fmaxf(f0.z, 0.f), fmaxf(f0.w, 0.f));
        v.z = bf16pair(fmaxf(f1.x, 0.f), fmaxf(f1.y, 0.f));
        v.w = bf16pair(fmaxf(f1.z, 0.f), fmaxf(f1.w, 0.f));
        Bk[ks] = *reinterpret_cast<short8*>(&v);
    }
    short8 Bt[2][2];   // B[k=i][col=h]
    #pragma unroll
    for (int t = 0; t < 2; ++t)
        #pragma unroll
        for (int ks = 0; ks < 2; ++ks) {
            float xx[8];
            #pragma unroll
            for (int j = 0; j < 8; ++j)
                xx[j] = fmaxf(Kg[(ks * 32 + lg * 8 + j) * NH + 32 * w + 16 * t + lr], 0.f);
            uint4 v;
            v.x = bf16pair(xx[0], xx[1]); v.y = bf16pair(xx[2], xx[3]);
            v.z = bf16pair(xx[4], xx[5]); v.w = bf16pair(xx[6], xx[7]);
            Bt[t][ks] = *reinterpret_cast<short8*>(&v);
        }

    float ltv[4];
    #pragma unroll
    for (int r = 0; r < 4; ++r)
        ltv[r] = LT[(size_t)(b0row + lg * 4 + r) * DIN + 16 * w + lr];
    float atv[2];
    #pragma unroll
    for (int t = 0; t < 2; ++t)
        atv[t] = fmaxf(AT[32 * w + 16 * t + lr], 0.f);

    __syncthreads();

    int step = 0;
    bool done = false;

    if (!isL) {
        // ================= AF chain =================
        float prevA[2][4] = {};
        while (step < max_step && !done) {
            // P1: S1 = X @ K~^T -> Ldi (16x64)
            f32x4 aH = {0.f,0.f,0.f,0.f}, aL = aH;
            #pragma unroll
            for (int ks = 0; ks < 4; ++ks) {
                short8 hi = *reinterpret_cast<const short8*>(&Xh[lr][ks * 32 + lg * 8]);
                short8 lo = *reinterpret_cast<const short8*>(&Xl[lr][ks * 32 + lg * 8]);
                aH = __builtin_amdgcn_mfma_f32_16x16x32_bf16(hi, Bk[ks], aH, 0, 0, 0);
                aL = __builtin_amdgcn_mfma_f32_16x16x32_bf16(lo, Bk[ks], aL, 0, 0, 0);
            }
            #pragma unroll
            for (int r = 0; r < 4; ++r) {
                float v = ltv[r] * frcp(aH[r] + aL[r] + 1.0f);
                splitw(v, &Yh[lg * 4 + r][16 * w + lr], &Yl[lg * 4 + r][16 * w + lr]);
            }
            __syncthreads();
            // P2: S2 = Ldi @ K~ -> AF' (16x128)
            short8 yh0 = *reinterpret_cast<const short8*>(&Yh[lr][lg * 8]);
            short8 yh1 = *reinterpret_cast<const short8*>(&Yh[lr][32 + lg * 8]);
            short8 yl0 = *reinterpret_cast<const short8*>(&Yl[lr][lg * 8]);
            short8 yl1 = *reinterpret_cast<const short8*>(&Yl[lr][32 + lg * 8]);
            float flag = -1.0f;
            #pragma unroll
            for (int t = 0; t < 2; ++t) {
                f32x4 bH = {0.f,0.f,0.f,0.f}, bL = bH;
                bH = __builtin_amdgcn_mfma_f32_16x16x32_bf16(yh0, Bt[t][0], bH, 0, 0, 0);
                bL = __builtin_amdgcn_mfma_f32_16x16x32_bf16(yl0, Bt[t][0], bL, 0, 0, 0);
                bH = __builtin_amdgcn_mfma_f32_16x16x32_bf16(yh1, Bt[t][1], bH, 0, 0, 0);
                bL = __builtin_amdgcn_mfma_f32_16x16x32_bf16(yl1, Bt[t][1], bL, 0, 0, 0);
                #pragma unroll
                for (int r = 0; r < 4; ++r) {
                    float v = atv[t] * frcp(bH[r] + bL[r] + 1.0f);
                    float p = prevA[t][r];
                    flag = fmaxf(flag, fabsf(v - p) - TOL * (p + 1e-5f));
                    prevA[t][r] = v;
                    splitw(v, &Xh[lg * 4 + r][32 * w + 16 * t + lr],
                              &Xl[lg * 4 + r][32 * w + 16 * t + lr]);
                }
            }
            #pragma unroll
            for (int off = 32; off; off >>= 1)
                flag = fmaxf(flag, __shfl_xor(flag, off));
            if (lane == 0) wred[w] = flag;
            __syncthreads();
            done = fmaxf(fmaxf(wred[0], wred[1]), fmaxf(wred[2], wred[3])) < 0.0f;
            ++step;
        }
        // bridge to f32 refinement
        float af0[4], af1[4], ltr[4];
        #pragma unroll
        for (int r = 0; r < 4; ++r) {
            af0[r] = cmb(Xh[(w << 2) + r][lane], Xl[(w << 2) + r][lane]);
            af1[r] = cmb(Xh[(w << 2) + r][64 + lane], Xl[(w << 2) + r][64 + lane]);
            ltr[r] = LT[(size_t)(b0row + (w << 2) + r) * DIN + lane];
        }
        const float at0 = fmaxf(AT[lane], 0.f), at1 = fmaxf(AT[64 + lane], 0.f);
        __syncthreads();
        for (int it = 0; it < 3; ++it) {
            #pragma unroll
            for (int r = 0; r < 4; ++r) {
                int s = (w << 2) + r;
                sXf[s][lane] = af0[r];
                sXf[s][64 + lane] = af1[r];
            }
            __syncthreads();
            float s1[4] = {0.f, 0.f, 0.f, 0.f};
            const f32x4* Kr4 = reinterpret_cast<const f32x4*>(&Ksf[lane][0]);
            #pragma unroll 8
            for (int c = 0; c < 32; ++c) {
                f32x4 k4 = Kr4[c];
                #pragma unroll
                for (int r = 0; r < 4; ++r) {
                    f32x4 a4 = *reinterpret_cast<const f32x4*>(&sXf[(w << 2) + r][c << 2]);
                    s1[r] += k4[0]*a4[0] + k4[1]*a4[1] + k4[2]*a4[2] + k4[3]*a4[3];
                }
            }
            __syncthreads();   // all reads of sXf done before sYf (alias-safe)
            #pragma unroll
            for (int r = 0; r < 4; ++r)
                sYf[(w << 2) + r][lane] = ltr[r] * frcp(s1[r] + 1.0f);
            __syncthreads();
            float s2a[4] = {0.f,0.f,0.f,0.f}, s2b[4] = {0.f,0.f,0.f,0.f};
            #pragma unroll 4
            for (int i4 = 0; i4 < 16; ++i4) {
                f32x4 yb[4];
                #pragma unroll
                for (int r = 0; r < 4; ++r)
                    yb[r] = *reinterpret_cast<const f32x4*>(&sYf[(w << 2) + r][i4 << 2]);
                #pragma unroll
                for (int j = 0; j < 4; ++j) {
                    int i = (i4 << 2) + j;
                    float k0 = Ksf[i][lane], k1 = Ksf[i][64 + lane];
                    #pragma unroll
                    for (int r = 0; r < 4; ++r) {
                        s2a[r] += k0 * yb[r][j];
                        s2b[r] += k1 * yb[r][j];
                    }
                }
            }
            #pragma unroll
            for (int r = 0; r < 4; ++r) {
                af0[r] = at0 * frcp(s2a[r] + 1.0f);
                af1[r] = at1 * frcp(s2b[r] + 1.0f);
            }
            __syncthreads();
        }
        #pragma unroll
        for (int r = 0; r < 4; ++r) {
            int row = b0row + (w << 2) + r;
            AFout[row * NH + lane]      = af0[r];
            AFout[row * NH + 64 + lane] = af1[r];
        }
    } else {
        // ================= LF chain =================
        float prevL[4] = {};
        while (step < max_step && !done) {
            // P1: S3 = LF @ K~ -> Adi (16x128)
            short8 xh0 = *reinterpret_cast<const short8*>(&Xh[lr][lg * 8]);
            short8 xh1 = *reinterpret_cast<const short8*>(&Xh[lr][32 + lg * 8]);
            short8 xl0 = *reinterpret_cast<const short8*>(&Xl[lr][lg * 8]);
            short8 xl1 = *reinterpret_cast<const short8*>(&Xl[lr][32 + lg * 8]);
            #pragma unroll
            for (int t = 0; t < 2; ++t) {
                f32x4 bH = {0.f,0.f,0.f,0.f}, bL = bH;
                bH = __builtin_amdgcn_mfma_f32_16x16x32_bf16(xh0, Bt[t][0], bH, 0, 0, 0);
                bL = __builtin_amdgcn_mfma_f32_16x16x32_bf16(xl0, Bt[t][0], bL, 0, 0, 0);
                bH = __builtin_amdgcn_mfma_f32_16x16x32_bf16(xh1, Bt[t][1], bH, 0, 0, 0);
                bL = __builtin_amdgcn_mfma_f32_16x16x32_bf16(xl1, Bt[t][1], bL, 0, 0, 0);
                #pragma unroll
                for (int r = 0; r < 4; ++r) {
                    float v = atv[t] * frcp(bH[r] + bL[r] + 1.0f);
                    splitw(v, &Yh[lg * 4 + r][32 * w + 16 * t + lr],
                              &Yl[lg * 4 + r][32 * w + 16 * t + lr]);
                }
            }
            __syncthreads();
            // P2: S4 = Adi @ K~^T -> LF' (16x64)
            f32x4 aH = {0.f,0.f,0.f,0.f}, aL = aH;
            #pragma unroll
            for (int ks = 0; ks < 4; ++ks) {
                short8 hi = *reinterpret_cast<const short8*>(&Yh[lr][ks * 32 + lg * 8]);
                short8 lo = *reinterpret_cast<const short8*>(&Yl[lr][ks * 32 + lg * 8]);
                aH = __builtin_amdgcn_mfma_f32_16x16x32_bf16(hi, Bk[ks], aH, 0, 0, 0);
                aL = __builtin_amdgcn_mfma_f32_16x16x32_bf16(lo, Bk[ks], aL, 0, 0, 0);
            }
            float flag = -1.0f;
            #pragma unroll
            for (int r = 0; r < 4; ++r) {
                float v = ltv[r] * frcp(aH[r] + aL[r] + 1.0f);
                float p = prevL[r];
                flag = fmaxf(flag, fabsf(v - p) - TOL * (p + 1e-5f));
                prevL[r] = v;
                splitw(v, &Xh[lg * 4 + r][16 * w + lr], &Xl[lg * 4 + r][16 * w + lr]);
            }
            #pragma unroll
            for (int off = 32; off; off >>= 1)
                flag = fmaxf(flag, __shfl_xor(flag, off));
            if (lane == 0) wred[w] = flag;
            __syncthreads();
            done = fmaxf(fmaxf(wred[0], wred[1]), fmaxf(wred[2], wred[3])) < 0.0f;
            ++step;
        }
        // bridge + 3 exact-f32 refinements
        float lf[4], ltr[4];
        #pragma unroll
        for (int r = 0; r < 4; ++r) {
            lf[r]  = cmb(Xh[(w << 2) + r][lane], Xl[(w << 2) + r][lane]);
            ltr[r] = LT[(size_t)(b0row + (w << 2) + r) * DIN + lane];
        }
        const float at0 = fmaxf(AT[lane], 0.f), at1 = fmaxf(AT[64 + lane], 0.f);
        __syncthreads();
        for (int it = 0; it < 3; ++it) {
            #pragma unroll
            for (int r = 0; r < 4; ++r)
                sXf[(w << 2) + r][lane] = lf[r];
            __syncthreads();
            float s3a[4] = {0.f,0.f,0.f,0.f}, s3b[4] = {0.f,0.f,0.f,0.f};
            #pragma unroll 4
            for (int i4 = 0; i4 < 16; ++i4) {
                f32x4 xb[4];
                #pragma unroll
                for (int r = 0; r < 4; ++r)
                    xb[r] = *reinterpret_cast<const f32x4*>(&sXf[(w << 2) + r][i4 << 2]);
                #pragma unroll
                for (int j = 0; j < 4; ++j) {
                    int i = (i4 << 2) + j;
                    float k0 = Ksf[i][lane], k1 = Ksf[i][64 + lane];
                    #pragma unroll
                    for (int r = 0; r < 4; ++r) {
                        s3a[r] += k0 * xb[r][j];
                        s3b[r] += k1 * xb[r][j];
                    }
                }
            }
            #pragma unroll
            for (int r = 0; r < 4; ++r) {
                int s = (w << 2) + r;
                sYf[s][lane]      = at0 * frcp(s3a[r] + 1.0f);
                sYf[s][64 + lane] = at1 * frcp(s3b[r] + 1.0f);
            }
            __syncthreads();
            float s4[4] = {0.f, 0.f, 0.f, 0.f};
            const f32x4* Kr4 = reinterpret_cast<const f32x4*>(&Ksf[lane][0]);
            #pragma unroll 8
            for (int c = 0; c < 32; ++c) {
                f32x4 k4 = Kr4[c];
                #pragma unroll
                for (int r = 0; r < 4; ++r) {
                    f32x4 a4 = *reinterpret_cast<const f32x4*>(&sYf[(w << 2) + r][c << 2]);
                    s4[r] += k4[0]*a4[0] + k4[1]*a4[1] + k4[2]*a4[2] + k4[3]*a4[3];
                }
            }
            #pragma unroll
            for (int r = 0; r < 4; ++r)
                lf[r] = ltr[r] * frcp(s4[r] + 1.0f);
            __syncthreads();
        }
        #pragma unroll
        for (int r = 0; r < 4; ++r) {
            int row = b0row + (w << 2) + r;
            LFout[row * DIN + lane] = lf[r];
        }
    }
}

// ---------------------------------------------------------------------------
// Kernel P (v2): fragment-contiguous W layout (unchanged from round 8).
// ---------------------------------------------------------------------------
__global__ __launch_bounds__(256, 2)
void prep_wt2(const float* __restrict__ Kg, const float* __restrict__ ug,
              const float* __restrict__ eg, ushort* __restrict__ WT2)
{
    __shared__ float tile[128][68];
    const int t = threadIdx.x;
    const int i = blockIdx.x;        // 0..64
    const int ot = blockIdx.y;       // 0..7
    const int k0 = i * 128;
    const bool mn = (i < 64);

    {
        const int r = t >> 1, c0 = (t & 1) * 32;
        const float* src = mn ? &ug[(size_t)(k0 + r) * DOUT + ot * 64 + c0]
                              : &eg[(size_t)r * DOUT + ot * 64 + c0];
        const float sc = mn ? fmaxf(Kg[k0 + r], 0.0f) : 1.0f;
        #pragma unroll
        for (int g = 0; g < 8; ++g) {
            float4 v = *reinterpret_cast<const float4*>(src + g * 4);
            v.x *= sc; v.y *= sc; v.z *= sc; v.w *= sc;
            *reinterpret_cast<float4*>(&tile[r][c0 + g * 4]) = v;
        }
    }
    __syncthreads();

    {
        const int wnf = t >> 4;
        const int f = wnf & 7;
        const int wn = wnf >> 3;
        const int ks = f & 3, n = (f >> 2) & 1;
        ushort* dst = WT2 + ((size_t)(ot * 65 + i) * 16 + wnf) * 512;
        #pragma unroll
        for (int q = 0; q < 4; ++q) {
            const int l = (t & 15) * 4 + q;
            const int rb = ks * 32 + (l >> 4) * 8;
            const int c  = wn * 32 + n * 16 + (l & 15);
            uint4 v;
            v.x = bf16pair(tile[rb + 0][c], tile[rb + 1][c]);
            v.y = bf16pair(tile[rb + 2][c], tile[rb + 3][c]);
            v.z = bf16pair(tile[rb + 4][c], tile[rb + 5][c]);
            v.w = bf16pair(tile[rb + 6][c], tile[rb + 7][c]);
            *reinterpret_cast<uint4*>(dst + l * 8) = v;
        }
    }
}

// ---------------------------------------------------------------------------
// Kernel B (v5): rank-1 + asm-pipelined B-stream (unchanged from round 8).
// ---------------------------------------------------------------------------
__global__ __launch_bounds__(256, 2)
void out_gemm_rank1(const float* __restrict__ AFw, const float* __restrict__ LFw,
                    const ushort* __restrict__ WT2, const float* __restrict__ bg,
                    float* __restrict__ out)
{
    __shared__ __align__(16) ushort AFb[64][136];
    __shared__ __align__(16) float  LFt[64][68];

    const int t = threadIdx.x;
    const int ot = blockIdx.x & 7;
    const int b0 = (blockIdx.x >> 3) * 64, o0 = ot * 64;
    const int w = t >> 6, l = t & 63;
    const int wm = w >> 1, wn = w & 1;
    const int lr = l & 15, lg = l >> 4;

    {
        const int row = t >> 2, q = t & 3;
        const float4* srcA = reinterpret_cast<const float4*>(
            &AFw[(size_t)(b0 + row) * NH + q * 32]);
        #pragma unroll
        for (int g = 0; g < 4; ++g) {
            float4 fa = srcA[2 * g], fb = srcA[2 * g + 1];
            uint4 wv;
            wv.x = bf16pair(fa.x, fa.y); wv.y = bf16pair(fa.z, fa.w);
            wv.z = bf16pair(fb.x, fb.y); wv.w = bf16pair(fb.z, fb.w);
            *reinterpret_cast<uint4*>(&AFb[row][q * 32 + g * 8]) = wv;
        }
        const f32x4* srcL = reinterpret_cast<const f32x4*>(
            &LFw[(size_t)(b0 + row) * DIN + q * 16]);
        #pragma unroll
        for (int g = 0; g < 4; ++g) {
            f32x4 fv = srcL[g];
            #pragma unroll
            for (int j = 0; j < 4; ++j)
                LFt[q * 16 + g * 4 + j][row] = fv[j];
        }
    }
    __syncthreads();

    const char* base = reinterpret_cast<const char*>(WT2)
        + ((size_t)(ot * 65) * 16 + wn * 8) * 1024 + l * 16;

    u32x4 bA[8], bB[8];
    ISSUE_TILE(bA, base);

    short8 afr0[4], afr1[4];
    #pragma unroll
    for (int ks = 0; ks < 4; ++ks) {
        afr0[ks] = *reinterpret_cast<const short8*>(&AFb[wm * 32 +      lr][ks * 32 + lg * 8]);
        afr1[ks] = *reinterpret_cast<const short8*>(&AFb[wm * 32 + 16 + lr][ks * 32 + lg * 8]);
    }

    f32x4 acc00 = {0.f,0.f,0.f,0.f}, acc01 = acc00, acc10 = acc00, acc11 = acc00;
    f32x4 t00, t01, t10, t11;

    auto computeI = [&](const u32x4* bf) {
        t00 = (f32x4){0.f,0.f,0.f,0.f}; t01 = t00; t10 = t00; t11 = t00;
        #pragma unroll
        for (int ks = 0; ks < 4; ++ks) {
            short8 b0v = as_s8(bf[ks]);
            short8 b1v = as_s8(bf[4 + ks]);
            t00 = __builtin_amdgcn_mfma_f32_16x16x32_bf16(afr0[ks], b0v, t00, 0, 0, 0);
            t10 = __builtin_amdgcn_mfma_f32_16x16x32_bf16(afr1[ks], b0v, t10, 0, 0, 0);
            t01 = __builtin_amdgcn_mfma_f32_16x16x32_bf16(afr0[ks], b1v, t01, 0, 0, 0);
            t11 = __builtin_amdgcn_mfma_f32_16x16x32_bf16(afr1[ks], b1v, t11, 0, 0, 0);
        }
    };
    auto scaleAdd = [&](int i) {
        f32x4 lf0 = *reinterpret_cast<const f32x4*>(&LFt[i][wm * 32 +      lg * 4]);
        f32x4 lf1 = *reinterpret_cast<const f32x4*>(&LFt[i][wm * 32 + 16 + lg * 4]);
        #pragma unroll
        for (int r = 0; r < 4; ++r) {
            acc00[r] += lf0[r] * t00[r];
            acc01[r] += lf0[r] * t01[r];
            acc10[r] += lf1[r] * t10[r];
            acc11[r] += lf1[r] * t11[r];
        }
    };

    #pragma unroll 1
    for (int i = 0; i < 64; i += 2) {
        ISSUE_TILE(bB, base + (size_t)(i + 1) * 16384);
        WAIT_VM(8);
        computeI(bA);
        scaleAdd(i);
        ISSUE_TILE(bA, base + (size_t)(i + 2) * 16384);
        WAIT_VM(8);
        computeI(bB);
        scaleAdd(i + 1);
    }
    WAIT_VM(0);
    computeI(bA);      // i = 64: e-term, scale 1
    #pragma unroll
    for (int r = 0; r < 4; ++r) {
        acc00[r] += t00[r];
        acc01[r] += t01[r];
        acc10[r] += t10[r];
        acc11[r] += t11[r];
    }

    const int col = o0 + wn * 32 + lr;
    const float bb0 = bg[col], bb1 = bg[col + 16];
    #pragma unroll
    for (int r = 0; r < 4; ++r) {
        const int row0 = b0 + wm * 32 + lg * 4 + r;
        out[(size_t)row0 * DOUT + col]             = acc00[r] + bb0;
        out[(size_t)row0 * DOUT + col + 16]        = acc01[r] + bb1;
        out[(size_t)(row0 + 16) * DOUT + col]      = acc10[r] + bb0;
        out[(size_t)(row0 + 16) * DOUT + col + 16] = acc11[r] + bb1;
    }
}

// ---------------------------------------------------------------------------
// Workspace layout (bytes):
//   [0,        2097152)   AF  : float[4096][128]
//   [2097152,  3145728)   LF  : float[4096][64]
//   [3145728, +8519680)   WT2 : fragment-ordered bf16 W (8 o-tiles x 65 x 16KB)
// Fully rewritten before use each launch -> deterministic.
// ---------------------------------------------------------------------------
extern "C" void kernel_launch(void* const* d_in, const int* in_sizes, int n_in,
                              void* d_out, int out_size, void* d_ws, size_t ws_size,
                              hipStream_t stream)
{
    const float* LT   = (const float*)d_in[0];
    const float* Kg   = (const float*)d_in[1];
    const float* AT   = (const float*)d_in[2];
    const float* ug   = (const float*)d_in[3];
    const float* eg   = (const float*)d_in[4];
    const float* bg   = (const float*)d_in[5];
    const int*   msp  = (const int*)d_in[6];
    float* out = (float*)d_out;

    char* ws = (char*)d_ws;
    float*  AFw = (float*)(ws);
    float*  LFw = (float*)(ws + 2097152);
    ushort* WT2 = (ushort*)(ws + 3145728);

    solve_chain<<<dim3(512), dim3(256), 0, stream>>>(LT, Kg, AT, msp, AFw, LFw);
    prep_wt2<<<dim3(65, 8), dim3(256), 0, stream>>>(Kg, ug, eg, WT2);

    out_gemm_rank1<<<dim3(512), dim3(256), 0, stream>>>(AFw, LFw, WT2, bg, out);
}

// Round 10
// 83.206 us; speedup vs baseline: 15.2338x; 1.2465x over previous
//
#include <hip/hip_runtime.h>

// Problem constants
#define B_ROWS 4096
#define DIN 64
#define NH 128
#define DOUT 512
#define ROWS_PER_BLK 16
#define MAXSTEP_CAP 1000

typedef __attribute__((ext_vector_type(8))) short short8;
typedef __attribute__((ext_vector_type(4))) float f32x4;
typedef __attribute__((ext_vector_type(4))) unsigned u32x4;

template<int N> struct IC { static constexpr int v = N; };

// round-to-nearest-even f32 -> bf16, packed pair into a uint
__device__ inline unsigned bf16pair(float lo, float hi) {
    unsigned a = __float_as_uint(lo), b = __float_as_uint(hi);
    a = (a + 0x7fffu + ((a >> 16) & 1u)) >> 16;
    b = (b + 0x7fffu + ((b >> 16) & 1u)) >> 16;
    return a | (b << 16);
}
__device__ inline ushort bf16r(float v) {
    unsigned u = __float_as_uint(v);
    return (ushort)((u + 0x7fffu + ((u >> 16) & 1u)) >> 16);
}
__device__ inline float frcp(float x) { return __builtin_amdgcn_rcpf(x); }
__device__ inline short8 as_s8(u32x4 v) { return __builtin_bit_cast(short8, v); }

// split-at-write: v -> hi=bf16(v), lo=bf16(v-hi) (validated rounds 6-9)
__device__ inline void splitw(float v, ushort* ph, ushort* pl) {
    unsigned u = __float_as_uint(v);
    unsigned uh = (u + 0x7fffu + ((u >> 16) & 1u)) & 0xffff0000u;
    float rs = v - __uint_as_float(uh);
    unsigned ul = __float_as_uint(rs);
    *ph = (ushort)(uh >> 16);
    *pl = (ushort)((ul + 0x7fffu + ((ul >> 16) & 1u)) >> 16);
}
// split 8 gathered f32 (after relu) into hi/lo bf16 fragments
__device__ inline void packsplit8(const float* x, short8& h8, short8& l8) {
    unsigned hb[8], lb[8];
    #pragma unroll
    for (int j = 0; j < 8; ++j) {
        float v = fmaxf(x[j], 0.0f);
        unsigned u = __float_as_uint(v);
        unsigned uh = (u + 0x7fffu + ((u >> 16) & 1u)) & 0xffff0000u;
        float rs = v - __uint_as_float(uh);
        unsigned ul = __float_as_uint(rs);
        hb[j] = uh >> 16;
        lb[j] = (ul + 0x7fffu + ((ul >> 16) & 1u)) >> 16;
    }
    uint4 hv, lv;
    hv.x = hb[0] | (hb[1] << 16); hv.y = hb[2] | (hb[3] << 16);
    hv.z = hb[4] | (hb[5] << 16); hv.w = hb[6] | (hb[7] << 16);
    lv.x = lb[0] | (lb[1] << 16); lv.y = lb[2] | (lb[3] << 16);
    lv.z = lb[4] | (lb[5] << 16); lv.w = lb[6] | (lb[7] << 16);
    h8 = *reinterpret_cast<short8*>(&hv);
    l8 = *reinterpret_cast<short8*>(&lv);
}

// issue 8 global_load_dwordx4 for one B-tile (frag-contiguous layout)
#define ISSUE_TILE(buf, ptr) do {                                                          \
    const char* _p  = (ptr);                                                               \
    const char* _p2 = _p + 4096;                                                           \
    asm volatile("global_load_dwordx4 %0, %1, off"             : "=v"(buf[0]) : "v"(_p));  \
    asm volatile("global_load_dwordx4 %0, %1, off offset:1024" : "=v"(buf[1]) : "v"(_p));  \
    asm volatile("global_load_dwordx4 %0, %1, off offset:2048" : "=v"(buf[2]) : "v"(_p));  \
    asm volatile("global_load_dwordx4 %0, %1, off offset:3072" : "=v"(buf[3]) : "v"(_p));  \
    asm volatile("global_load_dwordx4 %0, %1, off"             : "=v"(buf[4]) : "v"(_p2)); \
    asm volatile("global_load_dwordx4 %0, %1, off offset:1024" : "=v"(buf[5]) : "v"(_p2)); \
    asm volatile("global_load_dwordx4 %0, %1, off offset:2048" : "=v"(buf[6]) : "v"(_p2)); \
    asm volatile("global_load_dwordx4 %0, %1, off offset:3072" : "=v"(buf[7]) : "v"(_p2)); \
} while (0)

#define WAIT_VM(N) do {                                  \
    asm volatile("s_waitcnt vmcnt(" #N ")");             \
    __builtin_amdgcn_sched_barrier(0);                   \
} while (0)

// ---------------------------------------------------------------------------
// Kernel A (v5): BOTH chains fused per block + 3 precision phases.
// Grid 256: block b handles rows [16b,16b+16) for the AF chain AND LF chain.
// The chains are independent -> their P1/P2 interleave in each wave's stream
// (2x ILP per barrier interval, half the barriers per chain-iteration vs
// round 9's 512-block layout); K-fragments and per-lane constants shared.
// Phases: (1) cheap (X single-bf16, no lo path; 12 unchecked + checked to
// 6e-3, floor ~3e-3, capped at step 64); (2) mid hi/lo (== validated rounds
// 6-9 arithmetic) to 5e-5; (3) 3 full iterations with split-K 3-term MFMA
// (Xh*Kh + Xl*Kh + Xh*Kl; K accurate to 2^-17) replacing the f32 refinement
// entirely -- the last doubles as the reference's post-loop tracked update.
// Final AF/LF written directly from registers (C-layout scatter).
// ---------------------------------------------------------------------------
__global__ __launch_bounds__(256, 1)
void solve_chain(const float* __restrict__ LT, const float* __restrict__ Kg,
                 const float* __restrict__ AT, const int* __restrict__ msp,
                 float* __restrict__ AFout, float* __restrict__ LFout)
{
    __shared__ __align__(16) ushort AX[2][16][136];  // AF state hi/lo (128 cols)
    __shared__ __align__(16) ushort AY[2][16][136];  // Ldi hi/lo (64 cols)
    __shared__ __align__(16) ushort LX[2][16][136];  // LF state hi/lo (64 cols)
    __shared__ __align__(16) ushort LY[2][16][136];  // Adi hi/lo (128 cols)
    __shared__ float wred[4];

    const int tid = threadIdx.x;
    const int lane = tid & 63, w = tid >> 6;
    const int lr = lane & 15, lg = lane >> 4;
    const int b0row = blockIdx.x * ROWS_PER_BLK;

    // zero X arrays (Y is written before read every iteration; lo of X stays
    // 0 through the cheap phase, which is exactly the cheap representation)
    for (int idx = tid; idx < 2176; idx += 256) {
        reinterpret_cast<unsigned*>(&AX[0][0][0])[idx] = 0u;
        reinterpret_cast<unsigned*>(&LX[0][0][0])[idx] = 0u;
    }

    int max_step = *msp;
    if (max_step > MAXSTEP_CAP) max_step = MAXSTEP_CAP;

    // ---- K fragments (hi + lo) in registers, shared by both chains ----
    short8 BkH[4], BkL[4];   // B[k=h][col=i]: K[16w+lr][ks*32+lg*8+j]
    #pragma unroll
    for (int ks = 0; ks < 4; ++ks) {
        float xx[8];
        const float* p = &Kg[(16 * w + lr) * NH + ks * 32 + lg * 8];
        #pragma unroll
        for (int j = 0; j < 8; ++j) xx[j] = p[j];
        packsplit8(xx, BkH[ks], BkL[ks]);
    }
    short8 BtH[2][2], BtL[2][2];  // B[k=i][col=h]: K[ks*32+lg*8+j][32w+16t+lr]
    #pragma unroll
    for (int t = 0; t < 2; ++t)
        #pragma unroll
        for (int ks = 0; ks < 2; ++ks) {
            float xx[8];
            #pragma unroll
            for (int j = 0; j < 8; ++j)
                xx[j] = Kg[(ks * 32 + lg * 8 + j) * NH + 32 * w + 16 * t + lr];
            packsplit8(xx, BtH[t][ks], BtL[t][ks]);
        }

    float ltv[4];
    #pragma unroll
    for (int r = 0; r < 4; ++r)
        ltv[r] = LT[(size_t)(b0row + lg * 4 + r) * DIN + 16 * w + lr];
    float atv[2];
    #pragma unroll
    for (int t = 0; t < 2; ++t)
        atv[t] = fmaxf(AT[32 * w + 16 * t + lr], 0.f);

    float prevA[2][4] = {};
    float prevL[4] = {};
    bool done = false;

    __syncthreads();

    // one fused iteration of BOTH chains; mode: 0 cheap, 1 mid, 2 full
    auto iterate = [&](auto MC, bool check, float tol) {
        constexpr int mode = decltype(MC)::v;
        // ---------- P1 ----------
        {   // AF chain: Ldi = lt * rcp(X @ Bk + 1)   (16 x 64)
            f32x4 aH = {0.f,0.f,0.f,0.f}, aL = aH;
            #pragma unroll
            for (int ks = 0; ks < 4; ++ks) {
                short8 hi = *reinterpret_cast<const short8*>(&AX[0][lr][ks * 32 + lg * 8]);
                aH = __builtin_amdgcn_mfma_f32_16x16x32_bf16(hi, BkH[ks], aH, 0, 0, 0);
                if (mode >= 1) {
                    short8 lo = *reinterpret_cast<const short8*>(&AX[1][lr][ks * 32 + lg * 8]);
                    aL = __builtin_amdgcn_mfma_f32_16x16x32_bf16(lo, BkH[ks], aL, 0, 0, 0);
                }
                if (mode == 2)
                    aL = __builtin_amdgcn_mfma_f32_16x16x32_bf16(hi, BkL[ks], aL, 0, 0, 0);
            }
            #pragma unroll
            for (int r = 0; r < 4; ++r) {
                float v = ltv[r] * frcp(aH[r] + aL[r] + 1.0f);
                if (mode == 0) AY[0][lg * 4 + r][16 * w + lr] = bf16r(v);
                else splitw(v, &AY[0][lg * 4 + r][16 * w + lr],
                               &AY[1][lg * 4 + r][16 * w + lr]);
            }
        }
        {   // LF chain: Adi = at * rcp(X @ Bt + 1)   (16 x 128)
            short8 xh0 = *reinterpret_cast<const short8*>(&LX[0][lr][lg * 8]);
            short8 xh1 = *reinterpret_cast<const short8*>(&LX[0][lr][32 + lg * 8]);
            short8 xl0, xl1;
            if (mode >= 1) {
                xl0 = *reinterpret_cast<const short8*>(&LX[1][lr][lg * 8]);
                xl1 = *reinterpret_cast<const short8*>(&LX[1][lr][32 + lg * 8]);
            }
            #pragma unroll
            for (int t = 0; t < 2; ++t) {
                f32x4 bH = {0.f,0.f,0.f,0.f}, bL = bH;
                bH = __builtin_amdgcn_mfma_f32_16x16x32_bf16(xh0, BtH[t][0], bH, 0, 0, 0);
                bH = __builtin_amdgcn_mfma_f32_16x16x32_bf16(xh1, BtH[t][1], bH, 0, 0, 0);
                if (mode >= 1) {
                    bL = __builtin_amdgcn_mfma_f32_16x16x32_bf16(xl0, BtH[t][0], bL, 0, 0, 0);
                    bL = __builtin_amdgcn_mfma_f32_16x16x32_bf16(xl1, BtH[t][1], bL, 0, 0, 0);
                }
                if (mode == 2) {
                    bL = __builtin_amdgcn_mfma_f32_16x16x32_bf16(xh0, BtL[t][0], bL, 0, 0, 0);
                    bL = __builtin_amdgcn_mfma_f32_16x16x32_bf16(xh1, BtL[t][1], bL, 0, 0, 0);
                }
                #pragma unroll
                for (int r = 0; r < 4; ++r) {
                    float v = atv[t] * frcp(bH[r] + bL[r] + 1.0f);
                    if (mode == 0) LY[0][lg * 4 + r][32 * w + 16 * t + lr] = bf16r(v);
                    else splitw(v, &LY[0][lg * 4 + r][32 * w + 16 * t + lr],
                                   &LY[1][lg * 4 + r][32 * w + 16 * t + lr]);
                }
            }
        }
        __syncthreads();
        float flag = -1.0f;
        // ---------- P2 ----------
        {   // AF chain: AF' = at * rcp(Ldi @ Bt + 1)   (16 x 128)
            short8 yh0 = *reinterpret_cast<const short8*>(&AY[0][lr][lg * 8]);
            short8 yh1 = *reinterpret_cast<const short8*>(&AY[0][lr][32 + lg * 8]);
            short8 yl0, yl1;
            if (mode >= 1) {
                yl0 = *reinterpret_cast<const short8*>(&AY[1][lr][lg * 8]);
                yl1 = *reinterpret_cast<const short8*>(&AY[1][lr][32 + lg * 8]);
            }
            #pragma unroll
            for (int t = 0; t < 2; ++t) {
                f32x4 bH = {0.f,0.f,0.f,0.f}, bL = bH;
                bH = __builtin_amdgcn_mfma_f32_16x16x32_bf16(yh0, BtH[t][0], bH, 0, 0, 0);
                bH = __builtin_amdgcn_mfma_f32_16x16x32_bf16(yh1, BtH[t][1], bH, 0, 0, 0);
                if (mode >= 1) {
                    bL = __builtin_amdgcn_mfma_f32_16x16x32_bf16(yl0, BtH[t][0], bL, 0, 0, 0);
                    bL = __builtin_amdgcn_mfma_f32_16x16x32_bf16(yl1, BtH[t][1], bL, 0, 0, 0);
                }
                if (mode == 2) {
                    bL = __builtin_amdgcn_mfma_f32_16x16x32_bf16(yh0, BtL[t][0], bL, 0, 0, 0);
                    bL = __builtin_amdgcn_mfma_f32_16x16x32_bf16(yh1, BtL[t][1], bL, 0, 0, 0);
                }
                #pragma unroll
                for (int r = 0; r < 4; ++r) {
                    float v = atv[t] * frcp(bH[r] + bL[r] + 1.0f);
                    if (check) {
                        float p = prevA[t][r];
                        flag = fmaxf(flag, fabsf(v - p) - tol * (p + 1e-5f));
                    }
                    prevA[t][r] = v;
                    if (mode == 0) AX[0][lg * 4 + r][32 * w + 16 * t + lr] = bf16r(v);
                    else splitw(v, &AX[0][lg * 4 + r][32 * w + 16 * t + lr],
                                   &AX[1][lg * 4 + r][32 * w + 16 * t + lr]);
                }
            }
        }
        {   // LF chain: LF' = lt * rcp(Adi @ Bk + 1)   (16 x 64)
            f32x4 aH = {0.f,0.f,0.f,0.f}, aL = aH;
            #pragma unroll
            for (int ks = 0; ks < 4; ++ks) {
                short8 hi = *reinterpret_cast<const short8*>(&LY[0][lr][ks * 32 + lg * 8]);
                aH = __builtin_amdgcn_mfma_f32_16x16x32_bf16(hi, BkH[ks], aH, 0, 0, 0);
                if (mode >= 1) {
                    short8 lo = *reinterpret_cast<const short8*>(&LY[1][lr][ks * 32 + lg * 8]);
                    aL = __builtin_amdgcn_mfma_f32_16x16x32_bf16(lo, BkH[ks], aL, 0, 0, 0);
                }
                if (mode == 2)
                    aL = __builtin_amdgcn_mfma_f32_16x16x32_bf16(hi, BkL[ks], aL, 0, 0, 0);
            }
            #pragma unroll
            for (int r = 0; r < 4; ++r) {
                float v = ltv[r] * frcp(aH[r] + aL[r] + 1.0f);
                if (check) {
                    float p = prevL[r];
                    flag = fmaxf(flag, fabsf(v - p) - tol * (p + 1e-5f));
                }
                prevL[r] = v;
                if (mode == 0) LX[0][lg * 4 + r][16 * w + lr] = bf16r(v);
                else splitw(v, &LX[0][lg * 4 + r][16 * w + lr],
                               &LX[1][lg * 4 + r][16 * w + lr]);
            }
        }
        if (check) {
            #pragma unroll
            for (int off = 32; off; off >>= 1)
                flag = fmaxf(flag, __shfl_xor(flag, off));
            if (lane == 0) wred[w] = flag;
        }
        __syncthreads();
        if (check)
            done = fmaxf(fmaxf(wred[0], wred[1]), fmaxf(wred[2], wred[3])) < 0.0f;
    };

    int step = 0;
    // phase 1a: fixed cheap iterations, no convergence overhead
    const int cheapN = max_step < 12 ? max_step : 12;
    for (int s = 0; s < cheapN; ++s, ++step)
        iterate(IC<0>{}, false, 0.f);
    // phase 1b: cheap, checked at 6e-3 (floor ~3e-3), hard cap at 64
    const int capC = max_step < 64 ? max_step : 64;
    while (step < capC && !done) { iterate(IC<0>{}, true, 6e-3f); ++step; }
    // phase 2: mid hi/lo (validated arithmetic), tol 5e-5
    done = false;
    while (step < max_step && !done) { iterate(IC<1>{}, true, 5e-5f); ++step; }
    // phase 3: 3 split-K full iterations (replaces f32 refinement; the last
    // is the reference's post-loop tracked update)
    iterate(IC<2>{}, false, 0.f);
    iterate(IC<2>{}, false, 0.f);
    iterate(IC<2>{}, false, 0.f);

    // store final state straight from registers (C-layout scatter)
    #pragma unroll
    for (int t = 0; t < 2; ++t)
        #pragma unroll
        for (int r = 0; r < 4; ++r)
            AFout[(size_t)(b0row + lg * 4 + r) * NH + 32 * w + 16 * t + lr] = prevA[t][r];
    #pragma unroll
    for (int r = 0; r < 4; ++r)
        LFout[(size_t)(b0row + lg * 4 + r) * DIN + 16 * w + lr] = prevL[r];
}

// ---------------------------------------------------------------------------
// Kernel P (v2): fragment-contiguous W layout (unchanged from round 8).
// ---------------------------------------------------------------------------
__global__ __launch_bounds__(256, 2)
void prep_wt2(const float* __restrict__ Kg, const float* __restrict__ ug,
              const float* __restrict__ eg, ushort* __restrict__ WT2)
{
    __shared__ float tile[128][68];
    const int t = threadIdx.x;
    const int i = blockIdx.x;        // 0..64
    const int ot = blockIdx.y;       // 0..7
    const int k0 = i * 128;
    const bool mn = (i < 64);

    {
        const int r = t >> 1, c0 = (t & 1) * 32;
        const float* src = mn ? &ug[(size_t)(k0 + r) * DOUT + ot * 64 + c0]
                              : &eg[(size_t)r * DOUT + ot * 64 + c0];
        const float sc = mn ? fmaxf(Kg[k0 + r], 0.0f) : 1.0f;
        #pragma unroll
        for (int g = 0; g < 8; ++g) {
            float4 v = *reinterpret_cast<const float4*>(src + g * 4);
            v.x *= sc; v.y *= sc; v.z *= sc; v.w *= sc;
            *reinterpret_cast<float4*>(&tile[r][c0 + g * 4]) = v;
        }
    }
    __syncthreads();

    {
        const int wnf = t >> 4;
        const int f = wnf & 7;
        const int wn = wnf >> 3;
        const int ks = f & 3, n = (f >> 2) & 1;
        ushort* dst = WT2 + ((size_t)(ot * 65 + i) * 16 + wnf) * 512;
        #pragma unroll
        for (int q = 0; q < 4; ++q) {
            const int l = (t & 15) * 4 + q;
            const int rb = ks * 32 + (l >> 4) * 8;
            const int c  = wn * 32 + n * 16 + (l & 15);
            uint4 v;
            v.x = bf16pair(tile[rb + 0][c], tile[rb + 1][c]);
            v.y = bf16pair(tile[rb + 2][c], tile[rb + 3][c]);
            v.z = bf16pair(tile[rb + 4][c], tile[rb + 5][c]);
            v.w = bf16pair(tile[rb + 6][c], tile[rb + 7][c]);
            *reinterpret_cast<uint4*>(dst + l * 8) = v;
        }
    }
}

// ---------------------------------------------------------------------------
// Kernel B (v5): rank-1 + asm-pipelined B-stream (unchanged from round 8).
// ---------------------------------------------------------------------------
__global__ __launch_bounds__(256, 2)
void out_gemm_rank1(const float* __restrict__ AFw, const float* __restrict__ LFw,
                    const ushort* __restrict__ WT2, const float* __restrict__ bg,
                    float* __restrict__ out)
{
    __shared__ __align__(16) ushort AFb[64][136];
    __shared__ __align__(16) float  LFt[64][68];

    const int t = threadIdx.x;
    const int ot = blockIdx.x & 7;
    const int b0 = (blockIdx.x >> 3) * 64, o0 = ot * 64;
    const int w = t >> 6, l = t & 63;
    const int wm = w >> 1, wn = w & 1;
    const int lr = l & 15, lg = l >> 4;

    {
        const int row = t >> 2, q = t & 3;
        const float4* srcA = reinterpret_cast<const float4*>(
            &AFw[(size_t)(b0 + row) * NH + q * 32]);
        #pragma unroll
        for (int g = 0; g < 4; ++g) {
            float4 fa = srcA[2 * g], fb = srcA[2 * g + 1];
            uint4 wv;
            wv.x = bf16pair(fa.x, fa.y); wv.y = bf16pair(fa.z, fa.w);
            wv.z = bf16pair(fb.x, fb.y); wv.w = bf16pair(fb.z, fb.w);
            *reinterpret_cast<uint4*>(&AFb[row][q * 32 + g * 8]) = wv;
        }
        const f32x4* srcL = reinterpret_cast<const f32x4*>(
            &LFw[(size_t)(b0 + row) * DIN + q * 16]);
        #pragma unroll
        for (int g = 0; g < 4; ++g) {
            f32x4 fv = srcL[g];
            #pragma unroll
            for (int j = 0; j < 4; ++j)
                LFt[q * 16 + g * 4 + j][row] = fv[j];
        }
    }
    __syncthreads();

    const char* base = reinterpret_cast<const char*>(WT2)
        + ((size_t)(ot * 65) * 16 + wn * 8) * 1024 + l * 16;

    u32x4 bA[8], bB[8];
    ISSUE_TILE(bA, base);

    short8 afr0[4], afr1[4];
    #pragma unroll
    for (int ks = 0; ks < 4; ++ks) {
        afr0[ks] = *reinterpret_cast<const short8*>(&AFb[wm * 32 +      lr][ks * 32 + lg * 8]);
        afr1[ks] = *reinterpret_cast<const short8*>(&AFb[wm * 32 + 16 + lr][ks * 32 + lg * 8]);
    }

    f32x4 acc00 = {0.f,0.f,0.f,0.f}, acc01 = acc00, acc10 = acc00, acc11 = acc00;
    f32x4 t00, t01, t10, t11;

    auto computeI = [&](const u32x4* bf) {
        t00 = (f32x4){0.f,0.f,0.f,0.f}; t01 = t00; t10 = t00; t11 = t00;
        #pragma unroll
        for (int ks = 0; ks < 4; ++ks) {
            short8 b0v = as_s8(bf[ks]);
            short8 b1v = as_s8(bf[4 + ks]);
            t00 = __builtin_amdgcn_mfma_f32_16x16x32_bf16(afr0[ks], b0v, t00, 0, 0, 0);
            t10 = __builtin_amdgcn_mfma_f32_16x16x32_bf16(afr1[ks], b0v, t10, 0, 0, 0);
            t01 = __builtin_amdgcn_mfma_f32_16x16x32_bf16(afr0[ks], b1v, t01, 0, 0, 0);
            t11 = __builtin_amdgcn_mfma_f32_16x16x32_bf16(afr1[ks], b1v, t11, 0, 0, 0);
        }
    };
    auto scaleAdd = [&](int i) {
        f32x4 lf0 = *reinterpret_cast<const f32x4*>(&LFt[i][wm * 32 +      lg * 4]);
        f32x4 lf1 = *reinterpret_cast<const f32x4*>(&LFt[i][wm * 32 + 16 + lg * 4]);
        #pragma unroll
        for (int r = 0; r < 4; ++r) {
            acc00[r] += lf0[r] * t00[r];
            acc01[r] += lf0[r] * t01[r];
            acc10[r] += lf1[r] * t10[r];
            acc11[r] += lf1[r] * t11[r];
        }
    };

    #pragma unroll 1
    for (int i = 0; i < 64; i += 2) {
        ISSUE_TILE(bB, base + (size_t)(i + 1) * 16384);
        WAIT_VM(8);
        computeI(bA);
        scaleAdd(i);
        ISSUE_TILE(bA, base + (size_t)(i + 2) * 16384);
        WAIT_VM(8);
        computeI(bB);
        scaleAdd(i + 1);
    }
    WAIT_VM(0);
    computeI(bA);      // i = 64: e-term, scale 1
    #pragma unroll
    for (int r = 0; r < 4; ++r) {
        acc00[r] += t00[r];
        acc01[r] += t01[r];
        acc10[r] += t10[r];
        acc11[r] += t11[r];
    }

    const int col = o0 + wn * 32 + lr;
    const float bb0 = bg[col], bb1 = bg[col + 16];
    #pragma unroll
    for (int r = 0; r < 4; ++r) {
        const int row0 = b0 + wm * 32 + lg * 4 + r;
        out[(size_t)row0 * DOUT + col]             = acc00[r] + bb0;
        out[(size_t)row0 * DOUT + col + 16]        = acc01[r] + bb1;
        out[(size_t)(row0 + 16) * DOUT + col]      = acc10[r] + bb0;
        out[(size_t)(row0 + 16) * DOUT + col + 16] = acc11[r] + bb1;
    }
}

// ---------------------------------------------------------------------------
// Workspace layout (bytes):
//   [0,        2097152)   AF  : float[4096][128]
//   [2097152,  3145728)   LF  : float[4096][64]
//   [3145728, +8519680)   WT2 : fragment-ordered bf16 W (8 o-tiles x 65 x 16KB)
// Fully rewritten before use each launch -> deterministic.
// ---------------------------------------------------------------------------
extern "C" void kernel_launch(void* const* d_in, const int* in_sizes, int n_in,
                              void* d_out, int out_size, void* d_ws, size_t ws_size,
                              hipStream_t stream)
{
    const float* LT   = (const float*)d_in[0];
    const float* Kg   = (const float*)d_in[1];
    const float* AT   = (const float*)d_in[2];
    const float* ug   = (const float*)d_in[3];
    const float* eg   = (const float*)d_in[4];
    const float* bg   = (const float*)d_in[5];
    const int*   msp  = (const int*)d_in[6];
    float* out = (float*)d_out;

    char* ws = (char*)d_ws;
    float*  AFw = (float*)(ws);
    float*  LFw = (float*)(ws + 2097152);
    ushort* WT2 = (ushort*)(ws + 3145728);

    solve_chain<<<dim3(256), dim3(256), 0, stream>>>(LT, Kg, AT, msp, AFw, LFw);
    prep_wt2<<<dim3(65, 8), dim3(256), 0, stream>>>(Kg, ug, eg, WT2);

    out_gemm_rank1<<<dim3(512), dim3(256), 0, stream>>>(AFw, LFw, WT2, bg, out);
}

// Round 12
// 81.950 us; speedup vs baseline: 15.4672x; 1.0153x over previous
//
#include <hip/hip_runtime.h>

// Problem constants
#define B_ROWS 4096
#define DIN 64
#define NH 128
#define DOUT 512
#define ROWS_PER_BLK 16
#define MAXSTEP_CAP 1000

typedef __attribute__((ext_vector_type(8))) short short8;
typedef __attribute__((ext_vector_type(4))) float f32x4;
typedef __attribute__((ext_vector_type(4))) unsigned u32x4;

template<int N> struct IC { static constexpr int v = N; };

// round-to-nearest-even f32 -> bf16, packed pair into a uint
__device__ inline unsigned bf16pair(float lo, float hi) {
    unsigned a = __float_as_uint(lo), b = __float_as_uint(hi);
    a = (a + 0x7fffu + ((a >> 16) & 1u)) >> 16;
    b = (b + 0x7fffu + ((b >> 16) & 1u)) >> 16;
    return a | (b << 16);
}
__device__ inline ushort bf16r(float v) {
    unsigned u = __float_as_uint(v);
    return (ushort)((u + 0x7fffu + ((u >> 16) & 1u)) >> 16);
}
__device__ inline float frcp(float x) { return __builtin_amdgcn_rcpf(x); }
__device__ inline short8 as_s8(u32x4 v) { return __builtin_bit_cast(short8, v); }

// split-at-write: v -> hi=bf16(v), lo=bf16(v-hi) (validated rounds 6-10)
__device__ inline void splitw(float v, ushort* ph, ushort* pl) {
    unsigned u = __float_as_uint(v);
    unsigned uh = (u + 0x7fffu + ((u >> 16) & 1u)) & 0xffff0000u;
    float rs = v - __uint_as_float(uh);
    unsigned ul = __float_as_uint(rs);
    *ph = (ushort)(uh >> 16);
    *pl = (ushort)((ul + 0x7fffu + ((ul >> 16) & 1u)) >> 16);
}
// split 8 gathered f32 (after relu) into hi/lo bf16 fragments
__device__ inline void packsplit8(const float* x, short8& h8, short8& l8) {
    unsigned hb[8], lb[8];
    #pragma unroll
    for (int j = 0; j < 8; ++j) {
        float v = fmaxf(x[j], 0.0f);
        unsigned u = __float_as_uint(v);
        unsigned uh = (u + 0x7fffu + ((u >> 16) & 1u)) & 0xffff0000u;
        float rs = v - __uint_as_float(uh);
        unsigned ul = __float_as_uint(rs);
        hb[j] = uh >> 16;
        lb[j] = (ul + 0x7fffu + ((ul >> 16) & 1u)) >> 16;
    }
    uint4 hv, lv;
    hv.x = hb[0] | (hb[1] << 16); hv.y = hb[2] | (hb[3] << 16);
    hv.z = hb[4] | (hb[5] << 16); hv.w = hb[6] | (hb[7] << 16);
    lv.x = lb[0] | (lb[1] << 16); lv.y = lb[2] | (lb[3] << 16);
    lv.z = lb[4] | (lb[5] << 16); lv.w = lb[6] | (lb[7] << 16);
    h8 = *reinterpret_cast<short8*>(&hv);
    l8 = *reinterpret_cast<short8*>(&lv);
}

// issue 8 global_load_dwordx4 for one B-tile (frag-contiguous layout)
#define ISSUE_TILE(buf, ptr) do {                                                          \
    const char* _p  = (ptr);                                                               \
    const char* _p2 = _p + 4096;                                                           \
    asm volatile("global_load_dwordx4 %0, %1, off"             : "=v"(buf[0]) : "v"(_p));  \
    asm volatile("global_load_dwordx4 %0, %1, off offset:1024" : "=v"(buf[1]) : "v"(_p));  \
    asm volatile("global_load_dwordx4 %0, %1, off offset:2048" : "=v"(buf[2]) : "v"(_p));  \
    asm volatile("global_load_dwordx4 %0, %1, off offset:3072" : "=v"(buf[3]) : "v"(_p));  \
    asm volatile("global_load_dwordx4 %0, %1, off"             : "=v"(buf[4]) : "v"(_p2)); \
    asm volatile("global_load_dwordx4 %0, %1, off offset:1024" : "=v"(buf[5]) : "v"(_p2)); \
    asm volatile("global_load_dwordx4 %0, %1, off offset:2048" : "=v"(buf[6]) : "v"(_p2)); \
    asm volatile("global_load_dwordx4 %0, %1, off offset:3072" : "=v"(buf[7]) : "v"(_p2)); \
} while (0)

#define WAIT_VM(N) do {                                  \
    asm volatile("s_waitcnt vmcnt(" #N ")");             \
    __builtin_amdgcn_sched_barrier(0);                   \
} while (0)

// ---------------------------------------------------------------------------
// Kernel A (v5): fused AF+LF chains, 3 precision phases (round 10, ~28us).
// Unchanged.
// ---------------------------------------------------------------------------
__global__ __launch_bounds__(256, 1)
void solve_chain(const float* __restrict__ LT, const float* __restrict__ Kg,
                 const float* __restrict__ AT, const int* __restrict__ msp,
                 float* __restrict__ AFout, float* __restrict__ LFout)
{
    __shared__ __align__(16) ushort AX[2][16][136];
    __shared__ __align__(16) ushort AY[2][16][136];
    __shared__ __align__(16) ushort LX[2][16][136];
    __shared__ __align__(16) ushort LY[2][16][136];
    __shared__ float wred[4];

    const int tid = threadIdx.x;
    const int lane = tid & 63, w = tid >> 6;
    const int lr = lane & 15, lg = lane >> 4;
    const int b0row = blockIdx.x * ROWS_PER_BLK;

    for (int idx = tid; idx < 2176; idx += 256) {
        reinterpret_cast<unsigned*>(&AX[0][0][0])[idx] = 0u;
        reinterpret_cast<unsigned*>(&LX[0][0][0])[idx] = 0u;
    }

    int max_step = *msp;
    if (max_step > MAXSTEP_CAP) max_step = MAXSTEP_CAP;

    short8 BkH[4], BkL[4];
    #pragma unroll
    for (int ks = 0; ks < 4; ++ks) {
        float xx[8];
        const float* p = &Kg[(16 * w + lr) * NH + ks * 32 + lg * 8];
        #pragma unroll
        for (int j = 0; j < 8; ++j) xx[j] = p[j];
        packsplit8(xx, BkH[ks], BkL[ks]);
    }
    short8 BtH[2][2], BtL[2][2];
    #pragma unroll
    for (int t = 0; t < 2; ++t)
        #pragma unroll
        for (int ks = 0; ks < 2; ++ks) {
            float xx[8];
            #pragma unroll
            for (int j = 0; j < 8; ++j)
                xx[j] = Kg[(ks * 32 + lg * 8 + j) * NH + 32 * w + 16 * t + lr];
            packsplit8(xx, BtH[t][ks], BtL[t][ks]);
        }

    float ltv[4];
    #pragma unroll
    for (int r = 0; r < 4; ++r)
        ltv[r] = LT[(size_t)(b0row + lg * 4 + r) * DIN + 16 * w + lr];
    float atv[2];
    #pragma unroll
    for (int t = 0; t < 2; ++t)
        atv[t] = fmaxf(AT[32 * w + 16 * t + lr], 0.f);

    float prevA[2][4] = {};
    float prevL[4] = {};
    bool done = false;

    __syncthreads();

    auto iterate = [&](auto MC, bool check, float tol) {
        constexpr int mode = decltype(MC)::v;
        {   // AF P1
            f32x4 aH = {0.f,0.f,0.f,0.f}, aL = aH;
            #pragma unroll
            for (int ks = 0; ks < 4; ++ks) {
                short8 hi = *reinterpret_cast<const short8*>(&AX[0][lr][ks * 32 + lg * 8]);
                aH = __builtin_amdgcn_mfma_f32_16x16x32_bf16(hi, BkH[ks], aH, 0, 0, 0);
                if (mode >= 1) {
                    short8 lo = *reinterpret_cast<const short8*>(&AX[1][lr][ks * 32 + lg * 8]);
                    aL = __builtin_amdgcn_mfma_f32_16x16x32_bf16(lo, BkH[ks], aL, 0, 0, 0);
                }
                if (mode == 2)
                    aL = __builtin_amdgcn_mfma_f32_16x16x32_bf16(hi, BkL[ks], aL, 0, 0, 0);
            }
            #pragma unroll
            for (int r = 0; r < 4; ++r) {
                float v = ltv[r] * frcp(aH[r] + aL[r] + 1.0f);
                if (mode == 0) AY[0][lg * 4 + r][16 * w + lr] = bf16r(v);
                else splitw(v, &AY[0][lg * 4 + r][16 * w + lr],
                               &AY[1][lg * 4 + r][16 * w + lr]);
            }
        }
        {   // LF P1
            short8 xh0 = *reinterpret_cast<const short8*>(&LX[0][lr][lg * 8]);
            short8 xh1 = *reinterpret_cast<const short8*>(&LX[0][lr][32 + lg * 8]);
            short8 xl0, xl1;
            if (mode >= 1) {
                xl0 = *reinterpret_cast<const short8*>(&LX[1][lr][lg * 8]);
                xl1 = *reinterpret_cast<const short8*>(&LX[1][lr][32 + lg * 8]);
            }
            #pragma unroll
            for (int t = 0; t < 2; ++t) {
                f32x4 bH = {0.f,0.f,0.f,0.f}, bL = bH;
                bH = __builtin_amdgcn_mfma_f32_16x16x32_bf16(xh0, BtH[t][0], bH, 0, 0, 0);
                bH = __builtin_amdgcn_mfma_f32_16x16x32_bf16(xh1, BtH[t][1], bH, 0, 0, 0);
                if (mode >= 1) {
                    bL = __builtin_amdgcn_mfma_f32_16x16x32_bf16(xl0, BtH[t][0], bL, 0, 0, 0);
                    bL = __builtin_amdgcn_mfma_f32_16x16x32_bf16(xl1, BtH[t][1], bL, 0, 0, 0);
                }
                if (mode == 2) {
                    bL = __builtin_amdgcn_mfma_f32_16x16x32_bf16(xh0, BtL[t][0], bL, 0, 0, 0);
                    bL = __builtin_amdgcn_mfma_f32_16x16x32_bf16(xh1, BtL[t][1], bL, 0, 0, 0);
                }
                #pragma unroll
                for (int r = 0; r < 4; ++r) {
                    float v = atv[t] * frcp(bH[r] + bL[r] + 1.0f);
                    if (mode == 0) LY[0][lg * 4 + r][32 * w + 16 * t + lr] = bf16r(v);
                    else splitw(v, &LY[0][lg * 4 + r][32 * w + 16 * t + lr],
                                   &LY[1][lg * 4 + r][32 * w + 16 * t + lr]);
                }
            }
        }
        __syncthreads();
        float flag = -1.0f;
        {   // AF P2
            short8 yh0 = *reinterpret_cast<const short8*>(&AY[0][lr][lg * 8]);
            short8 yh1 = *reinterpret_cast<const short8*>(&AY[0][lr][32 + lg * 8]);
            short8 yl0, yl1;
            if (mode >= 1) {
                yl0 = *reinterpret_cast<const short8*>(&AY[1][lr][lg * 8]);
                yl1 = *reinterpret_cast<const short8*>(&AY[1][lr][32 + lg * 8]);
            }
            #pragma unroll
            for (int t = 0; t < 2; ++t) {
                f32x4 bH = {0.f,0.f,0.f,0.f}, bL = bH;
                bH = __builtin_amdgcn_mfma_f32_16x16x32_bf16(yh0, BtH[t][0], bH, 0, 0, 0);
                bH = __builtin_amdgcn_mfma_f32_16x16x32_bf16(yh1, BtH[t][1], bH, 0, 0, 0);
                if (mode >= 1) {
                    bL = __builtin_amdgcn_mfma_f32_16x16x32_bf16(yl0, BtH[t][0], bL, 0, 0, 0);
                    bL = __builtin_amdgcn_mfma_f32_16x16x32_bf16(yl1, BtH[t][1], bL, 0, 0, 0);
                }
                if (mode == 2) {
                    bL = __builtin_amdgcn_mfma_f32_16x16x32_bf16(yh0, BtL[t][0], bL, 0, 0, 0);
                    bL = __builtin_amdgcn_mfma_f32_16x16x32_bf16(yh1, BtL[t][1], bL, 0, 0, 0);
                }
                #pragma unroll
                for (int r = 0; r < 4; ++r) {
                    float v = atv[t] * frcp(bH[r] + bL[r] + 1.0f);
                    if (check) {
                        float p = prevA[t][r];
                        flag = fmaxf(flag, fabsf(v - p) - tol * (p + 1e-5f));
                    }
                    prevA[t][r] = v;
                    if (mode == 0) AX[0][lg * 4 + r][32 * w + 16 * t + lr] = bf16r(v);
                    else splitw(v, &AX[0][lg * 4 + r][32 * w + 16 * t + lr],
                                   &AX[1][lg * 4 + r][32 * w + 16 * t + lr]);
                }
            }
        }
        {   // LF P2
            f32x4 aH = {0.f,0.f,0.f,0.f}, aL = aH;
            #pragma unroll
            for (int ks = 0; ks < 4; ++ks) {
                short8 hi = *reinterpret_cast<const short8*>(&LY[0][lr][ks * 32 + lg * 8]);
                aH = __builtin_amdgcn_mfma_f32_16x16x32_bf16(hi, BkH[ks], aH, 0, 0, 0);
                if (mode >= 1) {
                    short8 lo = *reinterpret_cast<const short8*>(&LY[1][lr][ks * 32 + lg * 8]);
                    aL = __builtin_amdgcn_mfma_f32_16x16x32_bf16(lo, BkH[ks], aL, 0, 0, 0);
                }
                if (mode == 2)
                    aL = __builtin_amdgcn_mfma_f32_16x16x32_bf16(hi, BkL[ks], aL, 0, 0, 0);
            }
            #pragma unroll
            for (int r = 0; r < 4; ++r) {
                float v = ltv[r] * frcp(aH[r] + aL[r] + 1.0f);
                if (check) {
                    float p = prevL[r];
                    flag = fmaxf(flag, fabsf(v - p) - tol * (p + 1e-5f));
                }
                prevL[r] = v;
                if (mode == 0) LX[0][lg * 4 + r][16 * w + lr] = bf16r(v);
                else splitw(v, &LX[0][lg * 4 + r][16 * w + lr],
                               &LX[1][lg * 4 + r][16 * w + lr]);
            }
        }
        if (check) {
            #pragma unroll
            for (int off = 32; off; off >>= 1)
                flag = fmaxf(flag, __shfl_xor(flag, off));
            if (lane == 0) wred[w] = flag;
        }
        __syncthreads();
        if (check)
            done = fmaxf(fmaxf(wred[0], wred[1]), fmaxf(wred[2], wred[3])) < 0.0f;
    };

    int step = 0;
    const int cheapN = max_step < 12 ? max_step : 12;
    for (int s = 0; s < cheapN; ++s, ++step)
        iterate(IC<0>{}, false, 0.f);
    const int capC = max_step < 64 ? max_step : 64;
    while (step < capC && !done) { iterate(IC<0>{}, true, 6e-3f); ++step; }
    done = false;
    while (step < max_step && !done) { iterate(IC<1>{}, true, 5e-5f); ++step; }
    iterate(IC<2>{}, false, 0.f);
    iterate(IC<2>{}, false, 0.f);
    iterate(IC<2>{}, false, 0.f);

    #pragma unroll
    for (int t = 0; t < 2; ++t)
        #pragma unroll
        for (int r = 0; r < 4; ++r)
            AFout[(size_t)(b0row + lg * 4 + r) * NH + 32 * w + 16 * t + lr] = prevA[t][r];
    #pragma unroll
    for (int r = 0; r < 4; ++r)
        LFout[(size_t)(b0row + lg * 4 + r) * DIN + 16 * w + lr] = prevL[r];
}

// ---------------------------------------------------------------------------
// Kernel P (v2): fragment-contiguous W layout (unchanged from round 8).
// ---------------------------------------------------------------------------
__global__ __launch_bounds__(256, 2)
void prep_wt2(const float* __restrict__ Kg, const float* __restrict__ ug,
              const float* __restrict__ eg, ushort* __restrict__ WT2)
{
    __shared__ float tile[128][68];
    const int t = threadIdx.x;
    const int i = blockIdx.x;        // 0..64
    const int ot = blockIdx.y;       // 0..7
    const int k0 = i * 128;
    const bool mn = (i < 64);

    {
        const int r = t >> 1, c0 = (t & 1) * 32;
        const float* src = mn ? &ug[(size_t)(k0 + r) * DOUT + ot * 64 + c0]
                              : &eg[(size_t)r * DOUT + ot * 64 + c0];
        const float sc = mn ? fmaxf(Kg[k0 + r], 0.0f) : 1.0f;
        #pragma unroll
        for (int g = 0; g < 8; ++g) {
            float4 v = *reinterpret_cast<const float4*>(src + g * 4);
            v.x *= sc; v.y *= sc; v.z *= sc; v.w *= sc;
            *reinterpret_cast<float4*>(&tile[r][c0 + g * 4]) = v;
        }
    }
    __syncthreads();

    {
        const int wnf = t >> 4;
        const int f = wnf & 7;
        const int wn = wnf >> 3;
        const int ks = f & 3, n = (f >> 2) & 1;
        ushort* dst = WT2 + ((size_t)(ot * 65 + i) * 16 + wnf) * 512;
        #pragma unroll
        for (int q = 0; q < 4; ++q) {
            const int l = (t & 15) * 4 + q;
            const int rb = ks * 32 + (l >> 4) * 8;
            const int c  = wn * 32 + n * 16 + (l & 15);
            uint4 v;
            v.x = bf16pair(tile[rb + 0][c], tile[rb + 1][c]);
            v.y = bf16pair(tile[rb + 2][c], tile[rb + 3][c]);
            v.z = bf16pair(tile[rb + 4][c], tile[rb + 5][c]);
            v.w = bf16pair(tile[rb + 6][c], tile[rb + 7][c]);
            *reinterpret_cast<uint4*>(dst + l * 8) = v;
        }
    }
}

// ---------------------------------------------------------------------------
// Kernel B (v7): rank-1, 3-BUFFER / 3-tiles-in-flight asm pipeline.
// Round-11 post-mortem: the 4-buffer variant corrupted fragments (absmax
// 2.6) — 128 tied buffer VGPRs + temps hit the 256 cap and the allocator
// spilled/copied asm-tied in-flight registers before the loads landed.
// The 4th buffer also bought ZERO extra slack (each WAIT_VM(16) has
// exactly 2 tiles in flight either way). This version: 3-buffer rotation
// (96 tied regs, ~175 total), same 2-tile (~600cy) latency cover:
//   prologue: issue T0,T1,T2 (24 loads out)
//   step: WAIT_VM(16) -> oldest tile resident; compute it; re-issue that
//         buffer 3 tiles ahead (back to 24 out).
// ---------------------------------------------------------------------------
__global__ __launch_bounds__(256, 2)
void out_gemm_rank1(const float* __restrict__ AFw, const float* __restrict__ LFw,
                    const ushort* __restrict__ WT2, const float* __restrict__ bg,
                    float* __restrict__ out)
{
    __shared__ __align__(16) ushort AFb[64][136];
    __shared__ __align__(16) float  LFt[64][68];

    const int t = threadIdx.x;
    const int ot = blockIdx.x & 7;
    const int b0 = (blockIdx.x >> 3) * 64, o0 = ot * 64;
    const int w = t >> 6, l = t & 63;
    const int wm = w >> 1, wn = w & 1;
    const int lr = l & 15, lg = l >> 4;

    {
        const int row = t >> 2, q = t & 3;
        const float4* srcA = reinterpret_cast<const float4*>(
            &AFw[(size_t)(b0 + row) * NH + q * 32]);
        #pragma unroll
        for (int g = 0; g < 4; ++g) {
            float4 fa = srcA[2 * g], fb = srcA[2 * g + 1];
            uint4 wv;
            wv.x = bf16pair(fa.x, fa.y); wv.y = bf16pair(fa.z, fa.w);
            wv.z = bf16pair(fb.x, fb.y); wv.w = bf16pair(fb.z, fb.w);
            *reinterpret_cast<uint4*>(&AFb[row][q * 32 + g * 8]) = wv;
        }
        const f32x4* srcL = reinterpret_cast<const f32x4*>(
            &LFw[(size_t)(b0 + row) * DIN + q * 16]);
        #pragma unroll
        for (int g = 0; g < 4; ++g) {
            f32x4 fv = srcL[g];
            #pragma unroll
            for (int j = 0; j < 4; ++j)
                LFt[q * 16 + g * 4 + j][row] = fv[j];
        }
    }
    __syncthreads();

    const char* base = reinterpret_cast<const char*>(WT2)
        + ((size_t)(ot * 65) * 16 + wn * 8) * 1024 + l * 16;

    u32x4 bf0[8], bf1[8], bf2[8];
    ISSUE_TILE(bf0, base);                       // T0
    ISSUE_TILE(bf1, base + 16384);               // T1
    ISSUE_TILE(bf2, base + 2 * 16384);           // T2

    short8 afr0[4], afr1[4];
    #pragma unroll
    for (int ks = 0; ks < 4; ++ks) {
        afr0[ks] = *reinterpret_cast<const short8*>(&AFb[wm * 32 +      lr][ks * 32 + lg * 8]);
        afr1[ks] = *reinterpret_cast<const short8*>(&AFb[wm * 32 + 16 + lr][ks * 32 + lg * 8]);
    }

    f32x4 acc00 = {0.f,0.f,0.f,0.f}, acc01 = acc00, acc10 = acc00, acc11 = acc00;
    f32x4 t00, t01, t10, t11;

    auto computeI = [&](const u32x4* bf) {
        t00 = (f32x4){0.f,0.f,0.f,0.f}; t01 = t00; t10 = t00; t11 = t00;
        #pragma unroll
        for (int ks = 0; ks < 4; ++ks) {
            short8 b0v = as_s8(bf[ks]);
            short8 b1v = as_s8(bf[4 + ks]);
            t00 = __builtin_amdgcn_mfma_f32_16x16x32_bf16(afr0[ks], b0v, t00, 0, 0, 0);
            t10 = __builtin_amdgcn_mfma_f32_16x16x32_bf16(afr1[ks], b0v, t10, 0, 0, 0);
            t01 = __builtin_amdgcn_mfma_f32_16x16x32_bf16(afr0[ks], b1v, t01, 0, 0, 0);
            t11 = __builtin_amdgcn_mfma_f32_16x16x32_bf16(afr1[ks], b1v, t11, 0, 0, 0);
        }
    };
    auto scaleAdd = [&](int i) {
        f32x4 lf0 = *reinterpret_cast<const f32x4*>(&LFt[i][wm * 32 +      lg * 4]);
        f32x4 lf1 = *reinterpret_cast<const f32x4*>(&LFt[i][wm * 32 + 16 + lg * 4]);
        #pragma unroll
        for (int r = 0; r < 4; ++r) {
            acc00[r] += lf0[r] * t00[r];
            acc01[r] += lf0[r] * t01[r];
            acc10[r] += lf1[r] * t10[r];
            acc11[r] += lf1[r] * t11[r];
        }
    };

    // tiles 0..64 (65 total). Steady state: 3 tiles (24 loads) in flight;
    // WAIT_VM(16) == oldest tile resident, 2 tiles (~600cy) still flying.
    #pragma unroll 1
    for (int i = 0; i < 60; i += 3) {
        const char* p = base + (size_t)(i + 3) * 16384;
        WAIT_VM(16); computeI(bf0); scaleAdd(i);     ISSUE_TILE(bf0, p);
        WAIT_VM(16); computeI(bf1); scaleAdd(i + 1); ISSUE_TILE(bf1, p + 16384);
        WAIT_VM(16); computeI(bf2); scaleAdd(i + 2); ISSUE_TILE(bf2, p + 2 * 16384);
    }
    // loop computed tiles 0..59; in flight: T60(bf0), T61(bf1), T62(bf2)
    WAIT_VM(16); computeI(bf0); scaleAdd(60); ISSUE_TILE(bf0, base + (size_t)63 * 16384);
    WAIT_VM(16); computeI(bf1); scaleAdd(61); ISSUE_TILE(bf1, base + (size_t)64 * 16384);
    WAIT_VM(16); computeI(bf2); scaleAdd(62);
    WAIT_VM(8);  computeI(bf0); scaleAdd(63);
    WAIT_VM(0);  computeI(bf1);                  // T64: e-term, scale 1
    #pragma unroll
    for (int r = 0; r < 4; ++r) {
        acc00[r] += t00[r];
        acc01[r] += t01[r];
        acc10[r] += t10[r];
        acc11[r] += t11[r];
    }

    const int col = o0 + wn * 32 + lr;
    const float bb0 = bg[col], bb1 = bg[col + 16];
    #pragma unroll
    for (int r = 0; r < 4; ++r) {
        const int row0 = b0 + wm * 32 + lg * 4 + r;
        out[(size_t)row0 * DOUT + col]             = acc00[r] + bb0;
        out[(size_t)row0 * DOUT + col + 16]        = acc01[r] + bb1;
        out[(size_t)(row0 + 16) * DOUT + col]      = acc10[r] + bb0;
        out[(size_t)(row0 + 16) * DOUT + col + 16] = acc11[r] + bb1;
    }
}

// ---------------------------------------------------------------------------
// Workspace layout (bytes):
//   [0,        2097152)   AF  : float[4096][128]
//   [2097152,  3145728)   LF  : float[4096][64]
//   [3145728, +8519680)   WT2 : fragment-ordered bf16 W (8 o-tiles x 65 x 16KB)
// Fully rewritten before use each launch -> deterministic.
// ---------------------------------------------------------------------------
extern "C" void kernel_launch(void* const* d_in, const int* in_sizes, int n_in,
                              void* d_out, int out_size, void* d_ws, size_t ws_size,
                              hipStream_t stream)
{
    const float* LT   = (const float*)d_in[0];
    const float* Kg   = (const float*)d_in[1];
    const float* AT   = (const float*)d_in[2];
    const float* ug   = (const float*)d_in[3];
    const float* eg   = (const float*)d_in[4];
    const float* bg   = (const float*)d_in[5];
    const int*   msp  = (const int*)d_in[6];
    float* out = (float*)d_out;

    char* ws = (char*)d_ws;
    float*  AFw = (float*)(ws);
    float*  LFw = (float*)(ws + 2097152);
    ushort* WT2 = (ushort*)(ws + 3145728);

    solve_chain<<<dim3(256), dim3(256), 0, stream>>>(LT, Kg, AT, msp, AFw, LFw);
    prep_wt2<<<dim3(65, 8), dim3(256), 0, stream>>>(Kg, ug, eg, WT2);

    out_gemm_rank1<<<dim3(512), dim3(256), 0, stream>>>(AFw, LFw, WT2, bg, out);
}

// Round 13
// 76.222 us; speedup vs baseline: 16.6297x; 1.0752x over previous
//
#include <hip/hip_runtime.h>

// Problem constants
#define B_ROWS 4096
#define DIN 64
#define NH 128
#define DOUT 512
#define ROWS_PER_BLK 16
#define MAXSTEP_CAP 1000

typedef __attribute__((ext_vector_type(8))) short short8;
typedef __attribute__((ext_vector_type(4))) float f32x4;
typedef __attribute__((ext_vector_type(4))) unsigned u32x4;

template<int N> struct IC { static constexpr int v = N; };

// round-to-nearest-even f32 -> bf16, packed pair into a uint
__device__ inline unsigned bf16pair(float lo, float hi) {
    unsigned a = __float_as_uint(lo), b = __float_as_uint(hi);
    a = (a + 0x7fffu + ((a >> 16) & 1u)) >> 16;
    b = (b + 0x7fffu + ((b >> 16) & 1u)) >> 16;
    return a | (b << 16);
}
__device__ inline ushort bf16r(float v) {
    unsigned u = __float_as_uint(v);
    return (ushort)((u + 0x7fffu + ((u >> 16) & 1u)) >> 16);
}
__device__ inline float frcp(float x) { return __builtin_amdgcn_rcpf(x); }
__device__ inline short8 as_s8(u32x4 v) { return __builtin_bit_cast(short8, v); }

// split-at-write: v -> hi=bf16(v), lo=bf16(v-hi) (validated rounds 6-12)
__device__ inline void splitw(float v, ushort* ph, ushort* pl) {
    unsigned u = __float_as_uint(v);
    unsigned uh = (u + 0x7fffu + ((u >> 16) & 1u)) & 0xffff0000u;
    float rs = v - __uint_as_float(uh);
    unsigned ul = __float_as_uint(rs);
    *ph = (ushort)(uh >> 16);
    *pl = (ushort)((ul + 0x7fffu + ((ul >> 16) & 1u)) >> 16);
}
// split 8 gathered f32 (after relu) into hi/lo bf16 fragments
__device__ inline void packsplit8(const float* x, short8& h8, short8& l8) {
    unsigned hb[8], lb[8];
    #pragma unroll
    for (int j = 0; j < 8; ++j) {
        float v = fmaxf(x[j], 0.0f);
        unsigned u = __float_as_uint(v);
        unsigned uh = (u + 0x7fffu + ((u >> 16) & 1u)) & 0xffff0000u;
        float rs = v - __uint_as_float(uh);
        unsigned ul = __float_as_uint(rs);
        hb[j] = uh >> 16;
        lb[j] = (ul + 0x7fffu + ((ul >> 16) & 1u)) >> 16;
    }
    uint4 hv, lv;
    hv.x = hb[0] | (hb[1] << 16); hv.y = hb[2] | (hb[3] << 16);
    hv.z = hb[4] | (hb[5] << 16); hv.w = hb[6] | (hb[7] << 16);
    lv.x = lb[0] | (lb[1] << 16); lv.y = lb[2] | (lb[3] << 16);
    lv.z = lb[4] | (lb[5] << 16); lv.w = lb[6] | (lb[7] << 16);
    h8 = *reinterpret_cast<short8*>(&hv);
    l8 = *reinterpret_cast<short8*>(&lv);
}

// issue 4 global_load_dwordx4 for one wave's HALF-TILE SLICE (4KB contiguous:
// the wave's col-block cb has its 4 ks-frags at +cb*4096 + ks*1024)
#define ISSUE_SLICE(buf, ptr) do {                                                         \
    const char* _p = (ptr);                                                                \
    asm volatile("global_load_dwordx4 %0, %1, off"             : "=v"(buf[0]) : "v"(_p));  \
    asm volatile("global_load_dwordx4 %0, %1, off offset:1024" : "=v"(buf[1]) : "v"(_p));  \
    asm volatile("global_load_dwordx4 %0, %1, off offset:2048" : "=v"(buf[2]) : "v"(_p));  \
    asm volatile("global_load_dwordx4 %0, %1, off offset:3072" : "=v"(buf[3]) : "v"(_p));  \
} while (0)

#define WAIT_VM(N) do {                                  \
    asm volatile("s_waitcnt vmcnt(" #N ")");             \
    __builtin_amdgcn_sched_barrier(0);                   \
} while (0)

// ---------------------------------------------------------------------------
// Kernel A (v5): fused AF+LF chains, 3 precision phases (round 10, ~28us).
// Unchanged.
// ---------------------------------------------------------------------------
__global__ __launch_bounds__(256, 1)
void solve_chain(const float* __restrict__ LT, const float* __restrict__ Kg,
                 const float* __restrict__ AT, const int* __restrict__ msp,
                 float* __restrict__ AFout, float* __restrict__ LFout)
{
    __shared__ __align__(16) ushort AX[2][16][136];
    __shared__ __align__(16) ushort AY[2][16][136];
    __shared__ __align__(16) ushort LX[2][16][136];
    __shared__ __align__(16) ushort LY[2][16][136];
    __shared__ float wred[4];

    const int tid = threadIdx.x;
    const int lane = tid & 63, w = tid >> 6;
    const int lr = lane & 15, lg = lane >> 4;
    const int b0row = blockIdx.x * ROWS_PER_BLK;

    for (int idx = tid; idx < 2176; idx += 256) {
        reinterpret_cast<unsigned*>(&AX[0][0][0])[idx] = 0u;
        reinterpret_cast<unsigned*>(&LX[0][0][0])[idx] = 0u;
    }

    int max_step = *msp;
    if (max_step > MAXSTEP_CAP) max_step = MAXSTEP_CAP;

    short8 BkH[4], BkL[4];
    #pragma unroll
    for (int ks = 0; ks < 4; ++ks) {
        float xx[8];
        const float* p = &Kg[(16 * w + lr) * NH + ks * 32 + lg * 8];
        #pragma unroll
        for (int j = 0; j < 8; ++j) xx[j] = p[j];
        packsplit8(xx, BkH[ks], BkL[ks]);
    }
    short8 BtH[2][2], BtL[2][2];
    #pragma unroll
    for (int t = 0; t < 2; ++t)
        #pragma unroll
        for (int ks = 0; ks < 2; ++ks) {
            float xx[8];
            #pragma unroll
            for (int j = 0; j < 8; ++j)
                xx[j] = Kg[(ks * 32 + lg * 8 + j) * NH + 32 * w + 16 * t + lr];
            packsplit8(xx, BtH[t][ks], BtL[t][ks]);
        }

    float ltv[4];
    #pragma unroll
    for (int r = 0; r < 4; ++r)
        ltv[r] = LT[(size_t)(b0row + lg * 4 + r) * DIN + 16 * w + lr];
    float atv[2];
    #pragma unroll
    for (int t = 0; t < 2; ++t)
        atv[t] = fmaxf(AT[32 * w + 16 * t + lr], 0.f);

    float prevA[2][4] = {};
    float prevL[4] = {};
    bool done = false;

    __syncthreads();

    auto iterate = [&](auto MC, bool check, float tol) {
        constexpr int mode = decltype(MC)::v;
        {   // AF P1
            f32x4 aH = {0.f,0.f,0.f,0.f}, aL = aH;
            #pragma unroll
            for (int ks = 0; ks < 4; ++ks) {
                short8 hi = *reinterpret_cast<const short8*>(&AX[0][lr][ks * 32 + lg * 8]);
                aH = __builtin_amdgcn_mfma_f32_16x16x32_bf16(hi, BkH[ks], aH, 0, 0, 0);
                if (mode >= 1) {
                    short8 lo = *reinterpret_cast<const short8*>(&AX[1][lr][ks * 32 + lg * 8]);
                    aL = __builtin_amdgcn_mfma_f32_16x16x32_bf16(lo, BkH[ks], aL, 0, 0, 0);
                }
                if (mode == 2)
                    aL = __builtin_amdgcn_mfma_f32_16x16x32_bf16(hi, BkL[ks], aL, 0, 0, 0);
            }
            #pragma unroll
            for (int r = 0; r < 4; ++r) {
                float v = ltv[r] * frcp(aH[r] + aL[r] + 1.0f);
                if (mode == 0) AY[0][lg * 4 + r][16 * w + lr] = bf16r(v);
                else splitw(v, &AY[0][lg * 4 + r][16 * w + lr],
                               &AY[1][lg * 4 + r][16 * w + lr]);
            }
        }
        {   // LF P1
            short8 xh0 = *reinterpret_cast<const short8*>(&LX[0][lr][lg * 8]);
            short8 xh1 = *reinterpret_cast<const short8*>(&LX[0][lr][32 + lg * 8]);
            short8 xl0, xl1;
            if (mode >= 1) {
                xl0 = *reinterpret_cast<const short8*>(&LX[1][lr][lg * 8]);
                xl1 = *reinterpret_cast<const short8*>(&LX[1][lr][32 + lg * 8]);
            }
            #pragma unroll
            for (int t = 0; t < 2; ++t) {
                f32x4 bH = {0.f,0.f,0.f,0.f}, bL = bH;
                bH = __builtin_amdgcn_mfma_f32_16x16x32_bf16(xh0, BtH[t][0], bH, 0, 0, 0);
                bH = __builtin_amdgcn_mfma_f32_16x16x32_bf16(xh1, BtH[t][1], bH, 0, 0, 0);
                if (mode >= 1) {
                    bL = __builtin_amdgcn_mfma_f32_16x16x32_bf16(xl0, BtH[t][0], bL, 0, 0, 0);
                    bL = __builtin_amdgcn_mfma_f32_16x16x32_bf16(xl1, BtH[t][1], bL, 0, 0, 0);
                }
                if (mode == 2) {
                    bL = __builtin_amdgcn_mfma_f32_16x16x32_bf16(xh0, BtL[t][0], bL, 0, 0, 0);
                    bL = __builtin_amdgcn_mfma_f32_16x16x32_bf16(xh1, BtL[t][1], bL, 0, 0, 0);
                }
                #pragma unroll
                for (int r = 0; r < 4; ++r) {
                    float v = atv[t] * frcp(bH[r] + bL[r] + 1.0f);
                    if (mode == 0) LY[0][lg * 4 + r][32 * w + 16 * t + lr] = bf16r(v);
                    else splitw(v, &LY[0][lg * 4 + r][32 * w + 16 * t + lr],
                                   &LY[1][lg * 4 + r][32 * w + 16 * t + lr]);
                }
            }
        }
        __syncthreads();
        float flag = -1.0f;
        {   // AF P2
            short8 yh0 = *reinterpret_cast<const short8*>(&AY[0][lr][lg * 8]);
            short8 yh1 = *reinterpret_cast<const short8*>(&AY[0][lr][32 + lg * 8]);
            short8 yl0, yl1;
            if (mode >= 1) {
                yl0 = *reinterpret_cast<const short8*>(&AY[1][lr][lg * 8]);
                yl1 = *reinterpret_cast<const short8*>(&AY[1][lr][32 + lg * 8]);
            }
            #pragma unroll
            for (int t = 0; t < 2; ++t) {
                f32x4 bH = {0.f,0.f,0.f,0.f}, bL = bH;
                bH = __builtin_amdgcn_mfma_f32_16x16x32_bf16(yh0, BtH[t][0], bH, 0, 0, 0);
                bH = __builtin_amdgcn_mfma_f32_16x16x32_bf16(yh1, BtH[t][1], bH, 0, 0, 0);
                if (mode >= 1) {
                    bL = __builtin_amdgcn_mfma_f32_16x16x32_bf16(yl0, BtH[t][0], bL, 0, 0, 0);
                    bL = __builtin_amdgcn_mfma_f32_16x16x32_bf16(yl1, BtH[t][1], bL, 0, 0, 0);
                }
                if (mode == 2) {
                    bL = __builtin_amdgcn_mfma_f32_16x16x32_bf16(yh0, BtL[t][0], bL, 0, 0, 0);
                    bL = __builtin_amdgcn_mfma_f32_16x16x32_bf16(yh1, BtL[t][1], bL, 0, 0, 0);
                }
                #pragma unroll
                for (int r = 0; r < 4; ++r) {
                    float v = atv[t] * frcp(bH[r] + bL[r] + 1.0f);
                    if (check) {
                        float p = prevA[t][r];
                        flag = fmaxf(flag, fabsf(v - p) - tol * (p + 1e-5f));
                    }
                    prevA[t][r] = v;
                    if (mode == 0) AX[0][lg * 4 + r][32 * w + 16 * t + lr] = bf16r(v);
                    else splitw(v, &AX[0][lg * 4 + r][32 * w + 16 * t + lr],
                                   &AX[1][lg * 4 + r][32 * w + 16 * t + lr]);
                }
            }
        }
        {   // LF P2
            f32x4 aH = {0.f,0.f,0.f,0.f}, aL = aH;
            #pragma unroll
            for (int ks = 0; ks < 4; ++ks) {
                short8 hi = *reinterpret_cast<const short8*>(&LY[0][lr][ks * 32 + lg * 8]);
                aH = __builtin_amdgcn_mfma_f32_16x16x32_bf16(hi, BkH[ks], aH, 0, 0, 0);
                if (mode >= 1) {
                    short8 lo = *reinterpret_cast<const short8*>(&LY[1][lr][ks * 32 + lg * 8]);
                    aL = __builtin_amdgcn_mfma_f32_16x16x32_bf16(lo, BkH[ks], aL, 0, 0, 0);
                }
                if (mode == 2)
                    aL = __builtin_amdgcn_mfma_f32_16x16x32_bf16(hi, BkL[ks], aL, 0, 0, 0);
            }
            #pragma unroll
            for (int r = 0; r < 4; ++r) {
                float v = ltv[r] * frcp(aH[r] + aL[r] + 1.0f);
                if (check) {
                    float p = prevL[r];
                    flag = fmaxf(flag, fabsf(v - p) - tol * (p + 1e-5f));
                }
                prevL[r] = v;
                if (mode == 0) LX[0][lg * 4 + r][16 * w + lr] = bf16r(v);
                else splitw(v, &LX[0][lg * 4 + r][16 * w + lr],
                               &LX[1][lg * 4 + r][16 * w + lr]);
            }
        }
        if (check) {
            #pragma unroll
            for (int off = 32; off; off >>= 1)
                flag = fmaxf(flag, __shfl_xor(flag, off));
            if (lane == 0) wred[w] = flag;
        }
        __syncthreads();
        if (check)
            done = fmaxf(fmaxf(wred[0], wred[1]), fmaxf(wred[2], wred[3])) < 0.0f;
    };

    int step = 0;
    const int cheapN = max_step < 12 ? max_step : 12;
    for (int s = 0; s < cheapN; ++s, ++step)
        iterate(IC<0>{}, false, 0.f);
    const int capC = max_step < 64 ? max_step : 64;
    while (step < capC && !done) { iterate(IC<0>{}, true, 6e-3f); ++step; }
    done = false;
    while (step < max_step && !done) { iterate(IC<1>{}, true, 5e-5f); ++step; }
    iterate(IC<2>{}, false, 0.f);
    iterate(IC<2>{}, false, 0.f);
    iterate(IC<2>{}, false, 0.f);

    #pragma unroll
    for (int t = 0; t < 2; ++t)
        #pragma unroll
        for (int r = 0; r < 4; ++r)
            AFout[(size_t)(b0row + lg * 4 + r) * NH + 32 * w + 16 * t + lr] = prevA[t][r];
    #pragma unroll
    for (int r = 0; r < 4; ++r)
        LFout[(size_t)(b0row + lg * 4 + r) * DIN + 16 * w + lr] = prevL[r];
}

// ---------------------------------------------------------------------------
// Kernel P (v2): fragment-contiguous W layout (unchanged from round 8).
// Frag block wnf = cb*4 + ks (cb = col-block of 16, ks = k-slice of 32), so
// one wave's 4 ks-frags for col-block cb are CONTIGUOUS 4KB at +cb*4096.
// ---------------------------------------------------------------------------
__global__ __launch_bounds__(256, 2)
void prep_wt2(const float* __restrict__ Kg, const float* __restrict__ ug,
              const float* __restrict__ eg, ushort* __restrict__ WT2)
{
    __shared__ float tile[128][68];
    const int t = threadIdx.x;
    const int i = blockIdx.x;        // 0..64
    const int ot = blockIdx.y;       // 0..7
    const int k0 = i * 128;
    const bool mn = (i < 64);

    {
        const int r = t >> 1, c0 = (t & 1) * 32;
        const float* src = mn ? &ug[(size_t)(k0 + r) * DOUT + ot * 64 + c0]
                              : &eg[(size_t)r * DOUT + ot * 64 + c0];
        const float sc = mn ? fmaxf(Kg[k0 + r], 0.0f) : 1.0f;
        #pragma unroll
        for (int g = 0; g < 8; ++g) {
            float4 v = *reinterpret_cast<const float4*>(src + g * 4);
            v.x *= sc; v.y *= sc; v.z *= sc; v.w *= sc;
            *reinterpret_cast<float4*>(&tile[r][c0 + g * 4]) = v;
        }
    }
    __syncthreads();

    {
        const int wnf = t >> 4;
        const int f = wnf & 7;
        const int wn = wnf >> 3;
        const int ks = f & 3, n = (f >> 2) & 1;
        ushort* dst = WT2 + ((size_t)(ot * 65 + i) * 16 + wnf) * 512;
        #pragma unroll
        for (int q = 0; q < 4; ++q) {
            const int l = (t & 15) * 4 + q;
            const int rb = ks * 32 + (l >> 4) * 8;
            const int c  = wn * 32 + n * 16 + (l & 15);
            uint4 v;
            v.x = bf16pair(tile[rb + 0][c], tile[rb + 1][c]);
            v.y = bf16pair(tile[rb + 2][c], tile[rb + 3][c]);
            v.z = bf16pair(tile[rb + 4][c], tile[rb + 5][c]);
            v.w = bf16pair(tile[rb + 6][c], tile[rb + 7][c]);
            *reinterpret_cast<uint4*>(dst + l * 8) = v;
        }
    }
}

// ---------------------------------------------------------------------------
// Kernel B (v8): rank-1, wave = 64 rows x 16 cols (no duplicate loads).
// Round-12 diagnosis: deeper pipeline was neutral (44us, MfmaUtil 29%) —
// the bind is L1/TA load throughput: wm-paired waves loaded IDENTICAL
// B-fragments (2x redundancy), 4.16MB & 4160 load-instrs per CU (~27us
// floor at ~64B/cy L1). Fix: each wave owns col-block cb=w (16 cols) of
// all 64 rows: per tile 4 loads of its contiguous 4KB slice (+w*4096),
// zero intra-block duplication -> per-CU bytes & load instrs halved.
// A-frags for all 64 rows live in registers (16 x short8 = 64 VGPR,
// total ~165 < 256 cap — round-11 lesson). 3-buffer rotation, 2 tiles
// slack (vmcnt(8), 4-load tiles). Same WT2 bytes, same MFMA set ->
// numerically identical to rounds 8-12 (absmax 0.25).
// ---------------------------------------------------------------------------
__global__ __launch_bounds__(256, 2)
void out_gemm_rank1(const float* __restrict__ AFw, const float* __restrict__ LFw,
                    const ushort* __restrict__ WT2, const float* __restrict__ bg,
                    float* __restrict__ out)
{
    __shared__ __align__(16) ushort AFb[64][136];
    __shared__ __align__(16) float  LFt[64][68];

    const int t = threadIdx.x;
    const int ot = blockIdx.x & 7;
    const int b0 = (blockIdx.x >> 3) * 64, o0 = ot * 64;
    const int w = t >> 6, l = t & 63;
    const int lr = l & 15, lg = l >> 4;

    {
        const int row = t >> 2, q = t & 3;
        const float4* srcA = reinterpret_cast<const float4*>(
            &AFw[(size_t)(b0 + row) * NH + q * 32]);
        #pragma unroll
        for (int g = 0; g < 4; ++g) {
            float4 fa = srcA[2 * g], fb = srcA[2 * g + 1];
            uint4 wv;
            wv.x = bf16pair(fa.x, fa.y); wv.y = bf16pair(fa.z, fa.w);
            wv.z = bf16pair(fb.x, fb.y); wv.w = bf16pair(fb.z, fb.w);
            *reinterpret_cast<uint4*>(&AFb[row][q * 32 + g * 8]) = wv;
        }
        const f32x4* srcL = reinterpret_cast<const f32x4*>(
            &LFw[(size_t)(b0 + row) * DIN + q * 16]);
        #pragma unroll
        for (int g = 0; g < 4; ++g) {
            f32x4 fv = srcL[g];
            #pragma unroll
            for (int j = 0; j < 4; ++j)
                LFt[q * 16 + g * 4 + j][row] = fv[j];
        }
    }
    __syncthreads();

    // wave w owns col-block cb = w: cols o0 + w*16 + lr; its 4 ks-frags are
    // the contiguous 4KB at tile_base + w*4096 (+ l*16 per lane).
    const char* base = reinterpret_cast<const char*>(WT2)
        + ((size_t)(ot * 65) * 16) * 1024 + w * 4096 + l * 16;

    u32x4 bf0[4], bf1[4], bf2[4];
    ISSUE_SLICE(bf0, base);                      // T0
    ISSUE_SLICE(bf1, base + 16384);              // T1
    ISSUE_SLICE(bf2, base + 2 * 16384);          // T2

    // A-fragments: all 64 rows (4 row-frags) x 4 ks, held for the whole loop
    short8 afr[4][4];
    #pragma unroll
    for (int m = 0; m < 4; ++m)
        #pragma unroll
        for (int ks = 0; ks < 4; ++ks)
            afr[m][ks] = *reinterpret_cast<const short8*>(
                &AFb[m * 16 + lr][ks * 32 + lg * 8]);

    f32x4 acc[4], tt[4];
    #pragma unroll
    for (int m = 0; m < 4; ++m) acc[m] = (f32x4){0.f, 0.f, 0.f, 0.f};

    auto computeI = [&](const u32x4* bf) {
        #pragma unroll
        for (int m = 0; m < 4; ++m) tt[m] = (f32x4){0.f, 0.f, 0.f, 0.f};
        #pragma unroll
        for (int ks = 0; ks < 4; ++ks) {
            short8 bv = as_s8(bf[ks]);
            #pragma unroll
            for (int m = 0; m < 4; ++m)
                tt[m] = __builtin_amdgcn_mfma_f32_16x16x32_bf16(afr[m][ks], bv, tt[m], 0, 0, 0);
        }
    };
    auto scaleAdd = [&](int i) {
        #pragma unroll
        for (int m = 0; m < 4; ++m) {
            f32x4 lf = *reinterpret_cast<const f32x4*>(&LFt[i][m * 16 + lg * 4]);
            #pragma unroll
            for (int r = 0; r < 4; ++r)
                acc[m][r] += lf[r] * tt[m][r];
        }
    };

    // tiles 0..64. Steady state: 3 tiles (12 loads) in flight;
    // WAIT_VM(8) == oldest tile resident, 2 tiles still flying.
    #pragma unroll 1
    for (int i = 0; i < 60; i += 3) {
        const char* p = base + (size_t)(i + 3) * 16384;
        WAIT_VM(8); computeI(bf0); scaleAdd(i);     ISSUE_SLICE(bf0, p);
        WAIT_VM(8); computeI(bf1); scaleAdd(i + 1); ISSUE_SLICE(bf1, p + 16384);
        WAIT_VM(8); computeI(bf2); scaleAdd(i + 2); ISSUE_SLICE(bf2, p + 2 * 16384);
    }
    // computed 0..59; in flight: T60(bf0), T61(bf1), T62(bf2)
    WAIT_VM(8); computeI(bf0); scaleAdd(60); ISSUE_SLICE(bf0, base + (size_t)63 * 16384);
    WAIT_VM(8); computeI(bf1); scaleAdd(61); ISSUE_SLICE(bf1, base + (size_t)64 * 16384);
    WAIT_VM(8); computeI(bf2); scaleAdd(62);
    WAIT_VM(4); computeI(bf0); scaleAdd(63);
    WAIT_VM(0); computeI(bf1);                   // T64: e-term, scale 1
    #pragma unroll
    for (int m = 0; m < 4; ++m)
        #pragma unroll
        for (int r = 0; r < 4; ++r)
            acc[m][r] += tt[m][r];

    // epilogue: bias + store (wave w -> cols o0+w*16+lr, rows m*16+lg*4+r)
    const int col = o0 + w * 16 + lr;
    const float bb = bg[col];
    #pragma unroll
    for (int m = 0; m < 4; ++m) {
        #pragma unroll
        for (int r = 0; r < 4; ++r) {
            const int row = b0 + m * 16 + lg * 4 + r;
            out[(size_t)row * DOUT + col] = acc[m][r] + bb;
        }
    }
}

// ---------------------------------------------------------------------------
// Workspace layout (bytes):
//   [0,        2097152)   AF  : float[4096][128]
//   [2097152,  3145728)   LF  : float[4096][64]
//   [3145728, +8519680)   WT2 : fragment-ordered bf16 W (8 o-tiles x 65 x 16KB)
// Fully rewritten before use each launch -> deterministic.
// ---------------------------------------------------------------------------
extern "C" void kernel_launch(void* const* d_in, const int* in_sizes, int n_in,
                              void* d_out, int out_size, void* d_ws, size_t ws_size,
                              hipStream_t stream)
{
    const float* LT   = (const float*)d_in[0];
    const float* Kg   = (const float*)d_in[1];
    const float* AT   = (const float*)d_in[2];
    const float* ug   = (const float*)d_in[3];
    const float* eg   = (const float*)d_in[4];
    const float* bg   = (const float*)d_in[5];
    const int*   msp  = (const int*)d_in[6];
    float* out = (float*)d_out;

    char* ws = (char*)d_ws;
    float*  AFw = (float*)(ws);
    float*  LFw = (float*)(ws + 2097152);
    ushort* WT2 = (ushort*)(ws + 3145728);

    solve_chain<<<dim3(256), dim3(256), 0, stream>>>(LT, Kg, AT, msp, AFw, LFw);
    prep_wt2<<<dim3(65, 8), dim3(256), 0, stream>>>(Kg, ug, eg, WT2);

    out_gemm_rank1<<<dim3(512), dim3(256), 0, stream>>>(AFw, LFw, WT2, bg, out);
}

// Round 14
// 69.514 us; speedup vs baseline: 18.2342x; 1.0965x over previous
//
#include <hip/hip_runtime.h>

// Problem constants
#define B_ROWS 4096
#define DIN 64
#define NH 128
#define DOUT 512
#define ROWS_PER_BLK 16
#define MAXSTEP_CAP 1000
#define NBS 256            // solve blocks (1 per CU); prep blocks follow

typedef __attribute__((ext_vector_type(8))) short short8;
typedef __attribute__((ext_vector_type(4))) float f32x4;
typedef __attribute__((ext_vector_type(4))) unsigned u32x4;

template<int N> struct IC { static constexpr int v = N; };

// round-to-nearest-even f32 -> bf16, packed pair into a uint
__device__ inline unsigned bf16pair(float lo, float hi) {
    unsigned a = __float_as_uint(lo), b = __float_as_uint(hi);
    a = (a + 0x7fffu + ((a >> 16) & 1u)) >> 16;
    b = (b + 0x7fffu + ((b >> 16) & 1u)) >> 16;
    return a | (b << 16);
}
__device__ inline ushort bf16r(float v) {
    unsigned u = __float_as_uint(v);
    return (ushort)((u + 0x7fffu + ((u >> 16) & 1u)) >> 16);
}
__device__ inline float frcp(float x) { return __builtin_amdgcn_rcpf(x); }
__device__ inline short8 as_s8(u32x4 v) { return __builtin_bit_cast(short8, v); }

// split-at-write: v -> hi=bf16(v), lo=bf16(v-hi) (validated rounds 6-13)
__device__ inline void splitw(float v, ushort* ph, ushort* pl) {
    unsigned u = __float_as_uint(v);
    unsigned uh = (u + 0x7fffu + ((u >> 16) & 1u)) & 0xffff0000u;
    float rs = v - __uint_as_float(uh);
    unsigned ul = __float_as_uint(rs);
    *ph = (ushort)(uh >> 16);
    *pl = (ushort)((ul + 0x7fffu + ((ul >> 16) & 1u)) >> 16);
}
// split 8 gathered f32 (after relu) into hi/lo bf16 fragments
__device__ inline void packsplit8(const float* x, short8& h8, short8& l8) {
    unsigned hb[8], lb[8];
    #pragma unroll
    for (int j = 0; j < 8; ++j) {
        float v = fmaxf(x[j], 0.0f);
        unsigned u = __float_as_uint(v);
        unsigned uh = (u + 0x7fffu + ((u >> 16) & 1u)) & 0xffff0000u;
        float rs = v - __uint_as_float(uh);
        unsigned ul = __float_as_uint(rs);
        hb[j] = uh >> 16;
        lb[j] = (ul + 0x7fffu + ((ul >> 16) & 1u)) >> 16;
    }
    uint4 hv, lv;
    hv.x = hb[0] | (hb[1] << 16); hv.y = hb[2] | (hb[3] << 16);
    hv.z = hb[4] | (hb[5] << 16); hv.w = hb[6] | (hb[7] << 16);
    lv.x = lb[0] | (lb[1] << 16); lv.y = lb[2] | (lb[3] << 16);
    lv.z = lb[4] | (lb[5] << 16); lv.w = lb[6] | (lb[7] << 16);
    h8 = *reinterpret_cast<short8*>(&hv);
    l8 = *reinterpret_cast<short8*>(&lv);
}

// issue 4 global_load_dwordx4 for one wave's tile slice (4KB contiguous)
#define ISSUE_SLICE(buf, ptr) do {                                                         \
    const char* _p = (ptr);                                                                \
    asm volatile("global_load_dwordx4 %0, %1, off"             : "=v"(buf[0]) : "v"(_p));  \
    asm volatile("global_load_dwordx4 %0, %1, off offset:1024" : "=v"(buf[1]) : "v"(_p));  \
    asm volatile("global_load_dwordx4 %0, %1, off offset:2048" : "=v"(buf[2]) : "v"(_p));  \
    asm volatile("global_load_dwordx4 %0, %1, off offset:3072" : "=v"(buf[3]) : "v"(_p));  \
} while (0)

#define WAIT_VM(N) do {                                  \
    asm volatile("s_waitcnt vmcnt(" #N ")");             \
    __builtin_amdgcn_sched_barrier(0);                   \
} while (0)

// Shared-memory union for the fused solve+prep kernel (both ~34.8 KB)
struct SolveSM {
    ushort AX[2][16][136];
    ushort AY[2][16][136];
    ushort LX[2][16][136];
    ushort LY[2][16][136];
    float wred[4];
};
struct PrepSM {
    float tile[128][68];
};
#define FUSED_SM_BYTES (sizeof(SolveSM) > sizeof(PrepSM) ? sizeof(SolveSM) : sizeof(PrepSM))

// ---------------------------------------------------------------------------
// Kernel A+P (fused): blocks 0..255 run the fixed-point solve (1 per CU);
// blocks 256..775 run prep tiles, backfilling as SECOND-resident blocks on
// the same CUs (LDS 2x34.8KB = 69.6 < 160KB) -> prep's ~8-10us serial time
// hides entirely under the ~28us solve. Both paths unchanged numerically
// (rounds 10-13, absmax 0.25).
// ---------------------------------------------------------------------------
__global__ __launch_bounds__(256, 1)
void solve_prep(const float* __restrict__ LT, const float* __restrict__ Kg,
                const float* __restrict__ AT, const int* __restrict__ msp,
                const float* __restrict__ ug, const float* __restrict__ eg,
                float* __restrict__ AFout, float* __restrict__ LFout,
                ushort* __restrict__ WT2)
{
    __shared__ __align__(16) unsigned char SMEM[FUSED_SM_BYTES];

    const int tid = threadIdx.x;

    if (blockIdx.x >= NBS) {
        // ================= PREP path (520 blocks) =================
        PrepSM& P = *reinterpret_cast<PrepSM*>(SMEM);
        const int bid2 = blockIdx.x - NBS;
        const int i = bid2 % 65;         // k-tile 0..64
        const int ot = bid2 / 65;        // o-tile 0..7
        const int k0 = i * 128;
        const bool mn = (i < 64);

        {
            const int r = tid >> 1, c0 = (tid & 1) * 32;
            const float* src = mn ? &ug[(size_t)(k0 + r) * DOUT + ot * 64 + c0]
                                  : &eg[(size_t)r * DOUT + ot * 64 + c0];
            const float sc = mn ? fmaxf(Kg[k0 + r], 0.0f) : 1.0f;
            #pragma unroll
            for (int g = 0; g < 8; ++g) {
                float4 v = *reinterpret_cast<const float4*>(src + g * 4);
                v.x *= sc; v.y *= sc; v.z *= sc; v.w *= sc;
                *reinterpret_cast<float4*>(&P.tile[r][c0 + g * 4]) = v;
            }
        }
        __syncthreads();
        {
            const int wnf = tid >> 4;
            const int f = wnf & 7;
            const int wn = wnf >> 3;
            const int ks = f & 3, n = (f >> 2) & 1;
            ushort* dst = WT2 + ((size_t)(ot * 65 + i) * 16 + wnf) * 512;
            #pragma unroll
            for (int q = 0; q < 4; ++q) {
                const int l = (tid & 15) * 4 + q;
                const int rb = ks * 32 + (l >> 4) * 8;
                const int c  = wn * 32 + n * 16 + (l & 15);
                uint4 v;
                v.x = bf16pair(P.tile[rb + 0][c], P.tile[rb + 1][c]);
                v.y = bf16pair(P.tile[rb + 2][c], P.tile[rb + 3][c]);
                v.z = bf16pair(P.tile[rb + 4][c], P.tile[rb + 5][c]);
                v.w = bf16pair(P.tile[rb + 6][c], P.tile[rb + 7][c]);
                *reinterpret_cast<uint4*>(dst + l * 8) = v;
            }
        }
        return;
    }

    // ================= SOLVE path (blocks 0..255) =================
    SolveSM& S = *reinterpret_cast<SolveSM*>(SMEM);
    auto& AX = S.AX; auto& AY = S.AY; auto& LX = S.LX; auto& LY = S.LY;
    auto& wred = S.wred;

    const int lane = tid & 63, w = tid >> 6;
    const int lr = lane & 15, lg = lane >> 4;
    const int b0row = blockIdx.x * ROWS_PER_BLK;

    for (int idx = tid; idx < 2176; idx += 256) {
        reinterpret_cast<unsigned*>(&AX[0][0][0])[idx] = 0u;
        reinterpret_cast<unsigned*>(&LX[0][0][0])[idx] = 0u;
    }

    int max_step = *msp;
    if (max_step > MAXSTEP_CAP) max_step = MAXSTEP_CAP;

    short8 BkH[4], BkL[4];
    #pragma unroll
    for (int ks = 0; ks < 4; ++ks) {
        float xx[8];
        const float* p = &Kg[(16 * w + lr) * NH + ks * 32 + lg * 8];
        #pragma unroll
        for (int j = 0; j < 8; ++j) xx[j] = p[j];
        packsplit8(xx, BkH[ks], BkL[ks]);
    }
    short8 BtH[2][2], BtL[2][2];
    #pragma unroll
    for (int t = 0; t < 2; ++t)
        #pragma unroll
        for (int ks = 0; ks < 2; ++ks) {
            float xx[8];
            #pragma unroll
            for (int j = 0; j < 8; ++j)
                xx[j] = Kg[(ks * 32 + lg * 8 + j) * NH + 32 * w + 16 * t + lr];
            packsplit8(xx, BtH[t][ks], BtL[t][ks]);
        }

    float ltv[4];
    #pragma unroll
    for (int r = 0; r < 4; ++r)
        ltv[r] = LT[(size_t)(b0row + lg * 4 + r) * DIN + 16 * w + lr];
    float atv[2];
    #pragma unroll
    for (int t = 0; t < 2; ++t)
        atv[t] = fmaxf(AT[32 * w + 16 * t + lr], 0.f);

    float prevA[2][4] = {};
    float prevL[4] = {};
    bool done = false;

    __syncthreads();

    auto iterate = [&](auto MC, bool check, float tol) {
        constexpr int mode = decltype(MC)::v;
        {   // AF P1
            f32x4 aH = {0.f,0.f,0.f,0.f}, aL = aH;
            #pragma unroll
            for (int ks = 0; ks < 4; ++ks) {
                short8 hi = *reinterpret_cast<const short8*>(&AX[0][lr][ks * 32 + lg * 8]);
                aH = __builtin_amdgcn_mfma_f32_16x16x32_bf16(hi, BkH[ks], aH, 0, 0, 0);
                if (mode >= 1) {
                    short8 lo = *reinterpret_cast<const short8*>(&AX[1][lr][ks * 32 + lg * 8]);
                    aL = __builtin_amdgcn_mfma_f32_16x16x32_bf16(lo, BkH[ks], aL, 0, 0, 0);
                }
                if (mode == 2)
                    aL = __builtin_amdgcn_mfma_f32_16x16x32_bf16(hi, BkL[ks], aL, 0, 0, 0);
            }
            #pragma unroll
            for (int r = 0; r < 4; ++r) {
                float v = ltv[r] * frcp(aH[r] + aL[r] + 1.0f);
                if (mode == 0) AY[0][lg * 4 + r][16 * w + lr] = bf16r(v);
                else splitw(v, &AY[0][lg * 4 + r][16 * w + lr],
                               &AY[1][lg * 4 + r][16 * w + lr]);
            }
        }
        {   // LF P1
            short8 xh0 = *reinterpret_cast<const short8*>(&LX[0][lr][lg * 8]);
            short8 xh1 = *reinterpret_cast<const short8*>(&LX[0][lr][32 + lg * 8]);
            short8 xl0, xl1;
            if (mode >= 1) {
                xl0 = *reinterpret_cast<const short8*>(&LX[1][lr][lg * 8]);
                xl1 = *reinterpret_cast<const short8*>(&LX[1][lr][32 + lg * 8]);
            }
            #pragma unroll
            for (int t = 0; t < 2; ++t) {
                f32x4 bH = {0.f,0.f,0.f,0.f}, bL = bH;
                bH = __builtin_amdgcn_mfma_f32_16x16x32_bf16(xh0, BtH[t][0], bH, 0, 0, 0);
                bH = __builtin_amdgcn_mfma_f32_16x16x32_bf16(xh1, BtH[t][1], bH, 0, 0, 0);
                if (mode >= 1) {
                    bL = __builtin_amdgcn_mfma_f32_16x16x32_bf16(xl0, BtH[t][0], bL, 0, 0, 0);
                    bL = __builtin_amdgcn_mfma_f32_16x16x32_bf16(xl1, BtH[t][1], bL, 0, 0, 0);
                }
                if (mode == 2) {
                    bL = __builtin_amdgcn_mfma_f32_16x16x32_bf16(xh0, BtL[t][0], bL, 0, 0, 0);
                    bL = __builtin_amdgcn_mfma_f32_16x16x32_bf16(xh1, BtL[t][1], bL, 0, 0, 0);
                }
                #pragma unroll
                for (int r = 0; r < 4; ++r) {
                    float v = atv[t] * frcp(bH[r] + bL[r] + 1.0f);
                    if (mode == 0) LY[0][lg * 4 + r][32 * w + 16 * t + lr] = bf16r(v);
                    else splitw(v, &LY[0][lg * 4 + r][32 * w + 16 * t + lr],
                                   &LY[1][lg * 4 + r][32 * w + 16 * t + lr]);
                }
            }
        }
        __syncthreads();
        float flag = -1.0f;
        {   // AF P2
            short8 yh0 = *reinterpret_cast<const short8*>(&AY[0][lr][lg * 8]);
            short8 yh1 = *reinterpret_cast<const short8*>(&AY[0][lr][32 + lg * 8]);
            short8 yl0, yl1;
            if (mode >= 1) {
                yl0 = *reinterpret_cast<const short8*>(&AY[1][lr][lg * 8]);
                yl1 = *reinterpret_cast<const short8*>(&AY[1][lr][32 + lg * 8]);
            }
            #pragma unroll
            for (int t = 0; t < 2; ++t) {
                f32x4 bH = {0.f,0.f,0.f,0.f}, bL = bH;
                bH = __builtin_amdgcn_mfma_f32_16x16x32_bf16(yh0, BtH[t][0], bH, 0, 0, 0);
                bH = __builtin_amdgcn_mfma_f32_16x16x32_bf16(yh1, BtH[t][1], bH, 0, 0, 0);
                if (mode >= 1) {
                    bL = __builtin_amdgcn_mfma_f32_16x16x32_bf16(yl0, BtH[t][0], bL, 0, 0, 0);
                    bL = __builtin_amdgcn_mfma_f32_16x16x32_bf16(yl1, BtH[t][1], bL, 0, 0, 0);
                }
                if (mode == 2) {
                    bL = __builtin_amdgcn_mfma_f32_16x16x32_bf16(yh0, BtL[t][0], bL, 0, 0, 0);
                    bL = __builtin_amdgcn_mfma_f32_16x16x32_bf16(yh1, BtL[t][1], bL, 0, 0, 0);
                }
                #pragma unroll
                for (int r = 0; r < 4; ++r) {
                    float v = atv[t] * frcp(bH[r] + bL[r] + 1.0f);
                    if (check) {
                        float p = prevA[t][r];
                        flag = fmaxf(flag, fabsf(v - p) - tol * (p + 1e-5f));
                    }
                    prevA[t][r] = v;
                    if (mode == 0) AX[0][lg * 4 + r][32 * w + 16 * t + lr] = bf16r(v);
                    else splitw(v, &AX[0][lg * 4 + r][32 * w + 16 * t + lr],
                                   &AX[1][lg * 4 + r][32 * w + 16 * t + lr]);
                }
            }
        }
        {   // LF P2
            f32x4 aH = {0.f,0.f,0.f,0.f}, aL = aH;
            #pragma unroll
            for (int ks = 0; ks < 4; ++ks) {
                short8 hi = *reinterpret_cast<const short8*>(&LY[0][lr][ks * 32 + lg * 8]);
                aH = __builtin_amdgcn_mfma_f32_16x16x32_bf16(hi, BkH[ks], aH, 0, 0, 0);
                if (mode >= 1) {
                    short8 lo = *reinterpret_cast<const short8*>(&LY[1][lr][ks * 32 + lg * 8]);
                    aL = __builtin_amdgcn_mfma_f32_16x16x32_bf16(lo, BkH[ks], aL, 0, 0, 0);
                }
                if (mode == 2)
                    aL = __builtin_amdgcn_mfma_f32_16x16x32_bf16(hi, BkL[ks], aL, 0, 0, 0);
            }
            #pragma unroll
            for (int r = 0; r < 4; ++r) {
                float v = ltv[r] * frcp(aH[r] + aL[r] + 1.0f);
                if (check) {
                    float p = prevL[r];
                    flag = fmaxf(flag, fabsf(v - p) - tol * (p + 1e-5f));
                }
                prevL[r] = v;
                if (mode == 0) LX[0][lg * 4 + r][16 * w + lr] = bf16r(v);
                else splitw(v, &LX[0][lg * 4 + r][16 * w + lr],
                               &LX[1][lg * 4 + r][16 * w + lr]);
            }
        }
        if (check) {
            #pragma unroll
            for (int off = 32; off; off >>= 1)
                flag = fmaxf(flag, __shfl_xor(flag, off));
            if (lane == 0) wred[w] = flag;
        }
        __syncthreads();
        if (check)
            done = fmaxf(fmaxf(wred[0], wred[1]), fmaxf(wred[2], wred[3])) < 0.0f;
    };

    int step = 0;
    const int cheapN = max_step < 12 ? max_step : 12;
    for (int s = 0; s < cheapN; ++s, ++step)
        iterate(IC<0>{}, false, 0.f);
    const int capC = max_step < 64 ? max_step : 64;
    while (step < capC && !done) { iterate(IC<0>{}, true, 6e-3f); ++step; }
    done = false;
    while (step < max_step && !done) { iterate(IC<1>{}, true, 5e-5f); ++step; }
    iterate(IC<2>{}, false, 0.f);
    iterate(IC<2>{}, false, 0.f);
    iterate(IC<2>{}, false, 0.f);

    #pragma unroll
    for (int t = 0; t < 2; ++t)
        #pragma unroll
        for (int r = 0; r < 4; ++r)
            AFout[(size_t)(b0row + lg * 4 + r) * NH + 32 * w + 16 * t + lr] = prevA[t][r];
    #pragma unroll
    for (int r = 0; r < 4; ++r)
        LFout[(size_t)(b0row + lg * 4 + r) * DIN + 16 * w + lr] = prevL[r];
}

// ---------------------------------------------------------------------------
// Kernel B (v8 + setprio): rank-1, wave = 64 rows x 16 cols, 3-buffer
// pipeline (round 13, validated). s_setprio(1) around the MFMA cluster —
// our waves are barrier-free/staggered (the m191 regime where setprio pays,
// not m190's lockstep), so the CU scheduler can favor MFMA-entering waves.
// ---------------------------------------------------------------------------
__global__ __launch_bounds__(256, 2)
void out_gemm_rank1(const float* __restrict__ AFw, const float* __restrict__ LFw,
                    const ushort* __restrict__ WT2, const float* __restrict__ bg,
                    float* __restrict__ out)
{
    __shared__ __align__(16) ushort AFb[64][136];
    __shared__ __align__(16) float  LFt[64][68];

    const int t = threadIdx.x;
    const int ot = blockIdx.x & 7;
    const int b0 = (blockIdx.x >> 3) * 64, o0 = ot * 64;
    const int w = t >> 6, l = t & 63;
    const int lr = l & 15, lg = l >> 4;

    {
        const int row = t >> 2, q = t & 3;
        const float4* srcA = reinterpret_cast<const float4*>(
            &AFw[(size_t)(b0 + row) * NH + q * 32]);
        #pragma unroll
        for (int g = 0; g < 4; ++g) {
            float4 fa = srcA[2 * g], fb = srcA[2 * g + 1];
            uint4 wv;
            wv.x = bf16pair(fa.x, fa.y); wv.y = bf16pair(fa.z, fa.w);
            wv.z = bf16pair(fb.x, fb.y); wv.w = bf16pair(fb.z, fb.w);
            *reinterpret_cast<uint4*>(&AFb[row][q * 32 + g * 8]) = wv;
        }
        const f32x4* srcL = reinterpret_cast<const f32x4*>(
            &LFw[(size_t)(b0 + row) * DIN + q * 16]);
        #pragma unroll
        for (int g = 0; g < 4; ++g) {
            f32x4 fv = srcL[g];
            #pragma unroll
            for (int j = 0; j < 4; ++j)
                LFt[q * 16 + g * 4 + j][row] = fv[j];
        }
    }
    __syncthreads();

    const char* base = reinterpret_cast<const char*>(WT2)
        + ((size_t)(ot * 65) * 16) * 1024 + w * 4096 + l * 16;

    u32x4 bf0[4], bf1[4], bf2[4];
    ISSUE_SLICE(bf0, base);
    ISSUE_SLICE(bf1, base + 16384);
    ISSUE_SLICE(bf2, base + 2 * 16384);

    short8 afr[4][4];
    #pragma unroll
    for (int m = 0; m < 4; ++m)
        #pragma unroll
        for (int ks = 0; ks < 4; ++ks)
            afr[m][ks] = *reinterpret_cast<const short8*>(
                &AFb[m * 16 + lr][ks * 32 + lg * 8]);

    f32x4 acc[4], tt[4];
    #pragma unroll
    for (int m = 0; m < 4; ++m) acc[m] = (f32x4){0.f, 0.f, 0.f, 0.f};

    auto computeI = [&](const u32x4* bf) {
        #pragma unroll
        for (int m = 0; m < 4; ++m) tt[m] = (f32x4){0.f, 0.f, 0.f, 0.f};
        __builtin_amdgcn_s_setprio(1);
        #pragma unroll
        for (int ks = 0; ks < 4; ++ks) {
            short8 bv = as_s8(bf[ks]);
            #pragma unroll
            for (int m = 0; m < 4; ++m)
                tt[m] = __builtin_amdgcn_mfma_f32_16x16x32_bf16(afr[m][ks], bv, tt[m], 0, 0, 0);
        }
        __builtin_amdgcn_s_setprio(0);
    };
    auto scaleAdd = [&](int i) {
        #pragma unroll
        for (int m = 0; m < 4; ++m) {
            f32x4 lf = *reinterpret_cast<const f32x4*>(&LFt[i][m * 16 + lg * 4]);
            #pragma unroll
            for (int r = 0; r < 4; ++r)
                acc[m][r] += lf[r] * tt[m][r];
        }
    };

    #pragma unroll 1
    for (int i = 0; i < 60; i += 3) {
        const char* p = base + (size_t)(i + 3) * 16384;
        WAIT_VM(8); computeI(bf0); scaleAdd(i);     ISSUE_SLICE(bf0, p);
        WAIT_VM(8); computeI(bf1); scaleAdd(i + 1); ISSUE_SLICE(bf1, p + 16384);
        WAIT_VM(8); computeI(bf2); scaleAdd(i + 2); ISSUE_SLICE(bf2, p + 2 * 16384);
    }
    WAIT_VM(8); computeI(bf0); scaleAdd(60); ISSUE_SLICE(bf0, base + (size_t)63 * 16384);
    WAIT_VM(8); computeI(bf1); scaleAdd(61); ISSUE_SLICE(bf1, base + (size_t)64 * 16384);
    WAIT_VM(8); computeI(bf2); scaleAdd(62);
    WAIT_VM(4); computeI(bf0); scaleAdd(63);
    WAIT_VM(0); computeI(bf1);                   // T64: e-term, scale 1
    #pragma unroll
    for (int m = 0; m < 4; ++m)
        #pragma unroll
        for (int r = 0; r < 4; ++r)
            acc[m][r] += tt[m][r];

    const int col = o0 + w * 16 + lr;
    const float bb = bg[col];
    #pragma unroll
    for (int m = 0; m < 4; ++m) {
        #pragma unroll
        for (int r = 0; r < 4; ++r) {
            const int row = b0 + m * 16 + lg * 4 + r;
            out[(size_t)row * DOUT + col] = acc[m][r] + bb;
        }
    }
}

// ---------------------------------------------------------------------------
// Workspace layout (bytes):
//   [0,        2097152)   AF  : float[4096][128]
//   [2097152,  3145728)   LF  : float[4096][64]
//   [3145728, +8519680)   WT2 : fragment-ordered bf16 W (8 o-tiles x 65 x 16KB)
// Fully rewritten before use each launch -> deterministic.
// ---------------------------------------------------------------------------
extern "C" void kernel_launch(void* const* d_in, const int* in_sizes, int n_in,
                              void* d_out, int out_size, void* d_ws, size_t ws_size,
                              hipStream_t stream)
{
    const float* LT   = (const float*)d_in[0];
    const float* Kg   = (const float*)d_in[1];
    const float* AT   = (const float*)d_in[2];
    const float* ug   = (const float*)d_in[3];
    const float* eg   = (const float*)d_in[4];
    const float* bg   = (const float*)d_in[5];
    const int*   msp  = (const int*)d_in[6];
    float* out = (float*)d_out;

    char* ws = (char*)d_ws;
    float*  AFw = (float*)(ws);
    float*  LFw = (float*)(ws + 2097152);
    ushort* WT2 = (ushort*)(ws + 3145728);

    // fused: 256 solve blocks + 520 prep blocks (prep hides under solve)
    solve_prep<<<dim3(NBS + 520), dim3(256), 0, stream>>>(
        LT, Kg, AT, msp, ug, eg, AFw, LFw, WT2);

    out_gemm_rank1<<<dim3(512), dim3(256), 0, stream>>>(AFw, LFw, WT2, bg, out);
}